// Round 12
// baseline (412.851 us; speedup 1.0000x reference)
//
#include <hip/hip_runtime.h>

#define HIST_BPG 32              // edge-slice blocks per (histogram, half) group
#define HIST_B   (HIST_BPG * 4)  // 4 groups: src-lo, src-hi, dst-lo, dst-hi
#define HIST_MAXW 12288          // max packed words (supports Nn <= ~49k)

// ---------- helpers ----------
__device__ inline float bf2f(unsigned short u) {
    return __uint_as_float(((unsigned)u) << 16);
}
__device__ inline unsigned short f2bf(float f) {
    unsigned u = __float_as_uint(f);
    u += 0x7fffu + ((u >> 16) & 1u);   // round-to-nearest-even
    return (unsigned short)(u >> 16);
}

typedef __attribute__((ext_vector_type(8))) short short8v;   // 8 bf16 (4 VGPRs)
typedef __attribute__((ext_vector_type(4))) float f32x4;

// ================= device bodies =================

// ---- f32 GEMM body (64-row tile): C[M x 128] = A @ W (+ bias) ----
// Optional outputs: C (f32 [row][col]) and Ct (bf16 TRANSPOSED [col][row]).
// __shared__ declared DIRECTLY here (char*-cast LDS caused 256-VGPR spill, r7-8).
__device__ __forceinline__
void gemmf32_body(const float* __restrict__ A, const float* __restrict__ W,
                  const float* __restrict__ bias, float* __restrict__ C,
                  unsigned short* __restrict__ Ct, int M, int tile)
{
    __shared__ float As[64][132];
    __shared__ float Ws[32][128];

    const int tid = threadIdx.x;
    const int row0 = tile * 64;

#pragma unroll
    for (int i = 0; i < 8; ++i) {
        int idx = tid + i * 256;
        int rr = idx >> 5;
        int cc = (idx & 31) << 2;
        int gr = row0 + rr;
        float4 v = make_float4(0.f, 0.f, 0.f, 0.f);
        if (gr < M) v = *reinterpret_cast<const float4*>(A + (size_t)gr * 128 + cc);
        *reinterpret_cast<float4*>(&As[rr][cc]) = v;
    }

    const int tx = tid & 15;
    const int ty = tid >> 4;
    float acc[4][8];
#pragma unroll
    for (int i = 0; i < 4; ++i)
#pragma unroll
        for (int j = 0; j < 8; ++j) acc[i][j] = 0.f;

    for (int kt = 0; kt < 4; ++kt) {
        __syncthreads();
#pragma unroll
        for (int i = 0; i < 4; ++i) {
            int idx = tid + i * 256;
            int rr = idx >> 5;
            int cc = (idx & 31) << 2;
            *reinterpret_cast<float4*>(&Ws[rr][cc]) =
                *reinterpret_cast<const float4*>(W + (size_t)(kt * 32 + rr) * 128 + cc);
        }
        __syncthreads();
#pragma unroll
        for (int kk = 0; kk < 32; ++kk) {
            const int k = kt * 32 + kk;
            float a0 = As[ty * 4 + 0][k];
            float a1 = As[ty * 4 + 1][k];
            float a2 = As[ty * 4 + 2][k];
            float a3 = As[ty * 4 + 3][k];
            float w[8];
#pragma unroll
            for (int j = 0; j < 8; ++j) w[j] = Ws[kk][tx + 16 * j];
#pragma unroll
            for (int j = 0; j < 8; ++j) {
                acc[0][j] = fmaf(a0, w[j], acc[0][j]);
                acc[1][j] = fmaf(a1, w[j], acc[1][j]);
                acc[2][j] = fmaf(a2, w[j], acc[2][j]);
                acc[3][j] = fmaf(a3, w[j], acc[3][j]);
            }
        }
    }

    float bb[8];
#pragma unroll
    for (int j = 0; j < 8; ++j) bb[j] = bias ? bias[tx + 16 * j] : 0.f;

#pragma unroll
    for (int i = 0; i < 4; ++i) {
        int gr = row0 + ty * 4 + i;
        if (gr >= M) continue;
#pragma unroll
        for (int j = 0; j < 8; ++j) {
            float v = acc[i][j] + bb[j];
            if (C)  C[(size_t)gr * 128 + tx + 16 * j] = v;
            if (Ct) Ct[(size_t)(tx + 16 * j) * 128 + gr] = f2bf(v);
        }
    }
}

// ---- MFMA GEMM body (operand-swapped), LDS-staged B, 32 rows/wave ----
// Block = 4 waves = 128-row tile x 128 cols. Combines round-9's a[2]/acc[2][8]
// tiling (verified) with round-10's XOR-swizzled LDS B staging (verified):
// halves ds_read count per MFMA vs the 16-row variant.
__device__ __forceinline__
void mfma128_body(const unsigned short* __restrict__ A,
                  const unsigned short* __restrict__ Wmat,
                  const float* __restrict__ bias,
                  float* __restrict__ Cf, unsigned short* __restrict__ Cb,
                  int M, int tile)
{
    __shared__ unsigned short Bs[16384];   // 32 KB

    const int tid = threadIdx.x;
#pragma unroll
    for (int i = 0; i < 8; ++i) {
        int idx = tid + i * 256;                 // 16B chunk id, 0..2047
        uint4 v = *reinterpret_cast<const uint4*>(Wmat + (size_t)idx * 8);
        int row = idx >> 4;
        int j = idx & 15;
        int byte = row * 256 + ((j ^ (row & 15)) << 4);
        *reinterpret_cast<uint4*>(reinterpret_cast<char*>(Bs) + byte) = v;
    }
    __syncthreads();

    const int wave = tid >> 6;
    const int lane = tid & 63;
    const int grp = lane >> 4;
    const int l16 = lane & 15;
    const int row0 = tile * 128 + wave * 32;

    f32x4 acc[2][8] = {};
#pragma unroll
    for (int kt = 0; kt < 4; ++kt) {
        const int k0 = kt * 32 + grp * 8;
        short8v a[2];
#pragma unroll
        for (int m = 0; m < 2; ++m) {
            int r = row0 + 16 * m + l16;
            if (r > M - 1) r = M - 1;            // clamp; tail rows not stored
            a[m] = *reinterpret_cast<const short8v*>(A + (size_t)r * 128 + k0);
        }
        const int joff = kt * 4 + grp;           // k-chunk index 0..15
#pragma unroll
        for (int n = 0; n < 8; ++n) {
            int brow = 16 * n + l16;
            int byte = brow * 256 + ((joff ^ (brow & 15)) << 4);
            short8v b = *reinterpret_cast<const short8v*>(
                reinterpret_cast<const char*>(Bs) + byte);
            acc[0][n] = __builtin_amdgcn_mfma_f32_16x16x32_bf16(b, a[0], acc[0][n], 0, 0, 0);
            acc[1][n] = __builtin_amdgcn_mfma_f32_16x16x32_bf16(b, a[1], acc[1][n], 0, 0, 0);
        }
    }

    float4 bb[8];
#pragma unroll
    for (int n = 0; n < 8; ++n)
        bb[n] = bias ? *reinterpret_cast<const float4*>(bias + 16 * n + grp * 4)
                     : make_float4(0.f, 0.f, 0.f, 0.f);

#pragma unroll
    for (int m = 0; m < 2; ++m) {
        int row = row0 + 16 * m + l16;
        if (row >= M) continue;
#pragma unroll
        for (int n = 0; n < 8; ++n) {
            float v0 = acc[m][n][0] + bb[n].x;
            float v1 = acc[m][n][1] + bb[n].y;
            float v2 = acc[m][n][2] + bb[n].z;
            float v3 = acc[m][n][3] + bb[n].w;
            if (Cf) {
                *reinterpret_cast<float4*>(Cf + (size_t)row * 128 + 16 * n + grp * 4) =
                    make_float4(v0, v1, v2, v3);
            }
            if (Cb) {
                unsigned u0 = (unsigned)f2bf(v0) | ((unsigned)f2bf(v1) << 16);
                unsigned u1 = (unsigned)f2bf(v2) | ((unsigned)f2bf(v3) << 16);
                *reinterpret_cast<uint2*>(Cb + (size_t)row * 128 + 16 * n + grp * 4) =
                    make_uint2(u0, u1);
            }
        }
    }
}

// fused 6-mat pass dispatch (tile-major: consecutive blocks share A rows in L2)
__device__ void fused_dispatch(const unsigned short* A, const unsigned short* Wt,
                               const float* biasbuf, unsigned short* Xb,
                               unsigned short* Yb, int base, int M, int nmats, int bid)
{
    int m = bid % nmats;
    int tile = bid / nmats;
    unsigned short* out = (m == 0) ? Xb : Yb + (size_t)(m - 1) * (size_t)M * 128;
    mfma128_body(A, Wt + (size_t)(base + m) * 16384,
                 biasbuf + (size_t)(base + m) * 128, nullptr, out, M, tile);
}

// ---- bias product body: out[t] = sum_j v[j]*W[j*128+t] (+ add[t]) ----
__device__ void biasprod_body(const float* __restrict__ v, const float* __restrict__ W,
                              const float* __restrict__ add, float* __restrict__ out)
{
    int t = threadIdx.x;
    if (t >= 128) return;
    float s = add ? add[t] : 0.f;
    for (int j = 0; j < 128; ++j) s = fmaf(v[j], W[(size_t)j * 128 + t], s);
    out[t] = s;
}

// ---- bf16-transpose convert body: Wt[mat] <- f32 W[k][n] ----
__device__ void wtconv_body(const float* __restrict__ W, unsigned short* __restrict__ O)
{
    for (int i = threadIdx.x; i < 16384; i += 256) {
        int k = i >> 7, n = i & 127;
        O[(size_t)n * 128 + k] = f2bf(W[i]);
    }
}

// ---- bn stats body ----
__device__ void bn_stats_body(const float* __restrict__ h, float* __restrict__ sums,
                              int Nn, int b)
{
    const int c = threadIdx.x & 127;
    const int half = threadIdx.x >> 7;
    float s = 0.f, q = 0.f;
    for (int row = b * 2 + half; row < Nn; row += 512) {
        float v = h[(size_t)row * 128 + c];
        s += v;
        q += v * v;
    }
    __shared__ float ls[256], lq[256];
    ls[threadIdx.x] = s;
    lq[threadIdx.x] = q;
    __syncthreads();
    if (half == 0) {
        s += ls[threadIdx.x + 128];
        q += lq[threadIdx.x + 128];
        atomicAdd(&sums[c], s);
        atomicAdd(&sums[128 + c], q);
    }
}

// ---- scan bodies (counts padded to multiple of 4 for CSR 4-unroll) ----
__device__ void scan_block_sums_body(const int* __restrict__ cnt, int* __restrict__ bsum,
                                     int Nn, int b)
{
    __shared__ int sd[256];
    int tid = threadIdx.x;
    int i = b * 256 + tid;
    sd[tid] = i < Nn ? ((cnt[i] + 3) & ~3) : 0;
    __syncthreads();
#pragma unroll
    for (int s = 128; s > 0; s >>= 1) {
        if (tid < s) sd[tid] += sd[tid + s];
        __syncthreads();
    }
    if (tid == 0) bsum[b] = sd[0];
}

__device__ void scan_offsets_body(int* __restrict__ bsum, int nb)   // nb <= 256
{
    __shared__ int sd[256];
    int tid = threadIdx.x;
    int v = tid < nb ? bsum[tid] : 0;
    sd[tid] = v;
    __syncthreads();
    for (int d = 1; d < 256; d <<= 1) {
        int t = tid >= d ? sd[tid - d] : 0;
        __syncthreads();
        sd[tid] += t;
        __syncthreads();
    }
    if (tid < nb) bsum[tid] = sd[tid] - v;   // exclusive
}

// ================= kernels =================

// KP1: stage-1 weight products + biases + converts.
__global__ __launch_bounds__(256)
void kprod1(const float* win0w, const float* win0b, const float* win1w, const float* win1b,
            const float* cout0w, const float* cout0b, const float* cout1w,
            const float* cout1b, const float* wrel0,
            float* WfA1, unsigned short* Wt, float* biasbuf, int nrel)
{
    const int IA1 = 1 + nrel, IC1 = 2 + 2 * nrel;
    const int nProd = 1 + nrel;
    int bid = blockIdx.x;
    if (bid < 2 * nProd) {
        int p = bid >> 1, tile = bid & 1;
        if (p == 0)
            gemmf32_body(cout0w, win1w, nullptr, WfA1, Wt + (size_t)IA1 * 16384, 128, tile);
        else
            gemmf32_body(win0w, wrel0 + (size_t)(p - 1) * 16384, nullptr,
                         nullptr, Wt + (size_t)p * 16384, 128, tile);
        return;
    }
    bid -= 2 * nProd;
    if (bid < nProd) {
        if (bid == 0) biasprod_body(cout0b, win1w, win1b, biasbuf + (size_t)IA1 * 128);
        else biasprod_body(win0b, wrel0 + (size_t)(bid - 1) * 16384, nullptr,
                           biasbuf + (size_t)bid * 128);
        return;
    }
    bid -= nProd;
    if (bid == 0) { wtconv_body(win0w, Wt); return; }
    if (bid == 1) { wtconv_body(cout1w, Wt + (size_t)IC1 * 16384); return; }
    int t = threadIdx.x;
    if (t < 128) {
        biasbuf[t] = win0b[t];
        biasbuf[(size_t)IC1 * 128 + t] = cout1b[t];
    }
}

// KP2: stage-2 products.
__global__ __launch_bounds__(256)
void kprod2(const float* wrel1, const float* WfA1, unsigned short* Wt,
            float* biasbuf, int nrel)
{
    const int IA1 = 1 + nrel, IB1 = 2 + nrel;
    int bid = blockIdx.x;
    if (bid < 2 * nrel) {
        int p = bid >> 1, tile = bid & 1;
        gemmf32_body(WfA1, wrel1 + (size_t)p * 16384, nullptr,
                     nullptr, Wt + (size_t)(IB1 + p) * 16384, 128, tile);
        return;
    }
    int r = bid - 2 * nrel;
    biasprod_body(biasbuf + (size_t)IA1 * 128, wrel1 + (size_t)r * 16384, nullptr,
                  biasbuf + (size_t)(IB1 + r) * 128);
}

// histogram (standalone, low VGPR, no global atomics)
__global__ __launch_bounds__(256)
void hist_kernel(const int* __restrict__ ei, unsigned* __restrict__ partial,
                 int Nn, int E, int WORDS, int HALFR)
{
    __shared__ unsigned sh[HIST_MAXW];
    const int hbid = blockIdx.x;
    const int g = hbid / HIST_BPG;
    const int j = hbid - g * HIST_BPG;

    for (int w = threadIdx.x; w < WORDS; w += 256) sh[w] = 0;
    __syncthreads();

    const int* col = (g < 2) ? (ei + E) : ei;
    const int base = (g & 1) * HALFR;
    const size_t e0 = (size_t)E * j / HIST_BPG;
    const size_t e1 = (size_t)E * (j + 1) / HIST_BPG;
    for (size_t e = e0 + threadIdx.x; e < e1; e += 256) {
        int n = col[e] - base;
        if ((unsigned)n < (unsigned)HALFR)
            atomicAdd(&sh[n >> 1], 1u << ((n & 1) * 16));
    }
    __syncthreads();

    unsigned* out = partial + (size_t)hbid * WORDS;
    for (int w = threadIdx.x; w < WORDS; w += 256) out[w] = sh[w];
}

// proj f32 GEMM (standalone)
__global__ __launch_bounds__(256)
void proj_kernel(const float* __restrict__ x, const float* __restrict__ W,
                 const float* __restrict__ bias, float* __restrict__ h, int M)
{
    gemmf32_body(x, W, bias, h, nullptr, M, blockIdx.x);
}

// K2: hist-reduce (-> dis, cnt) | bn_stats
__global__ __launch_bounds__(256)
void k2_reduce_bnstats(const unsigned* __restrict__ partial, float* __restrict__ dis,
                       int* __restrict__ cnt, const float* __restrict__ h,
                       float* __restrict__ bnsums, int Nn, int WORDS, int HALFR, int nRed)
{
    int bid = blockIdx.x;
    if (bid < nRed) {
        int t = bid * 256 + threadIdx.x;
        if (t < 4 * WORDS) {
            int histo = t / (2 * WORDS);
            int rem = t - histo * 2 * WORDS;
            int half = rem / WORDS;
            int w = rem - half * WORDS;
            int g = histo * 2 + half;
            unsigned slo = 0, shi = 0;
            const unsigned* p = partial + (size_t)(g * HIST_BPG) * WORDS + w;
#pragma unroll 4
            for (int j = 0; j < HIST_BPG; ++j) {
                unsigned u = p[(size_t)j * WORDS];
                slo += u & 0xffffu;
                shi += u >> 16;
            }
            int n0 = half * HALFR + 2 * w;
            int n1 = n0 + 1;
            if (histo == 0) {
                if (n0 < Nn) dis[n0] = slo ? rsqrtf((float)slo) : 0.f;
                if (n1 < Nn) dis[n1] = shi ? rsqrtf((float)shi) : 0.f;
            } else {
                if (n0 < Nn) cnt[n0] = (int)slo;
                if (n1 < Nn) cnt[n1] = (int)shi;
            }
        }
        return;
    }
    bn_stats_body(h, bnsums, Nn, bid - nRed);
}

// K3: bn_finalize | scan_block_sums (padded)
__global__ __launch_bounds__(256)
void k3_bnfin_scan1(const float* __restrict__ sums, const float* __restrict__ g,
                    const float* __restrict__ b, float* __restrict__ sc,
                    const int* __restrict__ cnt, int* __restrict__ bsum, int Nn)
{
    if (blockIdx.x == 0) {
        int c = threadIdx.x;
        if (c < 128) {
            float inv = 1.f / (float)Nn;
            float mu = sums[c] * inv;
            float var = sums[128 + c] * inv - mu * mu;
            float rstd = rsqrtf(var + 1e-5f);
            float scale = rstd * g[c];
            sc[c] = scale;
            sc[128 + c] = b[c] - mu * scale;
        }
        return;
    }
    scan_block_sums_body(cnt, bsum, Nn, blockIdx.x - 1);
}

// K4: scan_offsets | bn_apply_relu (f32 -> bf16)
__global__ __launch_bounds__(256)
void k4_scanoff_bnapply(int* __restrict__ bsum, int nb,
                        const float* __restrict__ h, const float* __restrict__ sc,
                        unsigned short* __restrict__ hb, size_t n4)
{
    if (blockIdx.x == 0) { scan_offsets_body(bsum, nb); return; }
    size_t i = (size_t)(blockIdx.x - 1) * 256 + threadIdx.x;
    if (i >= n4) return;
    int c = (int)(i & 31) << 2;
    float4 v = reinterpret_cast<const float4*>(h)[i];
    float o0 = fmaxf(fmaf(v.x, sc[c + 0], sc[128 + c + 0]), 0.f);
    float o1 = fmaxf(fmaf(v.y, sc[c + 1], sc[128 + c + 1]), 0.f);
    float o2 = fmaxf(fmaf(v.z, sc[c + 2], sc[128 + c + 2]), 0.f);
    float o3 = fmaxf(fmaf(v.w, sc[c + 3], sc[128 + c + 3]), 0.f);
    ushort4 pk = make_ushort4(f2bf(o0), f2bf(o1), f2bf(o2), f2bf(o3));
    reinterpret_cast<ushort4*>(hb)[i] = pk;
}

// K4b: scan_final with 4-padded offsets; writes rowptr/cursor, sink pad
// entries, 8 global pad entries, and the bf16 -100 sink row in Yw.
__global__ __launch_bounds__(256)
void k4b_scanfinal(const int* __restrict__ cnt, const int* __restrict__ bsum,
                   int* __restrict__ rowptr, int* __restrict__ cursor,
                   uint4* __restrict__ csr, unsigned* __restrict__ Yw,
                   unsigned sink_woff, int Nn, int nb)
{
    if ((int)blockIdx.x == nb) {
        int t = threadIdx.x;
        if (t < 64) Yw[sink_woff + t] = 0xC2C8C2C8u;   // bf16 -100 pair
        return;
    }
    __shared__ int sd[256];
    int tid = threadIdx.x;
    int b = blockIdx.x;
    int i = b * 256 + tid;
    int v = i < Nn ? cnt[i] : 0;
    int pv = (v + 3) & ~3;
    sd[tid] = pv;
    __syncthreads();
    for (int d = 1; d < 256; d <<= 1) {
        int t2 = tid >= d ? sd[tid - d] : 0;
        __syncthreads();
        sd[tid] += t2;
        __syncthreads();
    }
    if (i < Nn) {
        int off = sd[tid] - pv + bsum[b];
        rowptr[i] = off;
        cursor[i] = off;
        uint4 sink = make_uint4(0u, sink_woff, 0u, 0u);
        for (int j = v; j < pv; ++j) csr[off + j] = sink;
        if (i == Nn - 1) {
            rowptr[Nn] = off + pv;
            for (int q = 0; q < 8; ++q) csr[off + pv + q] = sink;   // global pad
        }
    }
}

// K5: layer-0 fused 6-mat MFMA | scatter (interleaved; both ready after K4/K4b)
__global__ __launch_bounds__(256)
void k5_mfma_scatter(const unsigned short* hb, const unsigned short* Wt,
                     const float* biasbuf, unsigned short* Xb, unsigned short* Yb,
                     int M, int nmats, int nF,
                     const int* __restrict__ ei, const int* __restrict__ et,
                     const float* __restrict__ dis, int* __restrict__ cursor,
                     uint4* __restrict__ csr, int E, int Nn, int nS)
{
    const int minv = nF < nS ? nF : nS;
    int bid = blockIdx.x;
    int fIdx = -1, sIdx = -1;
    if (bid < 2 * minv) {
        if (bid & 1) fIdx = bid >> 1; else sIdx = bid >> 1;
    } else {
        int rem = bid - 2 * minv;
        if (nF > nS) fIdx = minv + rem; else sIdx = minv + rem;
    }
    if (sIdx >= 0) {
        int e = sIdx * 256 + threadIdx.x;
        if (e < E) {
            int dst = ei[e];
            int src = ei[E + e];
            int pos = atomicAdd(&cursor[dst], 1);
            float nrm = dis[dst] * dis[src];
            csr[pos] = make_uint4((unsigned)(src * 64),
                                  (unsigned)((et[e] * Nn + src) * 64),
                                  __float_as_uint(nrm), 0u);
        }
        return;
    }
    fused_dispatch(hb, Wt, biasbuf, Xb, Yb, 0, M, nmats, fIdx);
}

// fused 6-mat MFMA pass (generic base, layer 1)
__global__ __launch_bounds__(256)
void k_fusedpass(const unsigned short* A, const unsigned short* Wt, const float* biasbuf,
                 unsigned short* Xb, unsigned short* Yb, int base, int M, int nmats)
{
    fused_dispatch(A, Wt, biasbuf, Xb, Yb, base, M, nmats, blockIdx.x);
}

// final: out[row] = gelu(msg_dense[row] @ cout1 + b), f32, dense Mo rows
__global__ __launch_bounds__(256)
void k_cout_gelu(const unsigned short* __restrict__ A, const unsigned short* Wt,
                 const float* biasbuf, float* __restrict__ out, int mat, int M)
{
    const unsigned short* Wmat = Wt + (size_t)mat * 16384;
    const float* bias = biasbuf + (size_t)mat * 128;

    __shared__ unsigned short Bs[16384];
    const int tid = threadIdx.x;
#pragma unroll
    for (int i = 0; i < 8; ++i) {
        int idx = tid + i * 256;
        uint4 v = *reinterpret_cast<const uint4*>(Wmat + (size_t)idx * 8);
        int row = idx >> 4;
        int j = idx & 15;
        int byte = row * 256 + ((j ^ (row & 15)) << 4);
        *reinterpret_cast<uint4*>(reinterpret_cast<char*>(Bs) + byte) = v;
    }
    __syncthreads();

    const int wave = tid >> 6;
    const int lane = tid & 63;
    const int grp = lane >> 4;
    const int l16 = lane & 15;
    const int row0 = blockIdx.x * 128 + wave * 32;

    f32x4 acc[2][8] = {};
#pragma unroll
    for (int kt = 0; kt < 4; ++kt) {
        const int k0 = kt * 32 + grp * 8;
        short8v a[2];
#pragma unroll
        for (int m = 0; m < 2; ++m) {
            int r = row0 + 16 * m + l16;
            if (r > M - 1) r = M - 1;
            a[m] = *reinterpret_cast<const short8v*>(A + (size_t)r * 128 + k0);
        }
        const int joff = kt * 4 + grp;
#pragma unroll
        for (int n = 0; n < 8; ++n) {
            int brow = 16 * n + l16;
            int byte = brow * 256 + ((joff ^ (brow & 15)) << 4);
            short8v b = *reinterpret_cast<const short8v*>(
                reinterpret_cast<const char*>(Bs) + byte);
            acc[0][n] = __builtin_amdgcn_mfma_f32_16x16x32_bf16(b, a[0], acc[0][n], 0, 0, 0);
            acc[1][n] = __builtin_amdgcn_mfma_f32_16x16x32_bf16(b, a[1], acc[1][n], 0, 0, 0);
        }
    }

    const float kg = 0.7071067811865475f;
#pragma unroll
    for (int m = 0; m < 2; ++m) {
        int row = row0 + 16 * m + l16;
        if (row >= M) continue;
        float4 bb;
#pragma unroll
        for (int n = 0; n < 8; ++n) {
            bb = *reinterpret_cast<const float4*>(bias + 16 * n + grp * 4);
            float v0 = acc[m][n][0] + bb.x;
            float v1 = acc[m][n][1] + bb.y;
            float v2 = acc[m][n][2] + bb.z;
            float v3 = acc[m][n][3] + bb.w;
            v0 = 0.5f * v0 * (1.f + erff(v0 * kg));
            v1 = 0.5f * v1 * (1.f + erff(v1 * kg));
            v2 = 0.5f * v2 * (1.f + erff(v2 * kg));
            v3 = 0.5f * v3 * (1.f + erff(v3 * kg));
            *reinterpret_cast<float4*>(out + (size_t)row * 128 + 16 * n + grp * 4) =
                make_float4(v0, v1, v2, v3);
        }
    }
}

// ---- fused per-node gather: gcn-sum + scatter-softmax + combine ----
// Mask-free (sink-padded CSR). Optional idxmap: gid -> node (layer-1 only needs
// the idx destination nodes); output row = gid (dense). Duplicate idx entries
// write distinct rows -> no races.
__global__ __launch_bounds__(256)
void node_gather(const int* __restrict__ rowptr, const uint4* __restrict__ csr,
                 const unsigned* __restrict__ Xw, const unsigned* __restrict__ Yw,
                 unsigned short* __restrict__ outb,
                 const int* __restrict__ idxmap, int count)
{
    int gid = blockIdx.x * 4 + (threadIdx.x >> 6);
    if (gid >= count) return;
    int node = idxmap ? idxmap[gid] : gid;
    int lane = threadIdx.x & 63;

    int i = rowptr[node];
    const int end = rowptr[node + 1];

    float mg0 = 0.f, mg1 = 0.f, s0 = 0.f, s1 = 0.f, t0 = 0.f, t1 = 0.f;

    if (i < end) {
        uint4 cur[4];
#pragma unroll
        for (int q = 0; q < 4; ++q) cur[q] = csr[i + q];

        for (; i < end; i += 4) {
            uint4 nxt[4];
#pragma unroll
            for (int q = 0; q < 4; ++q) nxt[q] = csr[i + 4 + q];   // global pad covers

            unsigned xp[4], yp[4];
#pragma unroll
            for (int q = 0; q < 4; ++q) {
                xp[q] = Xw[cur[q].x + lane];
                yp[q] = Yw[cur[q].y + lane];
            }
#pragma unroll
            for (int q = 0; q < 4; ++q) {
                float nrm = __uint_as_float(cur[q].z);
                float x0 = bf2f((unsigned short)(xp[q] & 0xffffu));
                float x1 = bf2f((unsigned short)(xp[q] >> 16));
                float y0 = bf2f((unsigned short)(yp[q] & 0xffffu));
                float y1 = bf2f((unsigned short)(yp[q] >> 16));
                float w0 = __expf(y0), w1 = __expf(y1);
                mg0 = fmaf(x0, nrm, mg0);
                mg1 = fmaf(x1, nrm, mg1);
                s0 += w0; s1 += w1;
                t0 = fmaf(y0, w0, t0);
                t1 = fmaf(y1, w1, t1);
            }
#pragma unroll
            for (int q = 0; q < 4; ++q) cur[q] = nxt[q];
        }
    }

    float o0 = mg0 + 0.1f * fmaxf(s0 > 0.f ? t0 / s0 : 0.f, 0.f);
    float o1 = mg1 + 0.1f * fmaxf(s1 > 0.f ? t1 / s1 : 0.f, 0.f);
    unsigned pk = (unsigned)f2bf(o0) | ((unsigned)f2bf(o1) << 16);
    *reinterpret_cast<unsigned*>(outb + (size_t)gid * 128 + (lane << 1)) = pk;
}

// ================= launch =================
extern "C" void kernel_launch(void* const* d_in, const int* in_sizes, int n_in,
                              void* d_out, int out_size, void* d_ws, size_t ws_size,
                              hipStream_t stream)
{
    const float* x      = (const float*)d_in[0];
    const int*   ei     = (const int*)d_in[1];
    const int*   et     = (const int*)d_in[2];
    // d_in[3] edge_weight: unused by the reference
    const int*   idxp   = (const int*)d_in[4];
    const float* proj_w = (const float*)d_in[5];
    const float* proj_b = (const float*)d_in[6];
    const float* bn_g   = (const float*)d_in[7];
    const float* bn_b   = (const float*)d_in[8];
    const float* win_w[2]  = {(const float*)d_in[9],  (const float*)d_in[14]};
    const float* win_b[2]  = {(const float*)d_in[10], (const float*)d_in[15]};
    const float* wrel[2]   = {(const float*)d_in[11], (const float*)d_in[16]};
    const float* cout_w[2] = {(const float*)d_in[12], (const float*)d_in[17]};
    const float* cout_b[2] = {(const float*)d_in[13], (const float*)d_in[18]};

    const int Nn  = in_sizes[0] / 128;
    const int E   = in_sizes[1] / 2;
    const int Mo  = in_sizes[4];
    const int nrel = in_sizes[11] / (128 * 128);
    const size_t ND = (size_t)Nn * 128;

    const int HALFR = ((Nn + 3) / 4) * 2;
    const int WORDS = HALFR / 2;
    if (WORDS > HIST_MAXW) return;

    const int IA1 = 1 + nrel;
    const int IC1 = 2 + 2 * nrel;
    const int NMATS = 3 + 2 * nrel;

    // workspace layout
    char* p = (char*)d_ws;
    float* h    = (float*)p;                  p += ND * 4;
    unsigned short* hb = (unsigned short*)p;  p += ND * 2;
    unsigned short* Xb = (unsigned short*)p;  p += ND * 2;
    unsigned short* Yb = (unsigned short*)p;  p += (size_t)nrel * ND * 2 + 256;  // +sink row
    unsigned short* msgb = (unsigned short*)p; p += ND * 2;
    unsigned short* Wt = (unsigned short*)p;  p += (size_t)NMATS * 16384 * 2;
    float* WfA1 = (float*)p;                  p += (size_t)16384 * 4;
    float* biasbuf = (float*)p;               p += (size_t)NMATS * 128 * 4;
    uint4* csr  = (uint4*)p;                  p += ((size_t)E + 3 * (size_t)Nn + 16) * 16;
    unsigned* partial = (unsigned*)p;         p += (size_t)HIST_B * WORDS * 4;
    float* dis  = (float*)p;                  p += (size_t)Nn * 4;
    int*   cnt  = (int*)p;                    p += (size_t)Nn * 4;
    int*   rowptr = (int*)p;                  p += ((size_t)Nn + 1) * 4;
    int*   cursor = (int*)p;                  p += (size_t)Nn * 4;
    int*   bsum = (int*)p;                    p += 1024 * 4;
    float* bnsums = (float*)p;                p += 256 * 4;
    float* bnsc   = (float*)p;                p += 256 * 4;
    if ((size_t)(p - (char*)d_ws) > ws_size) return;

    const unsigned sink_woff = (unsigned)((size_t)nrel * Nn * 64);   // word offset in Yb

    const int gemmGrid = (Nn + 63) / 64;
    const int tiles128 = (Nn + 127) / 128;
    const size_t n4 = ND / 4;
    const int n4grid = (int)((n4 + 255) / 256);
    const int nb = (Nn + 255) / 256;
    const int nRed = (4 * WORDS + 255) / 256;
    const int nS = (E + 255) / 256;
    const int nmats = 1 + nrel;
    const int nFused = nmats * tiles128;

    hipMemsetAsync(bnsums, 0, 256 * 4, stream);

    // weight preprocessing
    kprod1<<<2 * (1 + nrel) + (1 + nrel) + 3, 256, 0, stream>>>(
        win_w[0], win_b[0], win_w[1], win_b[1], cout_w[0], cout_b[0],
        cout_w[1], cout_b[1], wrel[0], WfA1, Wt, biasbuf, nrel);
    kprod2<<<2 * nrel + nrel, 256, 0, stream>>>(wrel[1], WfA1, Wt, biasbuf, nrel);

    // histogram, proj GEMM
    hist_kernel<<<HIST_B, 256, 0, stream>>>(ei, partial, Nn, E, WORDS, HALFR);
    proj_kernel<<<gemmGrid, 256, 0, stream>>>(x, proj_w, proj_b, h, Nn);

    // K2: hist reduce (dis, cnt) | bn_stats
    k2_reduce_bnstats<<<nRed + 256, 256, 0, stream>>>(
        partial, dis, cnt, h, bnsums, Nn, WORDS, HALFR, nRed);

    // K3: bn_finalize | scan level-1 (padded counts)
    k3_bnfin_scan1<<<1 + nb, 256, 0, stream>>>(bnsums, bn_g, bn_b, bnsc, cnt, bsum, Nn);

    // K4: scan offsets | bn apply+relu -> hb
    k4_scanoff_bnapply<<<1 + n4grid, 256, 0, stream>>>(bsum, nb, h, bnsc, hb, n4);

    // K4b: scan final (padded rowptr/cursor) + sink pads + sink row
    k4b_scanfinal<<<nb + 1, 256, 0, stream>>>(cnt, bsum, rowptr, cursor, csr,
                                              (unsigned*)Yb, sink_woff, Nn, nb);

    // K5: layer-0 fused 6-mat MFMA | scatter (interleaved)
    k5_mfma_scatter<<<nFused + nS, 256, 0, stream>>>(
        hb, Wt, biasbuf, Xb, Yb, Nn, nmats, nFused,
        ei, et, dis, cursor, csr, E, Nn, nS);

    // layer 0 gather (all nodes)
    node_gather<<<(Nn + 3) / 4, 256, 0, stream>>>(
        rowptr, csr, (const unsigned*)Xb, (const unsigned*)Yb, msgb, nullptr, Nn);

    // layer-1 fused 6-mat pass (all nodes; srcs of idx-edges can be anywhere)
    k_fusedpass<<<nFused, 256, 0, stream>>>(msgb, Wt, biasbuf, Xb, Yb, IA1, Nn, nmats);

    // layer 1 gather: ONLY the idx destination nodes (dense Mo-row output)
    node_gather<<<(Mo + 3) / 4, 256, 0, stream>>>(
        rowptr, csr, (const unsigned*)Xb, (const unsigned*)Yb, msgb, idxp, Mo);

    // final: cout1 + gelu on dense Mo rows -> d_out
    k_cout_gelu<<<(Mo + 127) / 128, 256, 0, stream>>>(
        msgb, Wt, biasbuf, (float*)d_out, IC1, Mo);
}

// Round 13
// 329.349 us; speedup vs baseline: 1.2535x; 1.2535x over previous
//
#include <hip/hip_runtime.h>

#define HIST_BPG 32              // edge-slice blocks per (histogram, half) group
#define HIST_B   (HIST_BPG * 4)  // 4 groups: src-lo, src-hi, dst-lo, dst-hi
#define HIST_MAXW 12288          // max packed words (supports Nn <= ~49k)

// ---------- helpers ----------
__device__ inline float bf2f(unsigned short u) {
    return __uint_as_float(((unsigned)u) << 16);
}
__device__ inline unsigned short f2bf(float f) {
    unsigned u = __float_as_uint(f);
    u += 0x7fffu + ((u >> 16) & 1u);   // round-to-nearest-even
    return (unsigned short)(u >> 16);
}

typedef __attribute__((ext_vector_type(8))) short short8v;   // 8 bf16 (4 VGPRs)
typedef __attribute__((ext_vector_type(4))) float f32x4;

// ================= device bodies =================

// ---- f32 GEMM body (64-row tile): C[M x 128] = A @ W (+ bias) ----
// Optional outputs: C (f32 [row][col]) and Ct (bf16 TRANSPOSED [col][row]).
// __shared__ declared DIRECTLY here (char*-cast LDS caused 256-VGPR spill, r7-8).
__device__ __forceinline__
void gemmf32_body(const float* __restrict__ A, const float* __restrict__ W,
                  const float* __restrict__ bias, float* __restrict__ C,
                  unsigned short* __restrict__ Ct, int M, int tile)
{
    __shared__ float As[64][132];
    __shared__ float Ws[32][128];

    const int tid = threadIdx.x;
    const int row0 = tile * 64;

#pragma unroll
    for (int i = 0; i < 8; ++i) {
        int idx = tid + i * 256;
        int rr = idx >> 5;
        int cc = (idx & 31) << 2;
        int gr = row0 + rr;
        float4 v = make_float4(0.f, 0.f, 0.f, 0.f);
        if (gr < M) v = *reinterpret_cast<const float4*>(A + (size_t)gr * 128 + cc);
        *reinterpret_cast<float4*>(&As[rr][cc]) = v;
    }

    const int tx = tid & 15;
    const int ty = tid >> 4;
    float acc[4][8];
#pragma unroll
    for (int i = 0; i < 4; ++i)
#pragma unroll
        for (int j = 0; j < 8; ++j) acc[i][j] = 0.f;

    for (int kt = 0; kt < 4; ++kt) {
        __syncthreads();
#pragma unroll
        for (int i = 0; i < 4; ++i) {
            int idx = tid + i * 256;
            int rr = idx >> 5;
            int cc = (idx & 31) << 2;
            *reinterpret_cast<float4*>(&Ws[rr][cc]) =
                *reinterpret_cast<const float4*>(W + (size_t)(kt * 32 + rr) * 128 + cc);
        }
        __syncthreads();
#pragma unroll
        for (int kk = 0; kk < 32; ++kk) {
            const int k = kt * 32 + kk;
            float a0 = As[ty * 4 + 0][k];
            float a1 = As[ty * 4 + 1][k];
            float a2 = As[ty * 4 + 2][k];
            float a3 = As[ty * 4 + 3][k];
            float w[8];
#pragma unroll
            for (int j = 0; j < 8; ++j) w[j] = Ws[kk][tx + 16 * j];
#pragma unroll
            for (int j = 0; j < 8; ++j) {
                acc[0][j] = fmaf(a0, w[j], acc[0][j]);
                acc[1][j] = fmaf(a1, w[j], acc[1][j]);
                acc[2][j] = fmaf(a2, w[j], acc[2][j]);
                acc[3][j] = fmaf(a3, w[j], acc[3][j]);
            }
        }
    }

    float bb[8];
#pragma unroll
    for (int j = 0; j < 8; ++j) bb[j] = bias ? bias[tx + 16 * j] : 0.f;

#pragma unroll
    for (int i = 0; i < 4; ++i) {
        int gr = row0 + ty * 4 + i;
        if (gr >= M) continue;
#pragma unroll
        for (int j = 0; j < 8; ++j) {
            float v = acc[i][j] + bb[j];
            if (C)  C[(size_t)gr * 128 + tx + 16 * j] = v;
            if (Ct) Ct[(size_t)(tx + 16 * j) * 128 + gr] = f2bf(v);
        }
    }
}

// ---- MFMA GEMM body (operand-swapped), LDS-staged B, 16 rows/wave ----
// ROUND-11 VERIFIED FORM (52 VGPR). Do NOT widen to 32 rows/wave: acc[2][8]
// pushed VGPR to 172 (round 12), collapsing occupancy and the fused scatter.
// Block = 4 waves, 64-row tile x 128 cols. Wmat is bf16 [n][k] (16384).
// B staged in LDS with XOR swizzle: chunk (row, j) at row*256 + ((j^(row&15))<<4).
__device__ __forceinline__
void mfma64_body(const unsigned short* __restrict__ A,
                 const unsigned short* __restrict__ Wmat,
                 const float* __restrict__ bias,
                 float* __restrict__ Cf, unsigned short* __restrict__ Cb,
                 int M, int tile)
{
    __shared__ unsigned short Bs[16384];   // 32 KB

    const int tid = threadIdx.x;
#pragma unroll
    for (int i = 0; i < 8; ++i) {
        int idx = tid + i * 256;                 // 16B chunk id, 0..2047
        uint4 v = *reinterpret_cast<const uint4*>(Wmat + (size_t)idx * 8);
        int row = idx >> 4;
        int j = idx & 15;
        int byte = row * 256 + ((j ^ (row & 15)) << 4);
        *reinterpret_cast<uint4*>(reinterpret_cast<char*>(Bs) + byte) = v;
    }
    __syncthreads();

    const int wave = tid >> 6;
    const int lane = tid & 63;
    const int grp = lane >> 4;
    const int l16 = lane & 15;
    const int row = tile * 64 + wave * 16 + l16;
    const int rc = row < M ? row : M - 1;        // clamp; tail rows not stored

    f32x4 acc[8] = {};
#pragma unroll
    for (int kt = 0; kt < 4; ++kt) {
        const int k0 = kt * 32 + grp * 8;
        short8v a = *reinterpret_cast<const short8v*>(A + (size_t)rc * 128 + k0);
        const int joff = kt * 4 + grp;           // k-chunk index 0..15
#pragma unroll
        for (int n = 0; n < 8; ++n) {
            int brow = 16 * n + l16;
            int byte = brow * 256 + ((joff ^ (brow & 15)) << 4);
            short8v b = *reinterpret_cast<const short8v*>(
                reinterpret_cast<const char*>(Bs) + byte);
            acc[n] = __builtin_amdgcn_mfma_f32_16x16x32_bf16(b, a, acc[n], 0, 0, 0);
        }
    }

    if (row >= M) return;   // no barriers past this point

    float4 bb[8];
#pragma unroll
    for (int n = 0; n < 8; ++n)
        bb[n] = bias ? *reinterpret_cast<const float4*>(bias + 16 * n + grp * 4)
                     : make_float4(0.f, 0.f, 0.f, 0.f);

#pragma unroll
    for (int n = 0; n < 8; ++n) {
        float v0 = acc[n][0] + bb[n].x;
        float v1 = acc[n][1] + bb[n].y;
        float v2 = acc[n][2] + bb[n].z;
        float v3 = acc[n][3] + bb[n].w;
        if (Cf) {
            *reinterpret_cast<float4*>(Cf + (size_t)row * 128 + 16 * n + grp * 4) =
                make_float4(v0, v1, v2, v3);
        }
        if (Cb) {
            unsigned u0 = (unsigned)f2bf(v0) | ((unsigned)f2bf(v1) << 16);
            unsigned u1 = (unsigned)f2bf(v2) | ((unsigned)f2bf(v3) << 16);
            *reinterpret_cast<uint2*>(Cb + (size_t)row * 128 + 16 * n + grp * 4) =
                make_uint2(u0, u1);
        }
    }
}

// fused 6-mat pass dispatch (tile-major: consecutive blocks share A rows in L2)
__device__ void fused_dispatch(const unsigned short* A, const unsigned short* Wt,
                               const float* biasbuf, unsigned short* Xb,
                               unsigned short* Yb, int base, int M, int nmats, int bid)
{
    int m = bid % nmats;
    int tile = bid / nmats;
    unsigned short* out = (m == 0) ? Xb : Yb + (size_t)(m - 1) * (size_t)M * 128;
    mfma64_body(A, Wt + (size_t)(base + m) * 16384,
                biasbuf + (size_t)(base + m) * 128, nullptr, out, M, tile);
}

// ---- bias product body: out[t] = sum_j v[j]*W[j*128+t] (+ add[t]) ----
__device__ void biasprod_body(const float* __restrict__ v, const float* __restrict__ W,
                              const float* __restrict__ add, float* __restrict__ out)
{
    int t = threadIdx.x;
    if (t >= 128) return;
    float s = add ? add[t] : 0.f;
    for (int j = 0; j < 128; ++j) s = fmaf(v[j], W[(size_t)j * 128 + t], s);
    out[t] = s;
}

// ---- bf16-transpose convert body: Wt[mat] <- f32 W[k][n] ----
__device__ void wtconv_body(const float* __restrict__ W, unsigned short* __restrict__ O)
{
    for (int i = threadIdx.x; i < 16384; i += 256) {
        int k = i >> 7, n = i & 127;
        O[(size_t)n * 128 + k] = f2bf(W[i]);
    }
}

// ---- bn stats body ----
__device__ void bn_stats_body(const float* __restrict__ h, float* __restrict__ sums,
                              int Nn, int b)
{
    const int c = threadIdx.x & 127;
    const int half = threadIdx.x >> 7;
    float s = 0.f, q = 0.f;
    for (int row = b * 2 + half; row < Nn; row += 512) {
        float v = h[(size_t)row * 128 + c];
        s += v;
        q += v * v;
    }
    __shared__ float ls[256], lq[256];
    ls[threadIdx.x] = s;
    lq[threadIdx.x] = q;
    __syncthreads();
    if (half == 0) {
        s += ls[threadIdx.x + 128];
        q += lq[threadIdx.x + 128];
        atomicAdd(&sums[c], s);
        atomicAdd(&sums[128 + c], q);
    }
}

// ---- scan bodies (counts padded to multiple of 4 for CSR 4-unroll) ----
__device__ void scan_block_sums_body(const int* __restrict__ cnt, int* __restrict__ bsum,
                                     int Nn, int b)
{
    __shared__ int sd[256];
    int tid = threadIdx.x;
    int i = b * 256 + tid;
    sd[tid] = i < Nn ? ((cnt[i] + 3) & ~3) : 0;
    __syncthreads();
#pragma unroll
    for (int s = 128; s > 0; s >>= 1) {
        if (tid < s) sd[tid] += sd[tid + s];
        __syncthreads();
    }
    if (tid == 0) bsum[b] = sd[0];
}

__device__ void scan_offsets_body(int* __restrict__ bsum, int nb)   // nb <= 256
{
    __shared__ int sd[256];
    int tid = threadIdx.x;
    int v = tid < nb ? bsum[tid] : 0;
    sd[tid] = v;
    __syncthreads();
    for (int d = 1; d < 256; d <<= 1) {
        int t = tid >= d ? sd[tid - d] : 0;
        __syncthreads();
        sd[tid] += t;
        __syncthreads();
    }
    if (tid < nb) bsum[tid] = sd[tid] - v;   // exclusive
}

// ================= kernels =================

// KP1: stage-1 weight products + biases + converts.
__global__ __launch_bounds__(256)
void kprod1(const float* win0w, const float* win0b, const float* win1w, const float* win1b,
            const float* cout0w, const float* cout0b, const float* cout1w,
            const float* cout1b, const float* wrel0,
            float* WfA1, unsigned short* Wt, float* biasbuf, int nrel)
{
    const int IA1 = 1 + nrel, IC1 = 2 + 2 * nrel;
    const int nProd = 1 + nrel;
    int bid = blockIdx.x;
    if (bid < 2 * nProd) {
        int p = bid >> 1, tile = bid & 1;
        if (p == 0)
            gemmf32_body(cout0w, win1w, nullptr, WfA1, Wt + (size_t)IA1 * 16384, 128, tile);
        else
            gemmf32_body(win0w, wrel0 + (size_t)(p - 1) * 16384, nullptr,
                         nullptr, Wt + (size_t)p * 16384, 128, tile);
        return;
    }
    bid -= 2 * nProd;
    if (bid < nProd) {
        if (bid == 0) biasprod_body(cout0b, win1w, win1b, biasbuf + (size_t)IA1 * 128);
        else biasprod_body(win0b, wrel0 + (size_t)(bid - 1) * 16384, nullptr,
                           biasbuf + (size_t)bid * 128);
        return;
    }
    bid -= nProd;
    if (bid == 0) { wtconv_body(win0w, Wt); return; }
    if (bid == 1) { wtconv_body(cout1w, Wt + (size_t)IC1 * 16384); return; }
    int t = threadIdx.x;
    if (t < 128) {
        biasbuf[t] = win0b[t];
        biasbuf[(size_t)IC1 * 128 + t] = cout1b[t];
    }
}

// KP2: stage-2 products.
__global__ __launch_bounds__(256)
void kprod2(const float* wrel1, const float* WfA1, unsigned short* Wt,
            float* biasbuf, int nrel)
{
    const int IA1 = 1 + nrel, IB1 = 2 + nrel;
    int bid = blockIdx.x;
    if (bid < 2 * nrel) {
        int p = bid >> 1, tile = bid & 1;
        gemmf32_body(WfA1, wrel1 + (size_t)p * 16384, nullptr,
                     nullptr, Wt + (size_t)(IB1 + p) * 16384, 128, tile);
        return;
    }
    int r = bid - 2 * nrel;
    biasprod_body(biasbuf + (size_t)IA1 * 128, wrel1 + (size_t)r * 16384, nullptr,
                  biasbuf + (size_t)(IB1 + r) * 128);
}

// histogram (standalone, low VGPR, no global atomics)
__global__ __launch_bounds__(256)
void hist_kernel(const int* __restrict__ ei, unsigned* __restrict__ partial,
                 int Nn, int E, int WORDS, int HALFR)
{
    __shared__ unsigned sh[HIST_MAXW];
    const int hbid = blockIdx.x;
    const int g = hbid / HIST_BPG;
    const int j = hbid - g * HIST_BPG;

    for (int w = threadIdx.x; w < WORDS; w += 256) sh[w] = 0;
    __syncthreads();

    const int* col = (g < 2) ? (ei + E) : ei;
    const int base = (g & 1) * HALFR;
    const size_t e0 = (size_t)E * j / HIST_BPG;
    const size_t e1 = (size_t)E * (j + 1) / HIST_BPG;
    for (size_t e = e0 + threadIdx.x; e < e1; e += 256) {
        int n = col[e] - base;
        if ((unsigned)n < (unsigned)HALFR)
            atomicAdd(&sh[n >> 1], 1u << ((n & 1) * 16));
    }
    __syncthreads();

    unsigned* out = partial + (size_t)hbid * WORDS;
    for (int w = threadIdx.x; w < WORDS; w += 256) out[w] = sh[w];
}

// proj f32 GEMM (standalone)
__global__ __launch_bounds__(256)
void proj_kernel(const float* __restrict__ x, const float* __restrict__ W,
                 const float* __restrict__ bias, float* __restrict__ h, int M)
{
    gemmf32_body(x, W, bias, h, nullptr, M, blockIdx.x);
}

// K2: hist-reduce (-> dis, cnt) | bn_stats
__global__ __launch_bounds__(256)
void k2_reduce_bnstats(const unsigned* __restrict__ partial, float* __restrict__ dis,
                       int* __restrict__ cnt, const float* __restrict__ h,
                       float* __restrict__ bnsums, int Nn, int WORDS, int HALFR, int nRed)
{
    int bid = blockIdx.x;
    if (bid < nRed) {
        int t = bid * 256 + threadIdx.x;
        if (t < 4 * WORDS) {
            int histo = t / (2 * WORDS);
            int rem = t - histo * 2 * WORDS;
            int half = rem / WORDS;
            int w = rem - half * WORDS;
            int g = histo * 2 + half;
            unsigned slo = 0, shi = 0;
            const unsigned* p = partial + (size_t)(g * HIST_BPG) * WORDS + w;
#pragma unroll 4
            for (int j = 0; j < HIST_BPG; ++j) {
                unsigned u = p[(size_t)j * WORDS];
                slo += u & 0xffffu;
                shi += u >> 16;
            }
            int n0 = half * HALFR + 2 * w;
            int n1 = n0 + 1;
            if (histo == 0) {
                if (n0 < Nn) dis[n0] = slo ? rsqrtf((float)slo) : 0.f;
                if (n1 < Nn) dis[n1] = shi ? rsqrtf((float)shi) : 0.f;
            } else {
                if (n0 < Nn) cnt[n0] = (int)slo;
                if (n1 < Nn) cnt[n1] = (int)shi;
            }
        }
        return;
    }
    bn_stats_body(h, bnsums, Nn, bid - nRed);
}

// K3: bn_finalize | scan_block_sums (padded)
__global__ __launch_bounds__(256)
void k3_bnfin_scan1(const float* __restrict__ sums, const float* __restrict__ g,
                    const float* __restrict__ b, float* __restrict__ sc,
                    const int* __restrict__ cnt, int* __restrict__ bsum, int Nn)
{
    if (blockIdx.x == 0) {
        int c = threadIdx.x;
        if (c < 128) {
            float inv = 1.f / (float)Nn;
            float mu = sums[c] * inv;
            float var = sums[128 + c] * inv - mu * mu;
            float rstd = rsqrtf(var + 1e-5f);
            float scale = rstd * g[c];
            sc[c] = scale;
            sc[128 + c] = b[c] - mu * scale;
        }
        return;
    }
    scan_block_sums_body(cnt, bsum, Nn, blockIdx.x - 1);
}

// K4: scan_offsets | bn_apply_relu (f32 -> bf16)
__global__ __launch_bounds__(256)
void k4_scanoff_bnapply(int* __restrict__ bsum, int nb,
                        const float* __restrict__ h, const float* __restrict__ sc,
                        unsigned short* __restrict__ hb, size_t n4)
{
    if (blockIdx.x == 0) { scan_offsets_body(bsum, nb); return; }
    size_t i = (size_t)(blockIdx.x - 1) * 256 + threadIdx.x;
    if (i >= n4) return;
    int c = (int)(i & 31) << 2;
    float4 v = reinterpret_cast<const float4*>(h)[i];
    float o0 = fmaxf(fmaf(v.x, sc[c + 0], sc[128 + c + 0]), 0.f);
    float o1 = fmaxf(fmaf(v.y, sc[c + 1], sc[128 + c + 1]), 0.f);
    float o2 = fmaxf(fmaf(v.z, sc[c + 2], sc[128 + c + 2]), 0.f);
    float o3 = fmaxf(fmaf(v.w, sc[c + 3], sc[128 + c + 3]), 0.f);
    ushort4 pk = make_ushort4(f2bf(o0), f2bf(o1), f2bf(o2), f2bf(o3));
    reinterpret_cast<ushort4*>(hb)[i] = pk;
}

// K4b: scan_final with 4-padded offsets; writes rowptr/cursor, sink pad
// entries, 8 global pad entries, and the bf16 -100 sink row in Yw.
__global__ __launch_bounds__(256)
void k4b_scanfinal(const int* __restrict__ cnt, const int* __restrict__ bsum,
                   int* __restrict__ rowptr, int* __restrict__ cursor,
                   uint4* __restrict__ csr, unsigned* __restrict__ Yw,
                   unsigned sink_woff, int Nn, int nb)
{
    if ((int)blockIdx.x == nb) {
        int t = threadIdx.x;
        if (t < 64) Yw[sink_woff + t] = 0xC2C8C2C8u;   // bf16 -100 pair
        return;
    }
    __shared__ int sd[256];
    int tid = threadIdx.x;
    int b = blockIdx.x;
    int i = b * 256 + tid;
    int v = i < Nn ? cnt[i] : 0;
    int pv = (v + 3) & ~3;
    sd[tid] = pv;
    __syncthreads();
    for (int d = 1; d < 256; d <<= 1) {
        int t2 = tid >= d ? sd[tid - d] : 0;
        __syncthreads();
        sd[tid] += t2;
        __syncthreads();
    }
    if (i < Nn) {
        int off = sd[tid] - pv + bsum[b];
        rowptr[i] = off;
        cursor[i] = off;
        uint4 sink = make_uint4(0u, sink_woff, 0u, 0u);
        for (int j = v; j < pv; ++j) csr[off + j] = sink;
        if (i == Nn - 1) {
            rowptr[Nn] = off + pv;
            for (int q = 0; q < 8; ++q) csr[off + pv + q] = sink;   // global pad
        }
    }
}

// K5: layer-0 fused 6-mat MFMA | scatter (interleaved; both ready after K4/K4b)
__global__ __launch_bounds__(256)
void k5_mfma_scatter(const unsigned short* hb, const unsigned short* Wt,
                     const float* biasbuf, unsigned short* Xb, unsigned short* Yb,
                     int M, int nmats, int nF,
                     const int* __restrict__ ei, const int* __restrict__ et,
                     const float* __restrict__ dis, int* __restrict__ cursor,
                     uint4* __restrict__ csr, int E, int Nn, int nS)
{
    const int minv = nF < nS ? nF : nS;
    int bid = blockIdx.x;
    int fIdx = -1, sIdx = -1;
    if (bid < 2 * minv) {
        if (bid & 1) fIdx = bid >> 1; else sIdx = bid >> 1;
    } else {
        int rem = bid - 2 * minv;
        if (nF > nS) fIdx = minv + rem; else sIdx = minv + rem;
    }
    if (sIdx >= 0) {
        int e = sIdx * 256 + threadIdx.x;
        if (e < E) {
            int dst = ei[e];
            int src = ei[E + e];
            int pos = atomicAdd(&cursor[dst], 1);
            float nrm = dis[dst] * dis[src];
            csr[pos] = make_uint4((unsigned)(src * 64),
                                  (unsigned)((et[e] * Nn + src) * 64),
                                  __float_as_uint(nrm), 0u);
        }
        return;
    }
    fused_dispatch(hb, Wt, biasbuf, Xb, Yb, 0, M, nmats, fIdx);
}

// fused 6-mat MFMA pass (generic base, layer 1)
__global__ __launch_bounds__(256)
void k_fusedpass(const unsigned short* A, const unsigned short* Wt, const float* biasbuf,
                 unsigned short* Xb, unsigned short* Yb, int base, int M, int nmats)
{
    fused_dispatch(A, Wt, biasbuf, Xb, Yb, base, M, nmats, blockIdx.x);
}

// final: out[row] = gelu(msg_dense[row] @ cout1 + b), f32, dense M rows
// (mfma64 tiling: 4 waves x 16 rows = 64-row tile, 52-VGPR class)
__global__ __launch_bounds__(256)
void k_cout_gelu(const unsigned short* __restrict__ A, const unsigned short* Wt,
                 const float* biasbuf, float* __restrict__ out, int mat, int M)
{
    const unsigned short* Wmat = Wt + (size_t)mat * 16384;
    const float* bias = biasbuf + (size_t)mat * 128;

    __shared__ unsigned short Bs[16384];
    const int tid = threadIdx.x;
#pragma unroll
    for (int i = 0; i < 8; ++i) {
        int idx = tid + i * 256;
        uint4 v = *reinterpret_cast<const uint4*>(Wmat + (size_t)idx * 8);
        int row = idx >> 4;
        int j = idx & 15;
        int byte = row * 256 + ((j ^ (row & 15)) << 4);
        *reinterpret_cast<uint4*>(reinterpret_cast<char*>(Bs) + byte) = v;
    }
    __syncthreads();

    const int wave = tid >> 6;
    const int lane = tid & 63;
    const int grp = lane >> 4;
    const int l16 = lane & 15;
    const int row = blockIdx.x * 64 + wave * 16 + l16;
    const int rc = row < M ? row : M - 1;

    f32x4 acc[8] = {};
#pragma unroll
    for (int kt = 0; kt < 4; ++kt) {
        const int k0 = kt * 32 + grp * 8;
        short8v a = *reinterpret_cast<const short8v*>(A + (size_t)rc * 128 + k0);
        const int joff = kt * 4 + grp;
#pragma unroll
        for (int n = 0; n < 8; ++n) {
            int brow = 16 * n + l16;
            int byte = brow * 256 + ((joff ^ (brow & 15)) << 4);
            short8v b = *reinterpret_cast<const short8v*>(
                reinterpret_cast<const char*>(Bs) + byte);
            acc[n] = __builtin_amdgcn_mfma_f32_16x16x32_bf16(b, a, acc[n], 0, 0, 0);
        }
    }

    if (row >= M) return;

    const float kg = 0.7071067811865475f;
#pragma unroll
    for (int n = 0; n < 8; ++n) {
        float4 bb = *reinterpret_cast<const float4*>(bias + 16 * n + grp * 4);
        float v0 = acc[n][0] + bb.x;
        float v1 = acc[n][1] + bb.y;
        float v2 = acc[n][2] + bb.z;
        float v3 = acc[n][3] + bb.w;
        v0 = 0.5f * v0 * (1.f + erff(v0 * kg));
        v1 = 0.5f * v1 * (1.f + erff(v1 * kg));
        v2 = 0.5f * v2 * (1.f + erff(v2 * kg));
        v3 = 0.5f * v3 * (1.f + erff(v3 * kg));
        *reinterpret_cast<float4*>(out + (size_t)row * 128 + 16 * n + grp * 4) =
            make_float4(v0, v1, v2, v3);
    }
}

// ---- fused per-node gather: gcn-sum + scatter-softmax + combine ----
// Mask-free (sink-padded CSR). Optional idxmap: gid -> node (layer-1 only needs
// the idx destination nodes); output row = gid (dense). Duplicate idx entries
// write distinct rows -> no races.
__global__ __launch_bounds__(256)
void node_gather(const int* __restrict__ rowptr, const uint4* __restrict__ csr,
                 const unsigned* __restrict__ Xw, const unsigned* __restrict__ Yw,
                 unsigned short* __restrict__ outb,
                 const int* __restrict__ idxmap, int count)
{
    int gid = blockIdx.x * 4 + (threadIdx.x >> 6);
    if (gid >= count) return;
    int node = idxmap ? idxmap[gid] : gid;
    int lane = threadIdx.x & 63;

    int i = rowptr[node];
    const int end = rowptr[node + 1];

    float mg0 = 0.f, mg1 = 0.f, s0 = 0.f, s1 = 0.f, t0 = 0.f, t1 = 0.f;

    if (i < end) {
        uint4 cur[4];
#pragma unroll
        for (int q = 0; q < 4; ++q) cur[q] = csr[i + q];

        for (; i < end; i += 4) {
            uint4 nxt[4];
#pragma unroll
            for (int q = 0; q < 4; ++q) nxt[q] = csr[i + 4 + q];   // global pad covers

            unsigned xp[4], yp[4];
#pragma unroll
            for (int q = 0; q < 4; ++q) {
                xp[q] = Xw[cur[q].x + lane];
                yp[q] = Yw[cur[q].y + lane];
            }
#pragma unroll
            for (int q = 0; q < 4; ++q) {
                float nrm = __uint_as_float(cur[q].z);
                float x0 = bf2f((unsigned short)(xp[q] & 0xffffu));
                float x1 = bf2f((unsigned short)(xp[q] >> 16));
                float y0 = bf2f((unsigned short)(yp[q] & 0xffffu));
                float y1 = bf2f((unsigned short)(yp[q] >> 16));
                float w0 = __expf(y0), w1 = __expf(y1);
                mg0 = fmaf(x0, nrm, mg0);
                mg1 = fmaf(x1, nrm, mg1);
                s0 += w0; s1 += w1;
                t0 = fmaf(y0, w0, t0);
                t1 = fmaf(y1, w1, t1);
            }
#pragma unroll
            for (int q = 0; q < 4; ++q) cur[q] = nxt[q];
        }
    }

    float o0 = mg0 + 0.1f * fmaxf(s0 > 0.f ? t0 / s0 : 0.f, 0.f);
    float o1 = mg1 + 0.1f * fmaxf(s1 > 0.f ? t1 / s1 : 0.f, 0.f);
    unsigned pk = (unsigned)f2bf(o0) | ((unsigned)f2bf(o1) << 16);
    *reinterpret_cast<unsigned*>(outb + (size_t)gid * 128 + (lane << 1)) = pk;
}

// ================= launch =================
extern "C" void kernel_launch(void* const* d_in, const int* in_sizes, int n_in,
                              void* d_out, int out_size, void* d_ws, size_t ws_size,
                              hipStream_t stream)
{
    const float* x      = (const float*)d_in[0];
    const int*   ei     = (const int*)d_in[1];
    const int*   et     = (const int*)d_in[2];
    // d_in[3] edge_weight: unused by the reference
    const int*   idxp   = (const int*)d_in[4];
    const float* proj_w = (const float*)d_in[5];
    const float* proj_b = (const float*)d_in[6];
    const float* bn_g   = (const float*)d_in[7];
    const float* bn_b   = (const float*)d_in[8];
    const float* win_w[2]  = {(const float*)d_in[9],  (const float*)d_in[14]};
    const float* win_b[2]  = {(const float*)d_in[10], (const float*)d_in[15]};
    const float* wrel[2]   = {(const float*)d_in[11], (const float*)d_in[16]};
    const float* cout_w[2] = {(const float*)d_in[12], (const float*)d_in[17]};
    const float* cout_b[2] = {(const float*)d_in[13], (const float*)d_in[18]};

    const int Nn  = in_sizes[0] / 128;
    const int E   = in_sizes[1] / 2;
    const int Mo  = in_sizes[4];
    const int nrel = in_sizes[11] / (128 * 128);
    const size_t ND = (size_t)Nn * 128;

    const int HALFR = ((Nn + 3) / 4) * 2;
    const int WORDS = HALFR / 2;
    if (WORDS > HIST_MAXW) return;

    const int IA1 = 1 + nrel;
    const int IC1 = 2 + 2 * nrel;
    const int NMATS = 3 + 2 * nrel;

    // workspace layout
    char* p = (char*)d_ws;
    float* h    = (float*)p;                  p += ND * 4;
    unsigned short* hb = (unsigned short*)p;  p += ND * 2;
    unsigned short* Xb = (unsigned short*)p;  p += ND * 2;
    unsigned short* Yb = (unsigned short*)p;  p += (size_t)nrel * ND * 2 + 256;  // +sink row
    unsigned short* msgb = (unsigned short*)p; p += ND * 2;
    unsigned short* Wt = (unsigned short*)p;  p += (size_t)NMATS * 16384 * 2;
    float* WfA1 = (float*)p;                  p += (size_t)16384 * 4;
    float* biasbuf = (float*)p;               p += (size_t)NMATS * 128 * 4;
    uint4* csr  = (uint4*)p;                  p += ((size_t)E + 3 * (size_t)Nn + 16) * 16;
    unsigned* partial = (unsigned*)p;         p += (size_t)HIST_B * WORDS * 4;
    float* dis  = (float*)p;                  p += (size_t)Nn * 4;
    int*   cnt  = (int*)p;                    p += (size_t)Nn * 4;
    int*   rowptr = (int*)p;                  p += ((size_t)Nn + 1) * 4;
    int*   cursor = (int*)p;                  p += (size_t)Nn * 4;
    int*   bsum = (int*)p;                    p += 1024 * 4;
    float* bnsums = (float*)p;                p += 256 * 4;
    float* bnsc   = (float*)p;                p += 256 * 4;
    if ((size_t)(p - (char*)d_ws) > ws_size) return;

    const unsigned sink_woff = (unsigned)((size_t)nrel * Nn * 64);   // word offset in Yb

    const int gemmGrid = (Nn + 63) / 64;
    const int tiles64 = (Nn + 63) / 64;
    const size_t n4 = ND / 4;
    const int n4grid = (int)((n4 + 255) / 256);
    const int nb = (Nn + 255) / 256;
    const int nRed = (4 * WORDS + 255) / 256;
    const int nS = (E + 255) / 256;
    const int nmats = 1 + nrel;
    const int nFused = nmats * tiles64;

    hipMemsetAsync(bnsums, 0, 256 * 4, stream);

    // weight preprocessing
    kprod1<<<2 * (1 + nrel) + (1 + nrel) + 3, 256, 0, stream>>>(
        win_w[0], win_b[0], win_w[1], win_b[1], cout_w[0], cout_b[0],
        cout_w[1], cout_b[1], wrel[0], WfA1, Wt, biasbuf, nrel);
    kprod2<<<2 * nrel + nrel, 256, 0, stream>>>(wrel[1], WfA1, Wt, biasbuf, nrel);

    // histogram, proj GEMM
    hist_kernel<<<HIST_B, 256, 0, stream>>>(ei, partial, Nn, E, WORDS, HALFR);
    proj_kernel<<<gemmGrid, 256, 0, stream>>>(x, proj_w, proj_b, h, Nn);

    // K2: hist reduce (dis, cnt) | bn_stats
    k2_reduce_bnstats<<<nRed + 256, 256, 0, stream>>>(
        partial, dis, cnt, h, bnsums, Nn, WORDS, HALFR, nRed);

    // K3: bn_finalize | scan level-1 (padded counts)
    k3_bnfin_scan1<<<1 + nb, 256, 0, stream>>>(bnsums, bn_g, bn_b, bnsc, cnt, bsum, Nn);

    // K4: scan offsets | bn apply+relu -> hb
    k4_scanoff_bnapply<<<1 + n4grid, 256, 0, stream>>>(bsum, nb, h, bnsc, hb, n4);

    // K4b: scan final (padded rowptr/cursor) + sink pads + sink row
    k4b_scanfinal<<<nb + 1, 256, 0, stream>>>(cnt, bsum, rowptr, cursor, csr,
                                              (unsigned*)Yb, sink_woff, Nn, nb);

    // K5: layer-0 fused 6-mat MFMA | scatter (interleaved)
    k5_mfma_scatter<<<nFused + nS, 256, 0, stream>>>(
        hb, Wt, biasbuf, Xb, Yb, Nn, nmats, nFused,
        ei, et, dis, cursor, csr, E, Nn, nS);

    // layer 0 gather (all nodes)
    node_gather<<<(Nn + 3) / 4, 256, 0, stream>>>(
        rowptr, csr, (const unsigned*)Xb, (const unsigned*)Yb, msgb, nullptr, Nn);

    // layer-1 fused 6-mat pass (all nodes; srcs of idx-edges can be anywhere)
    k_fusedpass<<<nFused, 256, 0, stream>>>(msgb, Wt, biasbuf, Xb, Yb, IA1, Nn, nmats);

    // layer 1 gather: ONLY the idx destination nodes (dense Mo-row output)
    node_gather<<<(Mo + 3) / 4, 256, 0, stream>>>(
        rowptr, csr, (const unsigned*)Xb, (const unsigned*)Yb, msgb, idxp, Mo);

    // final: cout1 + gelu on dense Mo rows -> d_out
    k_cout_gelu<<<(Mo + 63) / 64, 256, 0, stream>>>(
        msgb, Wt, biasbuf, (float*)d_out, IC1, Mo);
}

// Round 14
// 311.540 us; speedup vs baseline: 1.3252x; 1.0572x over previous
//
#include <hip/hip_runtime.h>

#define HIST_BPG 32              // edge-slice blocks per (histogram, half) group
#define HIST_B   (HIST_BPG * 4)  // 4 groups: src-lo, src-hi, dst-lo, dst-hi
#define HIST_MAXW 12288          // max packed words (supports Nn <= ~49k)

// ---------- helpers ----------
__device__ inline float bf2f(unsigned short u) {
    return __uint_as_float(((unsigned)u) << 16);
}
__device__ inline unsigned short f2bf(float f) {
    unsigned u = __float_as_uint(f);
    u += 0x7fffu + ((u >> 16) & 1u);   // round-to-nearest-even
    return (unsigned short)(u >> 16);
}

typedef __attribute__((ext_vector_type(8))) short short8v;   // 8 bf16 (4 VGPRs)
typedef __attribute__((ext_vector_type(4))) float f32x4;

// ================= device bodies =================

// ---- f32 GEMM body (64-row tile, 256 threads): C[M x 128] = A @ W (+ bias) ----
// Optional outputs: C (f32 [row][col]) and Ct (bf16 TRANSPOSED [col][row]).
// __shared__ declared DIRECTLY here (char*-cast LDS caused 256-VGPR spill, r7-8).
__device__ __forceinline__
void gemmf32_body(const float* __restrict__ A, const float* __restrict__ W,
                  const float* __restrict__ bias, float* __restrict__ C,
                  unsigned short* __restrict__ Ct, int M, int tile)
{
    __shared__ float As[64][132];
    __shared__ float Ws[32][128];

    const int tid = threadIdx.x;
    const int row0 = tile * 64;

#pragma unroll
    for (int i = 0; i < 8; ++i) {
        int idx = tid + i * 256;
        int rr = idx >> 5;
        int cc = (idx & 31) << 2;
        int gr = row0 + rr;
        float4 v = make_float4(0.f, 0.f, 0.f, 0.f);
        if (gr < M) v = *reinterpret_cast<const float4*>(A + (size_t)gr * 128 + cc);
        *reinterpret_cast<float4*>(&As[rr][cc]) = v;
    }

    const int tx = tid & 15;
    const int ty = tid >> 4;
    float acc[4][8];
#pragma unroll
    for (int i = 0; i < 4; ++i)
#pragma unroll
        for (int j = 0; j < 8; ++j) acc[i][j] = 0.f;

    for (int kt = 0; kt < 4; ++kt) {
        __syncthreads();
#pragma unroll
        for (int i = 0; i < 4; ++i) {
            int idx = tid + i * 256;
            int rr = idx >> 5;
            int cc = (idx & 31) << 2;
            *reinterpret_cast<float4*>(&Ws[rr][cc]) =
                *reinterpret_cast<const float4*>(W + (size_t)(kt * 32 + rr) * 128 + cc);
        }
        __syncthreads();
#pragma unroll
        for (int kk = 0; kk < 32; ++kk) {
            const int k = kt * 32 + kk;
            float a0 = As[ty * 4 + 0][k];
            float a1 = As[ty * 4 + 1][k];
            float a2 = As[ty * 4 + 2][k];
            float a3 = As[ty * 4 + 3][k];
            float w[8];
#pragma unroll
            for (int j = 0; j < 8; ++j) w[j] = Ws[kk][tx + 16 * j];
#pragma unroll
            for (int j = 0; j < 8; ++j) {
                acc[0][j] = fmaf(a0, w[j], acc[0][j]);
                acc[1][j] = fmaf(a1, w[j], acc[1][j]);
                acc[2][j] = fmaf(a2, w[j], acc[2][j]);
                acc[3][j] = fmaf(a3, w[j], acc[3][j]);
            }
        }
    }

    float bb[8];
#pragma unroll
    for (int j = 0; j < 8; ++j) bb[j] = bias ? bias[tx + 16 * j] : 0.f;

#pragma unroll
    for (int i = 0; i < 4; ++i) {
        int gr = row0 + ty * 4 + i;
        if (gr >= M) continue;
#pragma unroll
        for (int j = 0; j < 8; ++j) {
            float v = acc[i][j] + bb[j];
            if (C)  C[(size_t)gr * 128 + tx + 16 * j] = v;
            if (Ct) Ct[(size_t)(tx + 16 * j) * 128 + gr] = f2bf(v);
        }
    }
}

// ---- MFMA GEMM body (operand-swapped), LDS-staged B, 512 THREADS ----
// 8 waves x 16 rows = 128-row tile. Per-wave footprint identical to the
// verified 52-VGPR mfma64 form (acc[8], one A frag) -- do NOT widen acc.
// 32KB LDS + 512 thr -> 4 blocks/CU = 32/32 waves (vs 20/32 at 256 thr).
__device__ __forceinline__
void mfmaw_body(const unsigned short* __restrict__ A,
                const unsigned short* __restrict__ Wmat,
                const float* __restrict__ bias,
                float* __restrict__ Cf, unsigned short* __restrict__ Cb,
                int M, int tile)
{
    __shared__ unsigned short Bs[16384];   // 32 KB

    const int tid = threadIdx.x;
#pragma unroll
    for (int i = 0; i < 4; ++i) {
        int idx = tid + i * 512;                 // 16B chunk id, 0..2047
        uint4 v = *reinterpret_cast<const uint4*>(Wmat + (size_t)idx * 8);
        int row = idx >> 4;
        int j = idx & 15;
        int byte = row * 256 + ((j ^ (row & 15)) << 4);
        *reinterpret_cast<uint4*>(reinterpret_cast<char*>(Bs) + byte) = v;
    }
    __syncthreads();

    const int wave = tid >> 6;                   // 0..7
    const int lane = tid & 63;
    const int grp = lane >> 4;
    const int l16 = lane & 15;
    const int row = tile * 128 + wave * 16 + l16;
    const int rc = row < M ? row : M - 1;        // clamp; tail rows not stored

    f32x4 acc[8] = {};
#pragma unroll
    for (int kt = 0; kt < 4; ++kt) {
        const int k0 = kt * 32 + grp * 8;
        short8v a = *reinterpret_cast<const short8v*>(A + (size_t)rc * 128 + k0);
        const int joff = kt * 4 + grp;           // k-chunk index 0..15
#pragma unroll
        for (int n = 0; n < 8; ++n) {
            int brow = 16 * n + l16;
            int byte = brow * 256 + ((joff ^ (brow & 15)) << 4);
            short8v b = *reinterpret_cast<const short8v*>(
                reinterpret_cast<const char*>(Bs) + byte);
            acc[n] = __builtin_amdgcn_mfma_f32_16x16x32_bf16(b, a, acc[n], 0, 0, 0);
        }
    }

    if (row >= M) return;   // no barriers past this point

    float4 bb[8];
#pragma unroll
    for (int n = 0; n < 8; ++n)
        bb[n] = bias ? *reinterpret_cast<const float4*>(bias + 16 * n + grp * 4)
                     : make_float4(0.f, 0.f, 0.f, 0.f);

#pragma unroll
    for (int n = 0; n < 8; ++n) {
        float v0 = acc[n][0] + bb[n].x;
        float v1 = acc[n][1] + bb[n].y;
        float v2 = acc[n][2] + bb[n].z;
        float v3 = acc[n][3] + bb[n].w;
        if (Cf) {
            *reinterpret_cast<float4*>(Cf + (size_t)row * 128 + 16 * n + grp * 4) =
                make_float4(v0, v1, v2, v3);
        }
        if (Cb) {
            unsigned u0 = (unsigned)f2bf(v0) | ((unsigned)f2bf(v1) << 16);
            unsigned u1 = (unsigned)f2bf(v2) | ((unsigned)f2bf(v3) << 16);
            *reinterpret_cast<uint2*>(Cb + (size_t)row * 128 + 16 * n + grp * 4) =
                make_uint2(u0, u1);
        }
    }
}

// fused 6-mat pass dispatch (tile-major: consecutive blocks share A rows in L2)
__device__ void fused_dispatch(const unsigned short* A, const unsigned short* Wt,
                               const float* biasbuf, unsigned short* Xb,
                               unsigned short* Yb, int base, int M, int nmats, int bid)
{
    int m = bid % nmats;
    int tile = bid / nmats;
    unsigned short* out = (m == 0) ? Xb : Yb + (size_t)(m - 1) * (size_t)M * 128;
    mfmaw_body(A, Wt + (size_t)(base + m) * 16384,
               biasbuf + (size_t)(base + m) * 128, nullptr, out, M, tile);
}

// ---- bias product body: out[t] = sum_j v[j]*W[j*128+t] (+ add[t]) ----
__device__ void biasprod_body(const float* __restrict__ v, const float* __restrict__ W,
                              const float* __restrict__ add, float* __restrict__ out)
{
    int t = threadIdx.x;
    if (t >= 128) return;
    float s = add ? add[t] : 0.f;
    for (int j = 0; j < 128; ++j) s = fmaf(v[j], W[(size_t)j * 128 + t], s);
    out[t] = s;
}

// ---- bf16-transpose convert body: Wt[mat] <- f32 W[k][n] ----
__device__ void wtconv_body(const float* __restrict__ W, unsigned short* __restrict__ O)
{
    for (int i = threadIdx.x; i < 16384; i += 256) {
        int k = i >> 7, n = i & 127;
        O[(size_t)n * 128 + k] = f2bf(W[i]);
    }
}

// ---- bn stats body ----
__device__ void bn_stats_body(const float* __restrict__ h, float* __restrict__ sums,
                              int Nn, int b)
{
    const int c = threadIdx.x & 127;
    const int half = threadIdx.x >> 7;
    float s = 0.f, q = 0.f;
    for (int row = b * 2 + half; row < Nn; row += 512) {
        float v = h[(size_t)row * 128 + c];
        s += v;
        q += v * v;
    }
    __shared__ float ls[256], lq[256];
    ls[threadIdx.x] = s;
    lq[threadIdx.x] = q;
    __syncthreads();
    if (half == 0) {
        s += ls[threadIdx.x + 128];
        q += lq[threadIdx.x + 128];
        atomicAdd(&sums[c], s);
        atomicAdd(&sums[128 + c], q);
    }
}

// ---- scan bodies (counts padded to multiple of 4 for CSR 4-unroll) ----
__device__ void scan_block_sums_body(const int* __restrict__ cnt, int* __restrict__ bsum,
                                     int Nn, int b)
{
    __shared__ int sd[256];
    int tid = threadIdx.x;
    int i = b * 256 + tid;
    sd[tid] = i < Nn ? ((cnt[i] + 3) & ~3) : 0;
    __syncthreads();
#pragma unroll
    for (int s = 128; s > 0; s >>= 1) {
        if (tid < s) sd[tid] += sd[tid + s];
        __syncthreads();
    }
    if (tid == 0) bsum[b] = sd[0];
}

__device__ void scan_offsets_body(int* __restrict__ bsum, int nb)   // nb <= 256
{
    __shared__ int sd[256];
    int tid = threadIdx.x;
    int v = tid < nb ? bsum[tid] : 0;
    sd[tid] = v;
    __syncthreads();
    for (int d = 1; d < 256; d <<= 1) {
        int t = tid >= d ? sd[tid - d] : 0;
        __syncthreads();
        sd[tid] += t;
        __syncthreads();
    }
    if (tid < nb) bsum[tid] = sd[tid] - v;   // exclusive
}

// ================= kernels =================

// histogram (standalone, low VGPR, no global atomics) -- depends only on ei
__global__ __launch_bounds__(256)
void hist_kernel(const int* __restrict__ ei, unsigned* __restrict__ partial,
                 int Nn, int E, int WORDS, int HALFR)
{
    __shared__ unsigned sh[HIST_MAXW];
    const int hbid = blockIdx.x;
    const int g = hbid / HIST_BPG;
    const int j = hbid - g * HIST_BPG;

    for (int w = threadIdx.x; w < WORDS; w += 256) sh[w] = 0;
    __syncthreads();

    const int* col = (g < 2) ? (ei + E) : ei;
    const int base = (g & 1) * HALFR;
    const size_t e0 = (size_t)E * j / HIST_BPG;
    const size_t e1 = (size_t)E * (j + 1) / HIST_BPG;
    for (size_t e = e0 + threadIdx.x; e < e1; e += 256) {
        int n = col[e] - base;
        if ((unsigned)n < (unsigned)HALFR)
            atomicAdd(&sh[n >> 1], 1u << ((n & 1) * 16));
    }
    __syncthreads();

    unsigned* out = partial + (size_t)hbid * WORDS;
    for (int w = threadIdx.x; w < WORDS; w += 256) out[w] = sh[w];
}

// KP1: stage-1 weight products + biases + converts.
__global__ __launch_bounds__(256)
void kprod1(const float* win0w, const float* win0b, const float* win1w, const float* win1b,
            const float* cout0w, const float* cout0b, const float* cout1w,
            const float* cout1b, const float* wrel0,
            float* WfA1, unsigned short* Wt, float* biasbuf, int nrel)
{
    const int IA1 = 1 + nrel, IC1 = 2 + 2 * nrel;
    const int nProd = 1 + nrel;
    int bid = blockIdx.x;
    if (bid < 2 * nProd) {
        int p = bid >> 1, tile = bid & 1;
        if (p == 0)
            gemmf32_body(cout0w, win1w, nullptr, WfA1, Wt + (size_t)IA1 * 16384, 128, tile);
        else
            gemmf32_body(win0w, wrel0 + (size_t)(p - 1) * 16384, nullptr,
                         nullptr, Wt + (size_t)p * 16384, 128, tile);
        return;
    }
    bid -= 2 * nProd;
    if (bid < nProd) {
        if (bid == 0) biasprod_body(cout0b, win1w, win1b, biasbuf + (size_t)IA1 * 128);
        else biasprod_body(win0b, wrel0 + (size_t)(bid - 1) * 16384, nullptr,
                           biasbuf + (size_t)bid * 128);
        return;
    }
    bid -= nProd;
    if (bid == 0) { wtconv_body(win0w, Wt); return; }
    if (bid == 1) { wtconv_body(cout1w, Wt + (size_t)IC1 * 16384); return; }
    int t = threadIdx.x;
    if (t < 128) {
        biasbuf[t] = win0b[t];
        biasbuf[(size_t)IC1 * 128 + t] = cout1b[t];
    }
}

// KMID: kprod2 (stage-2 products) | proj f32 GEMM -- both use gemmf32_body
// (identical register/LDS class; zero fusion risk), independent work overlapped.
__global__ __launch_bounds__(256)
void kmid(const float* wrel1, const float* WfA1, unsigned short* Wt, float* biasbuf,
          const float* x, const float* proj_w, const float* proj_b, float* h,
          int M, int nrel)
{
    const int IA1 = 1 + nrel, IB1 = 2 + nrel;
    int bid = blockIdx.x;
    if (bid < 2 * nrel) {
        int p = bid >> 1, tile = bid & 1;
        gemmf32_body(WfA1, wrel1 + (size_t)p * 16384, nullptr,
                     nullptr, Wt + (size_t)(IB1 + p) * 16384, 128, tile);
        return;
    }
    bid -= 2 * nrel;
    if (bid < nrel) {
        biasprod_body(biasbuf + (size_t)IA1 * 128, wrel1 + (size_t)bid * 16384, nullptr,
                      biasbuf + (size_t)(IB1 + bid) * 128);
        return;
    }
    bid -= nrel;
    gemmf32_body(x, proj_w, proj_b, h, nullptr, M, bid);
}

// K2: hist-reduce (-> dis, cnt) | bn_stats
__global__ __launch_bounds__(256)
void k2_reduce_bnstats(const unsigned* __restrict__ partial, float* __restrict__ dis,
                       int* __restrict__ cnt, const float* __restrict__ h,
                       float* __restrict__ bnsums, int Nn, int WORDS, int HALFR, int nRed)
{
    int bid = blockIdx.x;
    if (bid < nRed) {
        int t = bid * 256 + threadIdx.x;
        if (t < 4 * WORDS) {
            int histo = t / (2 * WORDS);
            int rem = t - histo * 2 * WORDS;
            int half = rem / WORDS;
            int w = rem - half * WORDS;
            int g = histo * 2 + half;
            unsigned slo = 0, shi = 0;
            const unsigned* p = partial + (size_t)(g * HIST_BPG) * WORDS + w;
#pragma unroll 4
            for (int j = 0; j < HIST_BPG; ++j) {
                unsigned u = p[(size_t)j * WORDS];
                slo += u & 0xffffu;
                shi += u >> 16;
            }
            int n0 = half * HALFR + 2 * w;
            int n1 = n0 + 1;
            if (histo == 0) {
                if (n0 < Nn) dis[n0] = slo ? rsqrtf((float)slo) : 0.f;
                if (n1 < Nn) dis[n1] = shi ? rsqrtf((float)shi) : 0.f;
            } else {
                if (n0 < Nn) cnt[n0] = (int)slo;
                if (n1 < Nn) cnt[n1] = (int)shi;
            }
        }
        return;
    }
    bn_stats_body(h, bnsums, Nn, bid - nRed);
}

// K3: bn_finalize | scan_block_sums (padded)
__global__ __launch_bounds__(256)
void k3_bnfin_scan1(const float* __restrict__ sums, const float* __restrict__ g,
                    const float* __restrict__ b, float* __restrict__ sc,
                    const int* __restrict__ cnt, int* __restrict__ bsum, int Nn)
{
    if (blockIdx.x == 0) {
        int c = threadIdx.x;
        if (c < 128) {
            float inv = 1.f / (float)Nn;
            float mu = sums[c] * inv;
            float var = sums[128 + c] * inv - mu * mu;
            float rstd = rsqrtf(var + 1e-5f);
            float scale = rstd * g[c];
            sc[c] = scale;
            sc[128 + c] = b[c] - mu * scale;
        }
        return;
    }
    scan_block_sums_body(cnt, bsum, Nn, blockIdx.x - 1);
}

// K4: scan_offsets | bn_apply_relu (f32 -> bf16)
__global__ __launch_bounds__(256)
void k4_scanoff_bnapply(int* __restrict__ bsum, int nb,
                        const float* __restrict__ h, const float* __restrict__ sc,
                        unsigned short* __restrict__ hb, size_t n4)
{
    if (blockIdx.x == 0) { scan_offsets_body(bsum, nb); return; }
    size_t i = (size_t)(blockIdx.x - 1) * 256 + threadIdx.x;
    if (i >= n4) return;
    int c = (int)(i & 31) << 2;
    float4 v = reinterpret_cast<const float4*>(h)[i];
    float o0 = fmaxf(fmaf(v.x, sc[c + 0], sc[128 + c + 0]), 0.f);
    float o1 = fmaxf(fmaf(v.y, sc[c + 1], sc[128 + c + 1]), 0.f);
    float o2 = fmaxf(fmaf(v.z, sc[c + 2], sc[128 + c + 2]), 0.f);
    float o3 = fmaxf(fmaf(v.w, sc[c + 3], sc[128 + c + 3]), 0.f);
    ushort4 pk = make_ushort4(f2bf(o0), f2bf(o1), f2bf(o2), f2bf(o3));
    reinterpret_cast<ushort4*>(hb)[i] = pk;
}

// K4b: scan_final with 4-padded offsets; writes rowptr/cursor, sink pads,
// 8 global pad entries, and the bf16 -100 sink row in Yw.
__global__ __launch_bounds__(256)
void k4b_scanfinal(const int* __restrict__ cnt, const int* __restrict__ bsum,
                   int* __restrict__ rowptr, int* __restrict__ cursor,
                   uint4* __restrict__ csr, unsigned* __restrict__ Yw,
                   unsigned sink_woff, int Nn, int nb)
{
    if ((int)blockIdx.x == nb) {
        int t = threadIdx.x;
        if (t < 64) Yw[sink_woff + t] = 0xC2C8C2C8u;   // bf16 -100 pair
        return;
    }
    __shared__ int sd[256];
    int tid = threadIdx.x;
    int b = blockIdx.x;
    int i = b * 256 + tid;
    int v = i < Nn ? cnt[i] : 0;
    int pv = (v + 3) & ~3;
    sd[tid] = pv;
    __syncthreads();
    for (int d = 1; d < 256; d <<= 1) {
        int t2 = tid >= d ? sd[tid - d] : 0;
        __syncthreads();
        sd[tid] += t2;
        __syncthreads();
    }
    if (i < Nn) {
        int off = sd[tid] - pv + bsum[b];
        rowptr[i] = off;
        cursor[i] = off;
        uint4 sink = make_uint4(0u, sink_woff, 0u, 0u);
        for (int j = v; j < pv; ++j) csr[off + j] = sink;
        if (i == Nn - 1) {
            rowptr[Nn] = off + pv;
            for (int q = 0; q < 8; ++q) csr[off + pv + q] = sink;   // global pad
        }
    }
}

// K5: layer-0 fused 6-mat MFMA | scatter (interleaved), 512 threads
__global__ __launch_bounds__(512)
void k5_mfma_scatter(const unsigned short* hb, const unsigned short* Wt,
                     const float* biasbuf, unsigned short* Xb, unsigned short* Yb,
                     int M, int nmats, int nF,
                     const int* __restrict__ ei, const int* __restrict__ et,
                     const float* __restrict__ dis, int* __restrict__ cursor,
                     uint4* __restrict__ csr, int E, int Nn, int nS)
{
    const int minv = nF < nS ? nF : nS;
    int bid = blockIdx.x;
    int fIdx = -1, sIdx = -1;
    if (bid < 2 * minv) {
        if (bid & 1) fIdx = bid >> 1; else sIdx = bid >> 1;
    } else {
        int rem = bid - 2 * minv;
        if (nF > nS) fIdx = minv + rem; else sIdx = minv + rem;
    }
    if (sIdx >= 0) {
        int e = sIdx * 512 + threadIdx.x;
        if (e < E) {
            int dst = ei[e];
            int src = ei[E + e];
            int pos = atomicAdd(&cursor[dst], 1);
            float nrm = dis[dst] * dis[src];
            csr[pos] = make_uint4((unsigned)(src * 64),
                                  (unsigned)((et[e] * Nn + src) * 64),
                                  __float_as_uint(nrm), 0u);
        }
        return;
    }
    fused_dispatch(hb, Wt, biasbuf, Xb, Yb, 0, M, nmats, fIdx);
}

// fused 6-mat MFMA pass (generic base, layer 1), 512 threads
__global__ __launch_bounds__(512)
void k_fusedpass(const unsigned short* A, const unsigned short* Wt, const float* biasbuf,
                 unsigned short* Xb, unsigned short* Yb, int base, int M, int nmats)
{
    fused_dispatch(A, Wt, biasbuf, Xb, Yb, base, M, nmats, blockIdx.x);
}

// final: out[row] = gelu(msg_dense[row] @ cout1 + b), f32, dense M rows, 512 thr
__global__ __launch_bounds__(512)
void k_cout_gelu(const unsigned short* __restrict__ A, const unsigned short* Wt,
                 const float* biasbuf, float* __restrict__ out, int mat, int M)
{
    const unsigned short* Wmat = Wt + (size_t)mat * 16384;
    const float* bias = biasbuf + (size_t)mat * 128;

    __shared__ unsigned short Bs[16384];
    const int tid = threadIdx.x;
#pragma unroll
    for (int i = 0; i < 4; ++i) {
        int idx = tid + i * 512;
        uint4 v = *reinterpret_cast<const uint4*>(Wmat + (size_t)idx * 8);
        int row = idx >> 4;
        int j = idx & 15;
        int byte = row * 256 + ((j ^ (row & 15)) << 4);
        *reinterpret_cast<uint4*>(reinterpret_cast<char*>(Bs) + byte) = v;
    }
    __syncthreads();

    const int wave = tid >> 6;
    const int lane = tid & 63;
    const int grp = lane >> 4;
    const int l16 = lane & 15;
    const int row = blockIdx.x * 128 + wave * 16 + l16;
    const int rc = row < M ? row : M - 1;

    f32x4 acc[8] = {};
#pragma unroll
    for (int kt = 0; kt < 4; ++kt) {
        const int k0 = kt * 32 + grp * 8;
        short8v a = *reinterpret_cast<const short8v*>(A + (size_t)rc * 128 + k0);
        const int joff = kt * 4 + grp;
#pragma unroll
        for (int n = 0; n < 8; ++n) {
            int brow = 16 * n + l16;
            int byte = brow * 256 + ((joff ^ (brow & 15)) << 4);
            short8v b = *reinterpret_cast<const short8v*>(
                reinterpret_cast<const char*>(Bs) + byte);
            acc[n] = __builtin_amdgcn_mfma_f32_16x16x32_bf16(b, a, acc[n], 0, 0, 0);
        }
    }

    if (row >= M) return;

    const float kg = 0.7071067811865475f;
#pragma unroll
    for (int n = 0; n < 8; ++n) {
        float4 bb = *reinterpret_cast<const float4*>(bias + 16 * n + grp * 4);
        float v0 = acc[n][0] + bb.x;
        float v1 = acc[n][1] + bb.y;
        float v2 = acc[n][2] + bb.z;
        float v3 = acc[n][3] + bb.w;
        v0 = 0.5f * v0 * (1.f + erff(v0 * kg));
        v1 = 0.5f * v1 * (1.f + erff(v1 * kg));
        v2 = 0.5f * v2 * (1.f + erff(v2 * kg));
        v3 = 0.5f * v3 * (1.f + erff(v3 * kg));
        *reinterpret_cast<float4*>(out + (size_t)row * 128 + 16 * n + grp * 4) =
            make_float4(v0, v1, v2, v3);
    }
}

// ---- fused per-node gather: gcn-sum + scatter-softmax + combine ----
// Mask-free (sink-padded CSR). Optional idxmap: gid -> node; output row = gid.
__global__ __launch_bounds__(256)
void node_gather(const int* __restrict__ rowptr, const uint4* __restrict__ csr,
                 const unsigned* __restrict__ Xw, const unsigned* __restrict__ Yw,
                 unsigned short* __restrict__ outb,
                 const int* __restrict__ idxmap, int count)
{
    int gid = blockIdx.x * 4 + (threadIdx.x >> 6);
    if (gid >= count) return;
    int node = idxmap ? idxmap[gid] : gid;
    int lane = threadIdx.x & 63;

    int i = rowptr[node];
    const int end = rowptr[node + 1];

    float mg0 = 0.f, mg1 = 0.f, s0 = 0.f, s1 = 0.f, t0 = 0.f, t1 = 0.f;

    if (i < end) {
        uint4 cur[4];
#pragma unroll
        for (int q = 0; q < 4; ++q) cur[q] = csr[i + q];

        for (; i < end; i += 4) {
            uint4 nxt[4];
#pragma unroll
            for (int q = 0; q < 4; ++q) nxt[q] = csr[i + 4 + q];   // global pad covers

            unsigned xp[4], yp[4];
#pragma unroll
            for (int q = 0; q < 4; ++q) {
                xp[q] = Xw[cur[q].x + lane];
                yp[q] = Yw[cur[q].y + lane];
            }
#pragma unroll
            for (int q = 0; q < 4; ++q) {
                float nrm = __uint_as_float(cur[q].z);
                float x0 = bf2f((unsigned short)(xp[q] & 0xffffu));
                float x1 = bf2f((unsigned short)(xp[q] >> 16));
                float y0 = bf2f((unsigned short)(yp[q] & 0xffffu));
                float y1 = bf2f((unsigned short)(yp[q] >> 16));
                float w0 = __expf(y0), w1 = __expf(y1);
                mg0 = fmaf(x0, nrm, mg0);
                mg1 = fmaf(x1, nrm, mg1);
                s0 += w0; s1 += w1;
                t0 = fmaf(y0, w0, t0);
                t1 = fmaf(y1, w1, t1);
            }
#pragma unroll
            for (int q = 0; q < 4; ++q) cur[q] = nxt[q];
        }
    }

    float o0 = mg0 + 0.1f * fmaxf(s0 > 0.f ? t0 / s0 : 0.f, 0.f);
    float o1 = mg1 + 0.1f * fmaxf(s1 > 0.f ? t1 / s1 : 0.f, 0.f);
    unsigned pk = (unsigned)f2bf(o0) | ((unsigned)f2bf(o1) << 16);
    *reinterpret_cast<unsigned*>(outb + (size_t)gid * 128 + (lane << 1)) = pk;
}

// ================= launch =================
extern "C" void kernel_launch(void* const* d_in, const int* in_sizes, int n_in,
                              void* d_out, int out_size, void* d_ws, size_t ws_size,
                              hipStream_t stream)
{
    const float* x      = (const float*)d_in[0];
    const int*   ei     = (const int*)d_in[1];
    const int*   et     = (const int*)d_in[2];
    // d_in[3] edge_weight: unused by the reference
    const int*   idxp   = (const int*)d_in[4];
    const float* proj_w = (const float*)d_in[5];
    const float* proj_b = (const float*)d_in[6];
    const float* bn_g   = (const float*)d_in[7];
    const float* bn_b   = (const float*)d_in[8];
    const float* win_w[2]  = {(const float*)d_in[9],  (const float*)d_in[14]};
    const float* win_b[2]  = {(const float*)d_in[10], (const float*)d_in[15]};
    const float* wrel[2]   = {(const float*)d_in[11], (const float*)d_in[16]};
    const float* cout_w[2] = {(const float*)d_in[12], (const float*)d_in[17]};
    const float* cout_b[2] = {(const float*)d_in[13], (const float*)d_in[18]};

    const int Nn  = in_sizes[0] / 128;
    const int E   = in_sizes[1] / 2;
    const int Mo  = in_sizes[4];
    const int nrel = in_sizes[11] / (128 * 128);
    const size_t ND = (size_t)Nn * 128;

    const int HALFR = ((Nn + 3) / 4) * 2;
    const int WORDS = HALFR / 2;
    if (WORDS > HIST_MAXW) return;

    const int IA1 = 1 + nrel;
    const int IC1 = 2 + 2 * nrel;
    const int NMATS = 3 + 2 * nrel;

    // workspace layout
    char* p = (char*)d_ws;
    float* h    = (float*)p;                  p += ND * 4;
    unsigned short* hb = (unsigned short*)p;  p += ND * 2;
    unsigned short* Xb = (unsigned short*)p;  p += ND * 2;
    unsigned short* Yb = (unsigned short*)p;  p += (size_t)nrel * ND * 2 + 256;  // +sink row
    unsigned short* msgb = (unsigned short*)p; p += ND * 2;
    unsigned short* Wt = (unsigned short*)p;  p += (size_t)NMATS * 16384 * 2;
    float* WfA1 = (float*)p;                  p += (size_t)16384 * 4;
    float* biasbuf = (float*)p;               p += (size_t)NMATS * 128 * 4;
    uint4* csr  = (uint4*)p;                  p += ((size_t)E + 3 * (size_t)Nn + 16) * 16;
    unsigned* partial = (unsigned*)p;         p += (size_t)HIST_B * WORDS * 4;
    float* dis  = (float*)p;                  p += (size_t)Nn * 4;
    int*   cnt  = (int*)p;                    p += (size_t)Nn * 4;
    int*   rowptr = (int*)p;                  p += ((size_t)Nn + 1) * 4;
    int*   cursor = (int*)p;                  p += (size_t)Nn * 4;
    int*   bsum = (int*)p;                    p += 1024 * 4;
    float* bnsums = (float*)p;                p += 256 * 4;
    float* bnsc   = (float*)p;                p += 256 * 4;
    if ((size_t)(p - (char*)d_ws) > ws_size) return;

    const unsigned sink_woff = (unsigned)((size_t)nrel * Nn * 64);   // word offset in Yb

    const int gemmGrid = (Nn + 63) / 64;
    const int tiles128 = (Nn + 127) / 128;
    const size_t n4 = ND / 4;
    const int n4grid = (int)((n4 + 255) / 256);
    const int nb = (Nn + 255) / 256;
    const int nRed = (4 * WORDS + 255) / 256;
    const int nS = (E + 511) / 512;               // 512-thread scatter blocks
    const int nmats = 1 + nrel;
    const int nFused = nmats * tiles128;

    hipMemsetAsync(bnsums, 0, 256 * 4, stream);

    // histogram first (depends only on ei)
    hist_kernel<<<HIST_B, 256, 0, stream>>>(ei, partial, Nn, E, WORDS, HALFR);

    // stage-1 weight products
    kprod1<<<2 * (1 + nrel) + (1 + nrel) + 3, 256, 0, stream>>>(
        win_w[0], win_b[0], win_w[1], win_b[1], cout_w[0], cout_b[0],
        cout_w[1], cout_b[1], wrel[0], WfA1, Wt, biasbuf, nrel);

    // KMID: stage-2 products | proj GEMM (overlapped)
    kmid<<<3 * nrel + gemmGrid, 256, 0, stream>>>(
        wrel[1], WfA1, Wt, biasbuf, x, proj_w, proj_b, h, Nn, nrel);

    // K2: hist reduce (dis, cnt) | bn_stats
    k2_reduce_bnstats<<<nRed + 256, 256, 0, stream>>>(
        partial, dis, cnt, h, bnsums, Nn, WORDS, HALFR, nRed);

    // K3: bn_finalize | scan level-1 (padded counts)
    k3_bnfin_scan1<<<1 + nb, 256, 0, stream>>>(bnsums, bn_g, bn_b, bnsc, cnt, bsum, Nn);

    // K4: scan offsets | bn apply+relu -> hb
    k4_scanoff_bnapply<<<1 + n4grid, 256, 0, stream>>>(bsum, nb, h, bnsc, hb, n4);

    // K4b: scan final (padded rowptr/cursor) + sink pads + sink row
    k4b_scanfinal<<<nb + 1, 256, 0, stream>>>(cnt, bsum, rowptr, cursor, csr,
                                              (unsigned*)Yb, sink_woff, Nn, nb);

    // K5: layer-0 fused 6-mat MFMA | scatter (interleaved, 512 thr)
    k5_mfma_scatter<<<nFused + nS, 512, 0, stream>>>(
        hb, Wt, biasbuf, Xb, Yb, Nn, nmats, nFused,
        ei, et, dis, cursor, csr, E, Nn, nS);

    // layer 0 gather (all nodes)
    node_gather<<<(Nn + 3) / 4, 256, 0, stream>>>(
        rowptr, csr, (const unsigned*)Xb, (const unsigned*)Yb, msgb, nullptr, Nn);

    // layer-1 fused 6-mat pass (all nodes)
    k_fusedpass<<<nFused, 512, 0, stream>>>(msgb, Wt, biasbuf, Xb, Yb, IA1, Nn, nmats);

    // layer 1 gather: ONLY the idx destination nodes (dense Mo-row output)
    node_gather<<<(Mo + 3) / 4, 256, 0, stream>>>(
        rowptr, csr, (const unsigned*)Xb, (const unsigned*)Yb, msgb, idxp, Mo);

    // final: cout1 + gelu on dense Mo rows -> d_out
    k_cout_gelu<<<(Mo + 127) / 128, 512, 0, stream>>>(
        msgb, Wt, biasbuf, (float*)d_out, IC1, Mo);
}

// Round 15
// 310.002 us; speedup vs baseline: 1.3318x; 1.0050x over previous
//
#include <hip/hip_runtime.h>

#define HIST_BPG 32              // edge-slice blocks per (histogram, half) group
#define HIST_B   (HIST_BPG * 4)  // 4 groups: src-lo, src-hi, dst-lo, dst-hi
#define HIST_MAXW 12288          // max packed words (supports Nn <= ~49k)

// ---------- helpers ----------
__device__ inline float bf2f(unsigned short u) {
    return __uint_as_float(((unsigned)u) << 16);
}
__device__ inline unsigned short f2bf(float f) {
    unsigned u = __float_as_uint(f);
    u += 0x7fffu + ((u >> 16) & 1u);   // round-to-nearest-even
    return (unsigned short)(u >> 16);
}

// bijective XCD swizzle (m204): blocks with bid%8==c get a CONTIGUOUS work
// range -> same-XCD L2 reuse across the 6 mats of a tile (tile-major work).
__device__ inline int xcd_swizzle(int bid, int n)
{
    const int NX = 8;
    int q = n / NX, r = n % NX;
    int xcd = bid % NX;
    int rank = bid / NX;
    return (xcd < r) ? xcd * (q + 1) + rank : r * (q + 1) + (xcd - r) * q + rank;
}

typedef __attribute__((ext_vector_type(8))) short short8v;   // 8 bf16 (4 VGPRs)
typedef __attribute__((ext_vector_type(4))) float f32x4;

// ================= device bodies =================

// ---- f32 GEMM body (64-row tile, 256 threads): C[M x 128] = A @ W (+ bias) ----
// Optional outputs: C (f32 [row][col]) and Ct (bf16 TRANSPOSED [col][row]).
// __shared__ declared DIRECTLY here (char*-cast LDS caused 256-VGPR spill, r7-8).
__device__ __forceinline__
void gemmf32_body(const float* __restrict__ A, const float* __restrict__ W,
                  const float* __restrict__ bias, float* __restrict__ C,
                  unsigned short* __restrict__ Ct, int M, int tile)
{
    __shared__ float As[64][132];
    __shared__ float Ws[32][128];

    const int tid = threadIdx.x;
    const int row0 = tile * 64;

#pragma unroll
    for (int i = 0; i < 8; ++i) {
        int idx = tid + i * 256;
        int rr = idx >> 5;
        int cc = (idx & 31) << 2;
        int gr = row0 + rr;
        float4 v = make_float4(0.f, 0.f, 0.f, 0.f);
        if (gr < M) v = *reinterpret_cast<const float4*>(A + (size_t)gr * 128 + cc);
        *reinterpret_cast<float4*>(&As[rr][cc]) = v;
    }

    const int tx = tid & 15;
    const int ty = tid >> 4;
    float acc[4][8];
#pragma unroll
    for (int i = 0; i < 4; ++i)
#pragma unroll
        for (int j = 0; j < 8; ++j) acc[i][j] = 0.f;

    for (int kt = 0; kt < 4; ++kt) {
        __syncthreads();
#pragma unroll
        for (int i = 0; i < 4; ++i) {
            int idx = tid + i * 256;
            int rr = idx >> 5;
            int cc = (idx & 31) << 2;
            *reinterpret_cast<float4*>(&Ws[rr][cc]) =
                *reinterpret_cast<const float4*>(W + (size_t)(kt * 32 + rr) * 128 + cc);
        }
        __syncthreads();
#pragma unroll
        for (int kk = 0; kk < 32; ++kk) {
            const int k = kt * 32 + kk;
            float a0 = As[ty * 4 + 0][k];
            float a1 = As[ty * 4 + 1][k];
            float a2 = As[ty * 4 + 2][k];
            float a3 = As[ty * 4 + 3][k];
            float w[8];
#pragma unroll
            for (int j = 0; j < 8; ++j) w[j] = Ws[kk][tx + 16 * j];
#pragma unroll
            for (int j = 0; j < 8; ++j) {
                acc[0][j] = fmaf(a0, w[j], acc[0][j]);
                acc[1][j] = fmaf(a1, w[j], acc[1][j]);
                acc[2][j] = fmaf(a2, w[j], acc[2][j]);
                acc[3][j] = fmaf(a3, w[j], acc[3][j]);
            }
        }
    }

    float bb[8];
#pragma unroll
    for (int j = 0; j < 8; ++j) bb[j] = bias ? bias[tx + 16 * j] : 0.f;

#pragma unroll
    for (int i = 0; i < 4; ++i) {
        int gr = row0 + ty * 4 + i;
        if (gr >= M) continue;
#pragma unroll
        for (int j = 0; j < 8; ++j) {
            float v = acc[i][j] + bb[j];
            if (C)  C[(size_t)gr * 128 + tx + 16 * j] = v;
            if (Ct) Ct[(size_t)(tx + 16 * j) * 128 + gr] = f2bf(v);
        }
    }
}

// ---- MFMA GEMM body (operand-swapped), LDS-staged B, 512 THREADS ----
// 8 waves x 16 rows = 128-row tile. Per-wave class: acc[8] + 4 prefetched
// A frags (~50 VGPR). A-PREFETCH: all 4 global loads issue up-front so the
// K-loop has no serialized HBM/L2 stalls (round-14 lesson: occupancy alone
// didn't cover the 4 dependent loads).
__device__ __forceinline__
void mfmaw_body(const unsigned short* __restrict__ A,
                const unsigned short* __restrict__ Wmat,
                const float* __restrict__ bias,
                float* __restrict__ Cf, unsigned short* __restrict__ Cb,
                int M, int tile)
{
    __shared__ unsigned short Bs[16384];   // 32 KB

    const int tid = threadIdx.x;
#pragma unroll
    for (int i = 0; i < 4; ++i) {
        int idx = tid + i * 512;                 // 16B chunk id, 0..2047
        uint4 v = *reinterpret_cast<const uint4*>(Wmat + (size_t)idx * 8);
        int row = idx >> 4;
        int j = idx & 15;
        int byte = row * 256 + ((j ^ (row & 15)) << 4);
        *reinterpret_cast<uint4*>(reinterpret_cast<char*>(Bs) + byte) = v;
    }

    const int wave = tid >> 6;                   // 0..7
    const int lane = tid & 63;
    const int grp = lane >> 4;
    const int l16 = lane & 15;
    const int row = tile * 128 + wave * 16 + l16;
    const int rc = row < M ? row : M - 1;        // clamp; tail rows not stored

    // prefetch all 4 A fragments (independent loads, issued before barrier)
    short8v a[4];
#pragma unroll
    for (int kt = 0; kt < 4; ++kt)
        a[kt] = *reinterpret_cast<const short8v*>(A + (size_t)rc * 128 + kt * 32 + grp * 8);

    __syncthreads();

    f32x4 acc[8] = {};
#pragma unroll
    for (int kt = 0; kt < 4; ++kt) {
        const int joff = kt * 4 + grp;           // k-chunk index 0..15
#pragma unroll
        for (int n = 0; n < 8; ++n) {
            int brow = 16 * n + l16;
            int byte = brow * 256 + ((joff ^ (brow & 15)) << 4);
            short8v b = *reinterpret_cast<const short8v*>(
                reinterpret_cast<const char*>(Bs) + byte);
            acc[n] = __builtin_amdgcn_mfma_f32_16x16x32_bf16(b, a[kt], acc[n], 0, 0, 0);
        }
    }

    if (row >= M) return;   // no barriers past this point

    float4 bb[8];
#pragma unroll
    for (int n = 0; n < 8; ++n)
        bb[n] = bias ? *reinterpret_cast<const float4*>(bias + 16 * n + grp * 4)
                     : make_float4(0.f, 0.f, 0.f, 0.f);

#pragma unroll
    for (int n = 0; n < 8; ++n) {
        float v0 = acc[n][0] + bb[n].x;
        float v1 = acc[n][1] + bb[n].y;
        float v2 = acc[n][2] + bb[n].z;
        float v3 = acc[n][3] + bb[n].w;
        if (Cf) {
            *reinterpret_cast<float4*>(Cf + (size_t)row * 128 + 16 * n + grp * 4) =
                make_float4(v0, v1, v2, v3);
        }
        if (Cb) {
            unsigned u0 = (unsigned)f2bf(v0) | ((unsigned)f2bf(v1) << 16);
            unsigned u1 = (unsigned)f2bf(v2) | ((unsigned)f2bf(v3) << 16);
            *reinterpret_cast<uint2*>(Cb + (size_t)row * 128 + 16 * n + grp * 4) =
                make_uint2(u0, u1);
        }
    }
}

// fused 6-mat pass dispatch; work index XCD-swizzled (tile-major within XCD)
__device__ void fused_dispatch(const unsigned short* A, const unsigned short* Wt,
                               const float* biasbuf, unsigned short* Xb,
                               unsigned short* Yb, int base, int M, int nmats,
                               int bid, int nF)
{
    int w = xcd_swizzle(bid, nF);
    int m = w % nmats;
    int tile = w / nmats;
    unsigned short* out = (m == 0) ? Xb : Yb + (size_t)(m - 1) * (size_t)M * 128;
    mfmaw_body(A, Wt + (size_t)(base + m) * 16384,
               biasbuf + (size_t)(base + m) * 128, nullptr, out, M, tile);
}

// ---- bias product body: out[t] = sum_j v[j]*W[j*128+t] (+ add[t]) ----
__device__ void biasprod_body(const float* __restrict__ v, const float* __restrict__ W,
                              const float* __restrict__ add, float* __restrict__ out)
{
    int t = threadIdx.x;
    if (t >= 128) return;
    float s = add ? add[t] : 0.f;
    for (int j = 0; j < 128; ++j) s = fmaf(v[j], W[(size_t)j * 128 + t], s);
    out[t] = s;
}

// ---- bf16-transpose convert body: Wt[mat] <- f32 W[k][n] ----
__device__ void wtconv_body(const float* __restrict__ W, unsigned short* __restrict__ O)
{
    for (int i = threadIdx.x; i < 16384; i += 256) {
        int k = i >> 7, n = i & 127;
        O[(size_t)n * 128 + k] = f2bf(W[i]);
    }
}

// ---- bn stats body ----
__device__ void bn_stats_body(const float* __restrict__ h, float* __restrict__ sums,
                              int Nn, int b)
{
    const int c = threadIdx.x & 127;
    const int half = threadIdx.x >> 7;
    float s = 0.f, q = 0.f;
    for (int row = b * 2 + half; row < Nn; row += 512) {
        float v = h[(size_t)row * 128 + c];
        s += v;
        q += v * v;
    }
    __shared__ float ls[256], lq[256];
    ls[threadIdx.x] = s;
    lq[threadIdx.x] = q;
    __syncthreads();
    if (half == 0) {
        s += ls[threadIdx.x + 128];
        q += lq[threadIdx.x + 128];
        atomicAdd(&sums[c], s);
        atomicAdd(&sums[128 + c], q);
    }
}

// ---- scan bodies (counts padded to multiple of 4 for CSR 4-unroll) ----
__device__ void scan_block_sums_body(const int* __restrict__ cnt, int* __restrict__ bsum,
                                     int Nn, int b)
{
    __shared__ int sd[256];
    int tid = threadIdx.x;
    int i = b * 256 + tid;
    sd[tid] = i < Nn ? ((cnt[i] + 3) & ~3) : 0;
    __syncthreads();
#pragma unroll
    for (int s = 128; s > 0; s >>= 1) {
        if (tid < s) sd[tid] += sd[tid + s];
        __syncthreads();
    }
    if (tid == 0) bsum[b] = sd[0];
}

__device__ void scan_offsets_body(int* __restrict__ bsum, int nb)   // nb <= 256
{
    __shared__ int sd[256];
    int tid = threadIdx.x;
    int v = tid < nb ? bsum[tid] : 0;
    sd[tid] = v;
    __syncthreads();
    for (int d = 1; d < 256; d <<= 1) {
        int t = tid >= d ? sd[tid - d] : 0;
        __syncthreads();
        sd[tid] += t;
        __syncthreads();
    }
    if (tid < nb) bsum[tid] = sd[tid] - v;   // exclusive
}

// ================= kernels =================

// histogram (standalone, low VGPR, no global atomics) -- depends only on ei
__global__ __launch_bounds__(256)
void hist_kernel(const int* __restrict__ ei, unsigned* __restrict__ partial,
                 int Nn, int E, int WORDS, int HALFR)
{
    __shared__ unsigned sh[HIST_MAXW];
    const int hbid = blockIdx.x;
    const int g = hbid / HIST_BPG;
    const int j = hbid - g * HIST_BPG;

    for (int w = threadIdx.x; w < WORDS; w += 256) sh[w] = 0;
    __syncthreads();

    const int* col = (g < 2) ? (ei + E) : ei;
    const int base = (g & 1) * HALFR;
    const size_t e0 = (size_t)E * j / HIST_BPG;
    const size_t e1 = (size_t)E * (j + 1) / HIST_BPG;
    for (size_t e = e0 + threadIdx.x; e < e1; e += 256) {
        int n = col[e] - base;
        if ((unsigned)n < (unsigned)HALFR)
            atomicAdd(&sh[n >> 1], 1u << ((n & 1) * 16));
    }
    __syncthreads();

    unsigned* out = partial + (size_t)hbid * WORDS;
    for (int w = threadIdx.x; w < WORDS; w += 256) out[w] = sh[w];
}

// KP1: stage-1 weight products + biases + converts.
__global__ __launch_bounds__(256)
void kprod1(const float* win0w, const float* win0b, const float* win1w, const float* win1b,
            const float* cout0w, const float* cout0b, const float* cout1w,
            const float* cout1b, const float* wrel0,
            float* WfA1, unsigned short* Wt, float* biasbuf, int nrel)
{
    const int IA1 = 1 + nrel, IC1 = 2 + 2 * nrel;
    const int nProd = 1 + nrel;
    int bid = blockIdx.x;
    if (bid < 2 * nProd) {
        int p = bid >> 1, tile = bid & 1;
        if (p == 0)
            gemmf32_body(cout0w, win1w, nullptr, WfA1, Wt + (size_t)IA1 * 16384, 128, tile);
        else
            gemmf32_body(win0w, wrel0 + (size_t)(p - 1) * 16384, nullptr,
                         nullptr, Wt + (size_t)p * 16384, 128, tile);
        return;
    }
    bid -= 2 * nProd;
    if (bid < nProd) {
        if (bid == 0) biasprod_body(cout0b, win1w, win1b, biasbuf + (size_t)IA1 * 128);
        else biasprod_body(win0b, wrel0 + (size_t)(bid - 1) * 16384, nullptr,
                           biasbuf + (size_t)bid * 128);
        return;
    }
    bid -= nProd;
    if (bid == 0) { wtconv_body(win0w, Wt); return; }
    if (bid == 1) { wtconv_body(cout1w, Wt + (size_t)IC1 * 16384); return; }
    int t = threadIdx.x;
    if (t < 128) {
        biasbuf[t] = win0b[t];
        biasbuf[(size_t)IC1 * 128 + t] = cout1b[t];
    }
}

// KMID: kprod2 (stage-2 products) | proj f32 GEMM -- both use gemmf32_body
__global__ __launch_bounds__(256)
void kmid(const float* wrel1, const float* WfA1, unsigned short* Wt, float* biasbuf,
          const float* x, const float* proj_w, const float* proj_b, float* h,
          int M, int nrel)
{
    const int IA1 = 1 + nrel, IB1 = 2 + nrel;
    int bid = blockIdx.x;
    if (bid < 2 * nrel) {
        int p = bid >> 1, tile = bid & 1;
        gemmf32_body(WfA1, wrel1 + (size_t)p * 16384, nullptr,
                     nullptr, Wt + (size_t)(IB1 + p) * 16384, 128, tile);
        return;
    }
    bid -= 2 * nrel;
    if (bid < nrel) {
        biasprod_body(biasbuf + (size_t)IA1 * 128, wrel1 + (size_t)bid * 16384, nullptr,
                      biasbuf + (size_t)(IB1 + bid) * 128);
        return;
    }
    bid -= nrel;
    gemmf32_body(x, proj_w, proj_b, h, nullptr, M, bid);
}

// K2: hist-reduce (-> dis, cnt) | bn_stats
__global__ __launch_bounds__(256)
void k2_reduce_bnstats(const unsigned* __restrict__ partial, float* __restrict__ dis,
                       int* __restrict__ cnt, const float* __restrict__ h,
                       float* __restrict__ bnsums, int Nn, int WORDS, int HALFR, int nRed)
{
    int bid = blockIdx.x;
    if (bid < nRed) {
        int t = bid * 256 + threadIdx.x;
        if (t < 4 * WORDS) {
            int histo = t / (2 * WORDS);
            int rem = t - histo * 2 * WORDS;
            int half = rem / WORDS;
            int w = rem - half * WORDS;
            int g = histo * 2 + half;
            unsigned slo = 0, shi = 0;
            const unsigned* p = partial + (size_t)(g * HIST_BPG) * WORDS + w;
#pragma unroll 4
            for (int j = 0; j < HIST_BPG; ++j) {
                unsigned u = p[(size_t)j * WORDS];
                slo += u & 0xffffu;
                shi += u >> 16;
            }
            int n0 = half * HALFR + 2 * w;
            int n1 = n0 + 1;
            if (histo == 0) {
                if (n0 < Nn) dis[n0] = slo ? rsqrtf((float)slo) : 0.f;
                if (n1 < Nn) dis[n1] = shi ? rsqrtf((float)shi) : 0.f;
            } else {
                if (n0 < Nn) cnt[n0] = (int)slo;
                if (n1 < Nn) cnt[n1] = (int)shi;
            }
        }
        return;
    }
    bn_stats_body(h, bnsums, Nn, bid - nRed);
}

// K3: bn_finalize | scan_block_sums (padded)
__global__ __launch_bounds__(256)
void k3_bnfin_scan1(const float* __restrict__ sums, const float* __restrict__ g,
                    const float* __restrict__ b, float* __restrict__ sc,
                    const int* __restrict__ cnt, int* __restrict__ bsum, int Nn)
{
    if (blockIdx.x == 0) {
        int c = threadIdx.x;
        if (c < 128) {
            float inv = 1.f / (float)Nn;
            float mu = sums[c] * inv;
            float var = sums[128 + c] * inv - mu * mu;
            float rstd = rsqrtf(var + 1e-5f);
            float scale = rstd * g[c];
            sc[c] = scale;
            sc[128 + c] = b[c] - mu * scale;
        }
        return;
    }
    scan_block_sums_body(cnt, bsum, Nn, blockIdx.x - 1);
}

// K4: scan_offsets | bn_apply_relu (f32 -> bf16)
__global__ __launch_bounds__(256)
void k4_scanoff_bnapply(int* __restrict__ bsum, int nb,
                        const float* __restrict__ h, const float* __restrict__ sc,
                        unsigned short* __restrict__ hb, size_t n4)
{
    if (blockIdx.x == 0) { scan_offsets_body(bsum, nb); return; }
    size_t i = (size_t)(blockIdx.x - 1) * 256 + threadIdx.x;
    if (i >= n4) return;
    int c = (int)(i & 31) << 2;
    float4 v = reinterpret_cast<const float4*>(h)[i];
    float o0 = fmaxf(fmaf(v.x, sc[c + 0], sc[128 + c + 0]), 0.f);
    float o1 = fmaxf(fmaf(v.y, sc[c + 1], sc[128 + c + 1]), 0.f);
    float o2 = fmaxf(fmaf(v.z, sc[c + 2], sc[128 + c + 2]), 0.f);
    float o3 = fmaxf(fmaf(v.w, sc[c + 3], sc[128 + c + 3]), 0.f);
    ushort4 pk = make_ushort4(f2bf(o0), f2bf(o1), f2bf(o2), f2bf(o3));
    reinterpret_cast<ushort4*>(hb)[i] = pk;
}

// K4b: scan_final with 4-padded offsets; writes rowptr/cursor, sink pads,
// 8 global pad entries, and the bf16 -100 sink row in Yw.
__global__ __launch_bounds__(256)
void k4b_scanfinal(const int* __restrict__ cnt, const int* __restrict__ bsum,
                   int* __restrict__ rowptr, int* __restrict__ cursor,
                   uint4* __restrict__ csr, unsigned* __restrict__ Yw,
                   unsigned sink_woff, int Nn, int nb)
{
    if ((int)blockIdx.x == nb) {
        int t = threadIdx.x;
        if (t < 64) Yw[sink_woff + t] = 0xC2C8C2C8u;   // bf16 -100 pair
        return;
    }
    __shared__ int sd[256];
    int tid = threadIdx.x;
    int b = blockIdx.x;
    int i = b * 256 + tid;
    int v = i < Nn ? cnt[i] : 0;
    int pv = (v + 3) & ~3;
    sd[tid] = pv;
    __syncthreads();
    for (int d = 1; d < 256; d <<= 1) {
        int t2 = tid >= d ? sd[tid - d] : 0;
        __syncthreads();
        sd[tid] += t2;
        __syncthreads();
    }
    if (i < Nn) {
        int off = sd[tid] - pv + bsum[b];
        rowptr[i] = off;
        cursor[i] = off;
        uint4 sink = make_uint4(0u, sink_woff, 0u, 0u);
        for (int j = v; j < pv; ++j) csr[off + j] = sink;
        if (i == Nn - 1) {
            rowptr[Nn] = off + pv;
            for (int q = 0; q < 8; ++q) csr[off + pv + q] = sink;   // global pad
        }
    }
}

// K5: layer-0 fused 6-mat MFMA | scatter (interleaved), 512 threads
__global__ __launch_bounds__(512)
void k5_mfma_scatter(const unsigned short* hb, const unsigned short* Wt,
                     const float* biasbuf, unsigned short* Xb, unsigned short* Yb,
                     int M, int nmats, int nF,
                     const int* __restrict__ ei, const int* __restrict__ et,
                     const float* __restrict__ dis, int* __restrict__ cursor,
                     uint4* __restrict__ csr, int E, int Nn, int nS)
{
    const int minv = nF < nS ? nF : nS;
    int bid = blockIdx.x;
    int fIdx = -1, sIdx = -1;
    if (bid < 2 * minv) {
        if (bid & 1) fIdx = bid >> 1; else sIdx = bid >> 1;
    } else {
        int rem = bid - 2 * minv;
        if (nF > nS) fIdx = minv + rem; else sIdx = minv + rem;
    }
    if (sIdx >= 0) {
        int e = sIdx * 512 + threadIdx.x;
        if (e < E) {
            int dst = ei[e];
            int src = ei[E + e];
            int pos = atomicAdd(&cursor[dst], 1);
            float nrm = dis[dst] * dis[src];
            csr[pos] = make_uint4((unsigned)(src * 64),
                                  (unsigned)((et[e] * Nn + src) * 64),
                                  __float_as_uint(nrm), 0u);
        }
        return;
    }
    fused_dispatch(hb, Wt, biasbuf, Xb, Yb, 0, M, nmats, fIdx, nF);
}

// fused 6-mat MFMA pass (generic base, layer 1), 512 threads
__global__ __launch_bounds__(512)
void k_fusedpass(const unsigned short* A, const unsigned short* Wt, const float* biasbuf,
                 unsigned short* Xb, unsigned short* Yb, int base, int M, int nmats,
                 int nF)
{
    fused_dispatch(A, Wt, biasbuf, Xb, Yb, base, M, nmats, blockIdx.x, nF);
}

// final: out[row] = gelu(msg_dense[row] @ cout1 + b), f32, dense M rows, 512 thr
__global__ __launch_bounds__(512)
void k_cout_gelu(const unsigned short* __restrict__ A, const unsigned short* Wt,
                 const float* biasbuf, float* __restrict__ out, int mat, int M)
{
    const unsigned short* Wmat = Wt + (size_t)mat * 16384;
    const float* bias = biasbuf + (size_t)mat * 128;

    __shared__ unsigned short Bs[16384];
    const int tid = threadIdx.x;
#pragma unroll
    for (int i = 0; i < 4; ++i) {
        int idx = tid + i * 512;
        uint4 v = *reinterpret_cast<const uint4*>(Wmat + (size_t)idx * 8);
        int row = idx >> 4;
        int j = idx & 15;
        int byte = row * 256 + ((j ^ (row & 15)) << 4);
        *reinterpret_cast<uint4*>(reinterpret_cast<char*>(Bs) + byte) = v;
    }

    const int wave = tid >> 6;
    const int lane = tid & 63;
    const int grp = lane >> 4;
    const int l16 = lane & 15;
    const int row = blockIdx.x * 128 + wave * 16 + l16;
    const int rc = row < M ? row : M - 1;

    short8v a[4];
#pragma unroll
    for (int kt = 0; kt < 4; ++kt)
        a[kt] = *reinterpret_cast<const short8v*>(A + (size_t)rc * 128 + kt * 32 + grp * 8);

    __syncthreads();

    f32x4 acc[8] = {};
#pragma unroll
    for (int kt = 0; kt < 4; ++kt) {
        const int joff = kt * 4 + grp;
#pragma unroll
        for (int n = 0; n < 8; ++n) {
            int brow = 16 * n + l16;
            int byte = brow * 256 + ((joff ^ (brow & 15)) << 4);
            short8v b = *reinterpret_cast<const short8v*>(
                reinterpret_cast<const char*>(Bs) + byte);
            acc[n] = __builtin_amdgcn_mfma_f32_16x16x32_bf16(b, a[kt], acc[n], 0, 0, 0);
        }
    }

    if (row >= M) return;

    const float kg = 0.7071067811865475f;
#pragma unroll
    for (int n = 0; n < 8; ++n) {
        float4 bb = *reinterpret_cast<const float4*>(bias + 16 * n + grp * 4);
        float v0 = acc[n][0] + bb.x;
        float v1 = acc[n][1] + bb.y;
        float v2 = acc[n][2] + bb.z;
        float v3 = acc[n][3] + bb.w;
        v0 = 0.5f * v0 * (1.f + erff(v0 * kg));
        v1 = 0.5f * v1 * (1.f + erff(v1 * kg));
        v2 = 0.5f * v2 * (1.f + erff(v2 * kg));
        v3 = 0.5f * v3 * (1.f + erff(v3 * kg));
        *reinterpret_cast<float4*>(out + (size_t)row * 128 + 16 * n + grp * 4) =
            make_float4(v0, v1, v2, v3);
    }
}

// ---- fused per-node gather: gcn-sum + scatter-softmax + combine ----
// Mask-free (sink-padded CSR). Optional idxmap: gid -> node; output row = gid.
__global__ __launch_bounds__(256)
void node_gather(const int* __restrict__ rowptr, const uint4* __restrict__ csr,
                 const unsigned* __restrict__ Xw, const unsigned* __restrict__ Yw,
                 unsigned short* __restrict__ outb,
                 const int* __restrict__ idxmap, int count)
{
    int gid = blockIdx.x * 4 + (threadIdx.x >> 6);
    if (gid >= count) return;
    int node = idxmap ? idxmap[gid] : gid;
    int lane = threadIdx.x & 63;

    int i = rowptr[node];
    const int end = rowptr[node + 1];

    float mg0 = 0.f, mg1 = 0.f, s0 = 0.f, s1 = 0.f, t0 = 0.f, t1 = 0.f;

    if (i < end) {
        uint4 cur[4];
#pragma unroll
        for (int q = 0; q < 4; ++q) cur[q] = csr[i + q];

        for (; i < end; i += 4) {
            uint4 nxt[4];
#pragma unroll
            for (int q = 0; q < 4; ++q) nxt[q] = csr[i + 4 + q];   // global pad covers

            unsigned xp[4], yp[4];
#pragma unroll
            for (int q = 0; q < 4; ++q) {
                xp[q] = Xw[cur[q].x + lane];
                yp[q] = Yw[cur[q].y + lane];
            }
#pragma unroll
            for (int q = 0; q < 4; ++q) {
                float nrm = __uint_as_float(cur[q].z);
                float x0 = bf2f((unsigned short)(xp[q] & 0xffffu));
                float x1 = bf2f((unsigned short)(xp[q] >> 16));
                float y0 = bf2f((unsigned short)(yp[q] & 0xffffu));
                float y1 = bf2f((unsigned short)(yp[q] >> 16));
                float w0 = __expf(y0), w1 = __expf(y1);
                mg0 = fmaf(x0, nrm, mg0);
                mg1 = fmaf(x1, nrm, mg1);
                s0 += w0; s1 += w1;
                t0 = fmaf(y0, w0, t0);
                t1 = fmaf(y1, w1, t1);
            }
#pragma unroll
            for (int q = 0; q < 4; ++q) cur[q] = nxt[q];
        }
    }

    float o0 = mg0 + 0.1f * fmaxf(s0 > 0.f ? t0 / s0 : 0.f, 0.f);
    float o1 = mg1 + 0.1f * fmaxf(s1 > 0.f ? t1 / s1 : 0.f, 0.f);
    unsigned pk = (unsigned)f2bf(o0) | ((unsigned)f2bf(o1) << 16);
    *reinterpret_cast<unsigned*>(outb + (size_t)gid * 128 + (lane << 1)) = pk;
}

// ================= launch =================
extern "C" void kernel_launch(void* const* d_in, const int* in_sizes, int n_in,
                              void* d_out, int out_size, void* d_ws, size_t ws_size,
                              hipStream_t stream)
{
    const float* x      = (const float*)d_in[0];
    const int*   ei     = (const int*)d_in[1];
    const int*   et     = (const int*)d_in[2];
    // d_in[3] edge_weight: unused by the reference
    const int*   idxp   = (const int*)d_in[4];
    const float* proj_w = (const float*)d_in[5];
    const float* proj_b = (const float*)d_in[6];
    const float* bn_g   = (const float*)d_in[7];
    const float* bn_b   = (const float*)d_in[8];
    const float* win_w[2]  = {(const float*)d_in[9],  (const float*)d_in[14]};
    const float* win_b[2]  = {(const float*)d_in[10], (const float*)d_in[15]};
    const float* wrel[2]   = {(const float*)d_in[11], (const float*)d_in[16]};
    const float* cout_w[2] = {(const float*)d_in[12], (const float*)d_in[17]};
    const float* cout_b[2] = {(const float*)d_in[13], (const float*)d_in[18]};

    const int Nn  = in_sizes[0] / 128;
    const int E   = in_sizes[1] / 2;
    const int Mo  = in_sizes[4];
    const int nrel = in_sizes[11] / (128 * 128);
    const size_t ND = (size_t)Nn * 128;

    const int HALFR = ((Nn + 3) / 4) * 2;
    const int WORDS = HALFR / 2;
    if (WORDS > HIST_MAXW) return;

    const int IA1 = 1 + nrel;
    const int IC1 = 2 + 2 * nrel;
    const int NMATS = 3 + 2 * nrel;

    // workspace layout
    char* p = (char*)d_ws;
    float* h    = (float*)p;                  p += ND * 4;
    unsigned short* hb = (unsigned short*)p;  p += ND * 2;
    unsigned short* Xb = (unsigned short*)p;  p += ND * 2;
    unsigned short* Yb = (unsigned short*)p;  p += (size_t)nrel * ND * 2 + 256;  // +sink row
    unsigned short* msgb = (unsigned short*)p; p += ND * 2;
    unsigned short* Wt = (unsigned short*)p;  p += (size_t)NMATS * 16384 * 2;
    float* WfA1 = (float*)p;                  p += (size_t)16384 * 4;
    float* biasbuf = (float*)p;               p += (size_t)NMATS * 128 * 4;
    uint4* csr  = (uint4*)p;                  p += ((size_t)E + 3 * (size_t)Nn + 16) * 16;
    unsigned* partial = (unsigned*)p;         p += (size_t)HIST_B * WORDS * 4;
    float* dis  = (float*)p;                  p += (size_t)Nn * 4;
    int*   cnt  = (int*)p;                    p += (size_t)Nn * 4;
    int*   rowptr = (int*)p;                  p += ((size_t)Nn + 1) * 4;
    int*   cursor = (int*)p;                  p += (size_t)Nn * 4;
    int*   bsum = (int*)p;                    p += 1024 * 4;
    float* bnsums = (float*)p;                p += 256 * 4;
    float* bnsc   = (float*)p;                p += 256 * 4;
    if ((size_t)(p - (char*)d_ws) > ws_size) return;

    const unsigned sink_woff = (unsigned)((size_t)nrel * Nn * 64);   // word offset in Yb

    const int gemmGrid = (Nn + 63) / 64;
    const int tiles128 = (Nn + 127) / 128;
    const size_t n4 = ND / 4;
    const int n4grid = (int)((n4 + 255) / 256);
    const int nb = (Nn + 255) / 256;
    const int nRed = (4 * WORDS + 255) / 256;
    const int nS = (E + 511) / 512;               // 512-thread scatter blocks
    const int nmats = 1 + nrel;
    const int nFused = nmats * tiles128;

    hipMemsetAsync(bnsums, 0, 256 * 4, stream);

    // histogram first (depends only on ei)
    hist_kernel<<<HIST_B, 256, 0, stream>>>(ei, partial, Nn, E, WORDS, HALFR);

    // stage-1 weight products
    kprod1<<<2 * (1 + nrel) + (1 + nrel) + 3, 256, 0, stream>>>(
        win_w[0], win_b[0], win_w[1], win_b[1], cout_w[0], cout_b[0],
        cout_w[1], cout_b[1], wrel[0], WfA1, Wt, biasbuf, nrel);

    // KMID: stage-2 products | proj GEMM (overlapped)
    kmid<<<3 * nrel + gemmGrid, 256, 0, stream>>>(
        wrel[1], WfA1, Wt, biasbuf, x, proj_w, proj_b, h, Nn, nrel);

    // K2: hist reduce (dis, cnt) | bn_stats
    k2_reduce_bnstats<<<nRed + 256, 256, 0, stream>>>(
        partial, dis, cnt, h, bnsums, Nn, WORDS, HALFR, nRed);

    // K3: bn_finalize | scan level-1 (padded counts)
    k3_bnfin_scan1<<<1 + nb, 256, 0, stream>>>(bnsums, bn_g, bn_b, bnsc, cnt, bsum, Nn);

    // K4: scan offsets | bn apply+relu -> hb
    k4_scanoff_bnapply<<<1 + n4grid, 256, 0, stream>>>(bsum, nb, h, bnsc, hb, n4);

    // K4b: scan final (padded rowptr/cursor) + sink pads + sink row
    k4b_scanfinal<<<nb + 1, 256, 0, stream>>>(cnt, bsum, rowptr, cursor, csr,
                                              (unsigned*)Yb, sink_woff, Nn, nb);

    // K5: layer-0 fused 6-mat MFMA | scatter (interleaved, 512 thr, XCD-swizzled)
    k5_mfma_scatter<<<nFused + nS, 512, 0, stream>>>(
        hb, Wt, biasbuf, Xb, Yb, Nn, nmats, nFused,
        ei, et, dis, cursor, csr, E, Nn, nS);

    // layer 0 gather (all nodes)
    node_gather<<<(Nn + 3) / 4, 256, 0, stream>>>(
        rowptr, csr, (const unsigned*)Xb, (const unsigned*)Yb, msgb, nullptr, Nn);

    // layer-1 fused 6-mat pass (all nodes, XCD-swizzled)
    k_fusedpass<<<nFused, 512, 0, stream>>>(msgb, Wt, biasbuf, Xb, Yb, IA1, Nn,
                                            nmats, nFused);

    // layer 1 gather: ONLY the idx destination nodes (dense Mo-row output)
    node_gather<<<(Mo + 3) / 4, 256, 0, stream>>>(
        rowptr, csr, (const unsigned*)Xb, (const unsigned*)Yb, msgb, idxp, Mo);

    // final: cout1 + gelu on dense Mo rows -> d_out
    k_cout_gelu<<<(Mo + 127) / 128, 512, 0, stream>>>(
        msgb, Wt, biasbuf, (float*)d_out, IC1, Mo);
}

// Round 16
// 292.280 us; speedup vs baseline: 1.4125x; 1.0606x over previous
//
#include <hip/hip_runtime.h>

#define HIST_BPG 32              // edge-slice blocks per (histogram, half) group
#define HIST_B   (HIST_BPG * 4)  // 4 groups: src-lo, src-hi, dst-lo, dst-hi
#define HIST_MAXW 12288          // max packed words (supports Nn <= ~49k)

// ---------- helpers ----------
__device__ inline float bf2f(unsigned short u) {
    return __uint_as_float(((unsigned)u) << 16);
}
__device__ inline unsigned short f2bf(float f) {
    unsigned u = __float_as_uint(f);
    u += 0x7fffu + ((u >> 16) & 1u);   // round-to-nearest-even
    return (unsigned short)(u >> 16);
}

// bijective XCD swizzle (m204)
__device__ inline int xcd_swizzle(int bid, int n)
{
    const int NX = 8;
    int q = n / NX, r = n % NX;
    int xcd = bid % NX;
    int rank = bid / NX;
    return (xcd < r) ? xcd * (q + 1) + rank : r * (q + 1) + (xcd - r) * q + rank;
}

typedef __attribute__((ext_vector_type(8))) short short8v;   // 8 bf16 (4 VGPRs)
typedef __attribute__((ext_vector_type(4))) float f32x4;

// ================= device bodies =================

// ---- f32 GEMM body (64-row tile, 256 threads): C[M x 128] = A @ W (+ bias) ----
// Optional outputs: C (f32) and Ct (bf16 transposed). __shared__ declared
// DIRECTLY (char*-cast LDS caused the r7-8 spill catastrophe).
__device__ __forceinline__
void gemmf32_body(const float* __restrict__ A, const float* __restrict__ W,
                  const float* __restrict__ bias, float* __restrict__ C,
                  unsigned short* __restrict__ Ct, int M, int tile)
{
    __shared__ float As[64][132];
    __shared__ float Ws[32][128];

    const int tid = threadIdx.x;
    const int row0 = tile * 64;

#pragma unroll
    for (int i = 0; i < 8; ++i) {
        int idx = tid + i * 256;
        int rr = idx >> 5;
        int cc = (idx & 31) << 2;
        int gr = row0 + rr;
        float4 v = make_float4(0.f, 0.f, 0.f, 0.f);
        if (gr < M) v = *reinterpret_cast<const float4*>(A + (size_t)gr * 128 + cc);
        *reinterpret_cast<float4*>(&As[rr][cc]) = v;
    }

    const int tx = tid & 15;
    const int ty = tid >> 4;
    float acc[4][8];
#pragma unroll
    for (int i = 0; i < 4; ++i)
#pragma unroll
        for (int j = 0; j < 8; ++j) acc[i][j] = 0.f;

    for (int kt = 0; kt < 4; ++kt) {
        __syncthreads();
#pragma unroll
        for (int i = 0; i < 4; ++i) {
            int idx = tid + i * 256;
            int rr = idx >> 5;
            int cc = (idx & 31) << 2;
            *reinterpret_cast<float4*>(&Ws[rr][cc]) =
                *reinterpret_cast<const float4*>(W + (size_t)(kt * 32 + rr) * 128 + cc);
        }
        __syncthreads();
#pragma unroll
        for (int kk = 0; kk < 32; ++kk) {
            const int k = kt * 32 + kk;
            float a0 = As[ty * 4 + 0][k];
            float a1 = As[ty * 4 + 1][k];
            float a2 = As[ty * 4 + 2][k];
            float a3 = As[ty * 4 + 3][k];
            float w[8];
#pragma unroll
            for (int j = 0; j < 8; ++j) w[j] = Ws[kk][tx + 16 * j];
#pragma unroll
            for (int j = 0; j < 8; ++j) {
                acc[0][j] = fmaf(a0, w[j], acc[0][j]);
                acc[1][j] = fmaf(a1, w[j], acc[1][j]);
                acc[2][j] = fmaf(a2, w[j], acc[2][j]);
                acc[3][j] = fmaf(a3, w[j], acc[3][j]);
            }
        }
    }

    float bb[8];
#pragma unroll
    for (int j = 0; j < 8; ++j) bb[j] = bias ? bias[tx + 16 * j] : 0.f;

#pragma unroll
    for (int i = 0; i < 4; ++i) {
        int gr = row0 + ty * 4 + i;
        if (gr >= M) continue;
#pragma unroll
        for (int j = 0; j < 8; ++j) {
            float v = acc[i][j] + bb[j];
            if (C)  C[(size_t)gr * 128 + tx + 16 * j] = v;
            if (Ct) Ct[(size_t)(tx + 16 * j) * 128 + gr] = f2bf(v);
        }
    }
}

// ---- MFMA GEMM body (operand-swapped), LDS-staged B, 512 THREADS ----
// 8 waves x 16 rows = 128-row tile; acc[8] + 4 prefetched A frags (~50 VGPR).
__device__ __forceinline__
void mfmaw_body(const unsigned short* __restrict__ A,
                const unsigned short* __restrict__ Wmat,
                const float* __restrict__ bias,
                float* __restrict__ Cf, unsigned short* __restrict__ Cb,
                int M, int tile)
{
    __shared__ unsigned short Bs[16384];   // 32 KB

    const int tid = threadIdx.x;
#pragma unroll
    for (int i = 0; i < 4; ++i) {
        int idx = tid + i * 512;                 // 16B chunk id, 0..2047
        uint4 v = *reinterpret_cast<const uint4*>(Wmat + (size_t)idx * 8);
        int row = idx >> 4;
        int j = idx & 15;
        int byte = row * 256 + ((j ^ (row & 15)) << 4);
        *reinterpret_cast<uint4*>(reinterpret_cast<char*>(Bs) + byte) = v;
    }

    const int wave = tid >> 6;                   // 0..7
    const int lane = tid & 63;
    const int grp = lane >> 4;
    const int l16 = lane & 15;
    const int row = tile * 128 + wave * 16 + l16;
    const int rc = row < M ? row : M - 1;        // clamp; tail rows not stored

    short8v a[4];
#pragma unroll
    for (int kt = 0; kt < 4; ++kt)
        a[kt] = *reinterpret_cast<const short8v*>(A + (size_t)rc * 128 + kt * 32 + grp * 8);

    __syncthreads();

    f32x4 acc[8] = {};
#pragma unroll
    for (int kt = 0; kt < 4; ++kt) {
        const int joff = kt * 4 + grp;           // k-chunk index 0..15
#pragma unroll
        for (int n = 0; n < 8; ++n) {
            int brow = 16 * n + l16;
            int byte = brow * 256 + ((joff ^ (brow & 15)) << 4);
            short8v b = *reinterpret_cast<const short8v*>(
                reinterpret_cast<const char*>(Bs) + byte);
            acc[n] = __builtin_amdgcn_mfma_f32_16x16x32_bf16(b, a[kt], acc[n], 0, 0, 0);
        }
    }

    if (row >= M) return;   // no barriers past this point

    float4 bb[8];
#pragma unroll
    for (int n = 0; n < 8; ++n)
        bb[n] = bias ? *reinterpret_cast<const float4*>(bias + 16 * n + grp * 4)
                     : make_float4(0.f, 0.f, 0.f, 0.f);

#pragma unroll
    for (int n = 0; n < 8; ++n) {
        float v0 = acc[n][0] + bb[n].x;
        float v1 = acc[n][1] + bb[n].y;
        float v2 = acc[n][2] + bb[n].z;
        float v3 = acc[n][3] + bb[n].w;
        if (Cf) {
            *reinterpret_cast<float4*>(Cf + (size_t)row * 128 + 16 * n + grp * 4) =
                make_float4(v0, v1, v2, v3);
        }
        if (Cb) {
            unsigned u0 = (unsigned)f2bf(v0) | ((unsigned)f2bf(v1) << 16);
            unsigned u1 = (unsigned)f2bf(v2) | ((unsigned)f2bf(v3) << 16);
            *reinterpret_cast<uint2*>(Cb + (size_t)row * 128 + 16 * n + grp * 4) =
                make_uint2(u0, u1);
        }
    }
}

// fused 6-mat pass dispatch; XCD-swizzled (tile-major within XCD)
__device__ void fused_dispatch(const unsigned short* A, const unsigned short* Wt,
                               const float* biasbuf, unsigned short* Xb,
                               unsigned short* Yb, int base, int M, int nmats,
                               int bid, int nF)
{
    int w = xcd_swizzle(bid, nF);
    int m = w % nmats;
    int tile = w / nmats;
    unsigned short* out = (m == 0) ? Xb : Yb + (size_t)(m - 1) * (size_t)M * 128;
    mfmaw_body(A, Wt + (size_t)(base + m) * 16384,
               biasbuf + (size_t)(base + m) * 128, nullptr, out, M, tile);
}

// ---- bias product body: out[t] = sum_j v[j]*W[j*128+t] (+ add[t]) ----
__device__ void biasprod_body(const float* __restrict__ v, const float* __restrict__ W,
                              const float* __restrict__ add, float* __restrict__ out)
{
    int t = threadIdx.x;
    if (t >= 128) return;
    float s = add ? add[t] : 0.f;
    for (int j = 0; j < 128; ++j) s = fmaf(v[j], W[(size_t)j * 128 + t], s);
    out[t] = s;
}

// ---- bf16-transpose convert body: Wt[mat] <- f32 W[k][n] ----
__device__ void wtconv_body(const float* __restrict__ W, unsigned short* __restrict__ O)
{
    for (int i = threadIdx.x; i < 16384; i += 256) {
        int k = i >> 7, n = i & 127;
        O[(size_t)n * 128 + k] = f2bf(W[i]);
    }
}

// ---- bn stats body ----
__device__ void bn_stats_body(const float* __restrict__ h, float* __restrict__ sums,
                              int Nn, int b)
{
    const int c = threadIdx.x & 127;
    const int half = threadIdx.x >> 7;
    float s = 0.f, q = 0.f;
    for (int row = b * 2 + half; row < Nn; row += 512) {
        float v = h[(size_t)row * 128 + c];
        s += v;
        q += v * v;
    }
    __shared__ float ls[256], lq[256];
    ls[threadIdx.x] = s;
    lq[threadIdx.x] = q;
    __syncthreads();
    if (half == 0) {
        s += ls[threadIdx.x + 128];
        q += lq[threadIdx.x + 128];
        atomicAdd(&sums[c], s);
        atomicAdd(&sums[128 + c], q);
    }
}

// ---- scan bodies (counts padded to multiple of 4 for CSR 4-unroll) ----
__device__ void scan_block_sums_body(const int* __restrict__ cnt, int* __restrict__ bsum,
                                     int Nn, int b)
{
    __shared__ int sd[256];
    int tid = threadIdx.x;
    int i = b * 256 + tid;
    sd[tid] = i < Nn ? ((cnt[i] + 3) & ~3) : 0;
    __syncthreads();
#pragma unroll
    for (int s = 128; s > 0; s >>= 1) {
        if (tid < s) sd[tid] += sd[tid + s];
        __syncthreads();
    }
    if (tid == 0) bsum[b] = sd[0];
}

__device__ void scan_offsets_body(int* __restrict__ bsum, int nb)   // nb <= 256
{
    __shared__ int sd[256];
    int tid = threadIdx.x;
    int v = tid < nb ? bsum[tid] : 0;
    sd[tid] = v;
    __syncthreads();
    for (int d = 1; d < 256; d <<= 1) {
        int t = tid >= d ? sd[tid - d] : 0;
        __syncthreads();
        sd[tid] += t;
        __syncthreads();
    }
    if (tid < nb) bsum[tid] = sd[tid] - v;   // exclusive
}

// ================= kernels =================

// histogram (standalone, low VGPR, no global atomics)
__global__ __launch_bounds__(256)
void hist_kernel(const int* __restrict__ ei, unsigned* __restrict__ partial,
                 int Nn, int E, int WORDS, int HALFR)
{
    __shared__ unsigned sh[HIST_MAXW];
    const int hbid = blockIdx.x;
    const int g = hbid / HIST_BPG;
    const int j = hbid - g * HIST_BPG;

    for (int w = threadIdx.x; w < WORDS; w += 256) sh[w] = 0;
    __syncthreads();

    const int* col = (g < 2) ? (ei + E) : ei;
    const int base = (g & 1) * HALFR;
    const size_t e0 = (size_t)E * j / HIST_BPG;
    const size_t e1 = (size_t)E * (j + 1) / HIST_BPG;
    for (size_t e = e0 + threadIdx.x; e < e1; e += 256) {
        int n = col[e] - base;
        if ((unsigned)n < (unsigned)HALFR)
            atomicAdd(&sh[n >> 1], 1u << ((n & 1) * 16));
    }
    __syncthreads();

    unsigned* out = partial + (size_t)hbid * WORDS;
    for (int w = threadIdx.x; w < WORDS; w += 256) out[w] = sh[w];
}

// KP1: stage-1 weight products + biases + converts + x->bf16 conversion.
// Wt slots: 0:A0(win0) 1..nrel:B0_r IA1:A1 IB1..:B1_r IC1:cout1 IPRJ:proj_w
__global__ __launch_bounds__(256)
void kprod1(const float* win0w, const float* win0b, const float* win1w, const float* win1b,
            const float* cout0w, const float* cout0b, const float* cout1w,
            const float* cout1b, const float* wrel0,
            const float* x, const float* proj_w, const float* proj_b,
            unsigned short* xb, float* WfA1, unsigned short* Wt, float* biasbuf,
            int nrel, size_t nx4)
{
    const int IA1 = 1 + nrel, IC1 = 2 + 2 * nrel, IPRJ = 3 + 2 * nrel;
    const int nProd = 1 + nrel;
    int bid = blockIdx.x;
    if (bid < 2 * nProd) {
        int p = bid >> 1, tile = bid & 1;
        if (p == 0)
            gemmf32_body(cout0w, win1w, nullptr, WfA1, Wt + (size_t)IA1 * 16384, 128, tile);
        else
            gemmf32_body(win0w, wrel0 + (size_t)(p - 1) * 16384, nullptr,
                         nullptr, Wt + (size_t)p * 16384, 128, tile);
        return;
    }
    bid -= 2 * nProd;
    if (bid < nProd) {
        if (bid == 0) biasprod_body(cout0b, win1w, win1b, biasbuf + (size_t)IA1 * 128);
        else biasprod_body(win0b, wrel0 + (size_t)(bid - 1) * 16384, nullptr,
                           biasbuf + (size_t)bid * 128);
        return;
    }
    bid -= nProd;
    if (bid == 0) { wtconv_body(win0w, Wt); return; }
    if (bid == 1) { wtconv_body(cout1w, Wt + (size_t)IC1 * 16384); return; }
    if (bid == 2) { wtconv_body(proj_w, Wt + (size_t)IPRJ * 16384); return; }
    if (bid == 3) {
        int t = threadIdx.x;
        if (t < 128) {
            biasbuf[t] = win0b[t];
            biasbuf[(size_t)IC1 * 128 + t] = cout1b[t];
            biasbuf[(size_t)IPRJ * 128 + t] = proj_b[t];
        }
        return;
    }
    // x -> bf16 conversion (float4 -> ushort4)
    size_t i = (size_t)(bid - 4) * 256 + threadIdx.x;
    if (i < nx4) {
        float4 v = reinterpret_cast<const float4*>(x)[i];
        ushort4 pk = make_ushort4(f2bf(v.x), f2bf(v.y), f2bf(v.z), f2bf(v.w));
        reinterpret_cast<ushort4*>(xb)[i] = pk;
    }
}

// KPROJ: h = xb @ proj_w + b  (MFMA, f32 out)
__global__ __launch_bounds__(512)
void kproj(const unsigned short* xb, const unsigned short* Wt, const float* biasbuf,
           float* h, int mat, int M)
{
    mfmaw_body(xb, Wt + (size_t)mat * 16384, biasbuf + (size_t)mat * 128,
               h, nullptr, M, blockIdx.x);
}

// K2: hist-reduce (-> dis, cnt) | bn_stats
__global__ __launch_bounds__(256)
void k2_reduce_bnstats(const unsigned* __restrict__ partial, float* __restrict__ dis,
                       int* __restrict__ cnt, const float* __restrict__ h,
                       float* __restrict__ bnsums, int Nn, int WORDS, int HALFR, int nRed)
{
    int bid = blockIdx.x;
    if (bid < nRed) {
        int t = bid * 256 + threadIdx.x;
        if (t < 4 * WORDS) {
            int histo = t / (2 * WORDS);
            int rem = t - histo * 2 * WORDS;
            int half = rem / WORDS;
            int w = rem - half * WORDS;
            int g = histo * 2 + half;
            unsigned slo = 0, shi = 0;
            const unsigned* p = partial + (size_t)(g * HIST_BPG) * WORDS + w;
#pragma unroll 4
            for (int j = 0; j < HIST_BPG; ++j) {
                unsigned u = p[(size_t)j * WORDS];
                slo += u & 0xffffu;
                shi += u >> 16;
            }
            int n0 = half * HALFR + 2 * w;
            int n1 = n0 + 1;
            if (histo == 0) {
                if (n0 < Nn) dis[n0] = slo ? rsqrtf((float)slo) : 0.f;
                if (n1 < Nn) dis[n1] = shi ? rsqrtf((float)shi) : 0.f;
            } else {
                if (n0 < Nn) cnt[n0] = (int)slo;
                if (n1 < Nn) cnt[n1] = (int)shi;
            }
        }
        return;
    }
    bn_stats_body(h, bnsums, Nn, bid - nRed);
}

// K3: kprod2 (stage-2 products) | bn_finalize | scan_block_sums
// kprod2 blocks first: B1_r = A1 @ wrel1_r ; bB1_r = bA1 @ wrel1_r
__global__ __launch_bounds__(256)
void k3_prod2_bnfin_scan1(const float* wrel1, const float* WfA1,
                          unsigned short* Wt, float* biasbuf, int nrel,
                          const float* __restrict__ sums, const float* __restrict__ g,
                          const float* __restrict__ b, float* __restrict__ sc,
                          const int* __restrict__ cnt, int* __restrict__ bsum, int Nn)
{
    const int IA1 = 1 + nrel, IB1 = 2 + nrel;
    int bid = blockIdx.x;
    if (bid < 2 * nrel) {
        int p = bid >> 1, tile = bid & 1;
        gemmf32_body(WfA1, wrel1 + (size_t)p * 16384, nullptr,
                     nullptr, Wt + (size_t)(IB1 + p) * 16384, 128, tile);
        return;
    }
    bid -= 2 * nrel;
    if (bid < nrel) {
        biasprod_body(biasbuf + (size_t)IA1 * 128, wrel1 + (size_t)bid * 16384, nullptr,
                      biasbuf + (size_t)(IB1 + bid) * 128);
        return;
    }
    bid -= nrel;
    if (bid == 0) {
        int c = threadIdx.x;
        if (c < 128) {
            float inv = 1.f / (float)Nn;
            float mu = sums[c] * inv;
            float var = sums[128 + c] * inv - mu * mu;
            float rstd = rsqrtf(var + 1e-5f);
            float scale = rstd * g[c];
            sc[c] = scale;
            sc[128 + c] = b[c] - mu * scale;
        }
        return;
    }
    scan_block_sums_body(cnt, bsum, Nn, bid - 1);
}

// K4: scan_offsets | bn_apply_relu (f32 -> bf16)
__global__ __launch_bounds__(256)
void k4_scanoff_bnapply(int* __restrict__ bsum, int nb,
                        const float* __restrict__ h, const float* __restrict__ sc,
                        unsigned short* __restrict__ hb, size_t n4)
{
    if (blockIdx.x == 0) { scan_offsets_body(bsum, nb); return; }
    size_t i = (size_t)(blockIdx.x - 1) * 256 + threadIdx.x;
    if (i >= n4) return;
    int c = (int)(i & 31) << 2;
    float4 v = reinterpret_cast<const float4*>(h)[i];
    float o0 = fmaxf(fmaf(v.x, sc[c + 0], sc[128 + c + 0]), 0.f);
    float o1 = fmaxf(fmaf(v.y, sc[c + 1], sc[128 + c + 1]), 0.f);
    float o2 = fmaxf(fmaf(v.z, sc[c + 2], sc[128 + c + 2]), 0.f);
    float o3 = fmaxf(fmaf(v.w, sc[c + 3], sc[128 + c + 3]), 0.f);
    ushort4 pk = make_ushort4(f2bf(o0), f2bf(o1), f2bf(o2), f2bf(o3));
    reinterpret_cast<ushort4*>(hb)[i] = pk;
}

// K4b: scan_final with 4-padded offsets; rowptr/cursor, sink pads, sink row.
__global__ __launch_bounds__(256)
void k4b_scanfinal(const int* __restrict__ cnt, const int* __restrict__ bsum,
                   int* __restrict__ rowptr, int* __restrict__ cursor,
                   uint4* __restrict__ csr, unsigned* __restrict__ Yw,
                   unsigned sink_woff, int Nn, int nb)
{
    if ((int)blockIdx.x == nb) {
        int t = threadIdx.x;
        if (t < 64) Yw[sink_woff + t] = 0xC2C8C2C8u;   // bf16 -100 pair
        return;
    }
    __shared__ int sd[256];
    int tid = threadIdx.x;
    int b = blockIdx.x;
    int i = b * 256 + tid;
    int v = i < Nn ? cnt[i] : 0;
    int pv = (v + 3) & ~3;
    sd[tid] = pv;
    __syncthreads();
    for (int d = 1; d < 256; d <<= 1) {
        int t2 = tid >= d ? sd[tid - d] : 0;
        __syncthreads();
        sd[tid] += t2;
        __syncthreads();
    }
    if (i < Nn) {
        int off = sd[tid] - pv + bsum[b];
        rowptr[i] = off;
        cursor[i] = off;
        uint4 sink = make_uint4(0u, sink_woff, 0u, 0u);
        for (int j = v; j < pv; ++j) csr[off + j] = sink;
        if (i == Nn - 1) {
            rowptr[Nn] = off + pv;
            for (int q = 0; q < 8; ++q) csr[off + pv + q] = sink;   // global pad
        }
    }
}

// K5: layer-0 fused 6-mat MFMA | scatter (interleaved), 512 threads
__global__ __launch_bounds__(512)
void k5_mfma_scatter(const unsigned short* hb, const unsigned short* Wt,
                     const float* biasbuf, unsigned short* Xb, unsigned short* Yb,
                     int M, int nmats, int nF,
                     const int* __restrict__ ei, const int* __restrict__ et,
                     const float* __restrict__ dis, int* __restrict__ cursor,
                     uint4* __restrict__ csr, int E, int Nn, int nS)
{
    const int minv = nF < nS ? nF : nS;
    int bid = blockIdx.x;
    int fIdx = -1, sIdx = -1;
    if (bid < 2 * minv) {
        if (bid & 1) fIdx = bid >> 1; else sIdx = bid >> 1;
    } else {
        int rem = bid - 2 * minv;
        if (nF > nS) fIdx = minv + rem; else sIdx = minv + rem;
    }
    if (sIdx >= 0) {
        int e = sIdx * 512 + threadIdx.x;
        if (e < E) {
            int dst = ei[e];
            int src = ei[E + e];
            int pos = atomicAdd(&cursor[dst], 1);
            float nrm = dis[dst] * dis[src];
            csr[pos] = make_uint4((unsigned)(src * 64),
                                  (unsigned)((et[e] * Nn + src) * 64),
                                  __float_as_uint(nrm), 0u);
        }
        return;
    }
    fused_dispatch(hb, Wt, biasbuf, Xb, Yb, 0, M, nmats, fIdx, nF);
}

// fused 6-mat MFMA pass (generic base, layer 1), 512 threads
__global__ __launch_bounds__(512)
void k_fusedpass(const unsigned short* A, const unsigned short* Wt, const float* biasbuf,
                 unsigned short* Xb, unsigned short* Yb, int base, int M, int nmats,
                 int nF)
{
    fused_dispatch(A, Wt, biasbuf, Xb, Yb, base, M, nmats, blockIdx.x, nF);
}

// final: out[row] = gelu(msg_dense[row] @ cout1 + b), f32, dense M rows, 512 thr
__global__ __launch_bounds__(512)
void k_cout_gelu(const unsigned short* __restrict__ A, const unsigned short* Wt,
                 const float* biasbuf, float* __restrict__ out, int mat, int M)
{
    const unsigned short* Wmat = Wt + (size_t)mat * 16384;
    const float* bias = biasbuf + (size_t)mat * 128;

    __shared__ unsigned short Bs[16384];
    const int tid = threadIdx.x;
#pragma unroll
    for (int i = 0; i < 4; ++i) {
        int idx = tid + i * 512;
        uint4 v = *reinterpret_cast<const uint4*>(Wmat + (size_t)idx * 8);
        int row = idx >> 4;
        int j = idx & 15;
        int byte = row * 256 + ((j ^ (row & 15)) << 4);
        *reinterpret_cast<uint4*>(reinterpret_cast<char*>(Bs) + byte) = v;
    }

    const int wave = tid >> 6;
    const int lane = tid & 63;
    const int grp = lane >> 4;
    const int l16 = lane & 15;
    const int row = blockIdx.x * 128 + wave * 16 + l16;
    const int rc = row < M ? row : M - 1;

    short8v a[4];
#pragma unroll
    for (int kt = 0; kt < 4; ++kt)
        a[kt] = *reinterpret_cast<const short8v*>(A + (size_t)rc * 128 + kt * 32 + grp * 8);

    __syncthreads();

    f32x4 acc[8] = {};
#pragma unroll
    for (int kt = 0; kt < 4; ++kt) {
        const int joff = kt * 4 + grp;
#pragma unroll
        for (int n = 0; n < 8; ++n) {
            int brow = 16 * n + l16;
            int byte = brow * 256 + ((joff ^ (brow & 15)) << 4);
            short8v b = *reinterpret_cast<const short8v*>(
                reinterpret_cast<const char*>(Bs) + byte);
            acc[n] = __builtin_amdgcn_mfma_f32_16x16x32_bf16(b, a[kt], acc[n], 0, 0, 0);
        }
    }

    if (row >= M) return;

    const float kg = 0.7071067811865475f;
#pragma unroll
    for (int n = 0; n < 8; ++n) {
        float4 bb = *reinterpret_cast<const float4*>(bias + 16 * n + grp * 4);
        float v0 = acc[n][0] + bb.x;
        float v1 = acc[n][1] + bb.y;
        float v2 = acc[n][2] + bb.z;
        float v3 = acc[n][3] + bb.w;
        v0 = 0.5f * v0 * (1.f + erff(v0 * kg));
        v1 = 0.5f * v1 * (1.f + erff(v1 * kg));
        v2 = 0.5f * v2 * (1.f + erff(v2 * kg));
        v3 = 0.5f * v3 * (1.f + erff(v3 * kg));
        *reinterpret_cast<float4*>(out + (size_t)row * 128 + 16 * n + grp * 4) =
            make_float4(v0, v1, v2, v3);
    }
}

// ---- fused per-node gather: gcn-sum + scatter-softmax + combine ----
__global__ __launch_bounds__(256)
void node_gather(const int* __restrict__ rowptr, const uint4* __restrict__ csr,
                 const unsigned* __restrict__ Xw, const unsigned* __restrict__ Yw,
                 unsigned short* __restrict__ outb,
                 const int* __restrict__ idxmap, int count)
{
    int gid = blockIdx.x * 4 + (threadIdx.x >> 6);
    if (gid >= count) return;
    int node = idxmap ? idxmap[gid] : gid;
    int lane = threadIdx.x & 63;

    int i = rowptr[node];
    const int end = rowptr[node + 1];

    float mg0 = 0.f, mg1 = 0.f, s0 = 0.f, s1 = 0.f, t0 = 0.f, t1 = 0.f;

    if (i < end) {
        uint4 cur[4];
#pragma unroll
        for (int q = 0; q < 4; ++q) cur[q] = csr[i + q];

        for (; i < end; i += 4) {
            uint4 nxt[4];
#pragma unroll
            for (int q = 0; q < 4; ++q) nxt[q] = csr[i + 4 + q];   // global pad covers

            unsigned xp[4], yp[4];
#pragma unroll
            for (int q = 0; q < 4; ++q) {
                xp[q] = Xw[cur[q].x + lane];
                yp[q] = Yw[cur[q].y + lane];
            }
#pragma unroll
            for (int q = 0; q < 4; ++q) {
                float nrm = __uint_as_float(cur[q].z);
                float x0 = bf2f((unsigned short)(xp[q] & 0xffffu));
                float x1 = bf2f((unsigned short)(xp[q] >> 16));
                float y0 = bf2f((unsigned short)(yp[q] & 0xffffu));
                float y1 = bf2f((unsigned short)(yp[q] >> 16));
                float w0 = __expf(y0), w1 = __expf(y1);
                mg0 = fmaf(x0, nrm, mg0);
                mg1 = fmaf(x1, nrm, mg1);
                s0 += w0; s1 += w1;
                t0 = fmaf(y0, w0, t0);
                t1 = fmaf(y1, w1, t1);
            }
#pragma unroll
            for (int q = 0; q < 4; ++q) cur[q] = nxt[q];
        }
    }

    float o0 = mg0 + 0.1f * fmaxf(s0 > 0.f ? t0 / s0 : 0.f, 0.f);
    float o1 = mg1 + 0.1f * fmaxf(s1 > 0.f ? t1 / s1 : 0.f, 0.f);
    unsigned pk = (unsigned)f2bf(o0) | ((unsigned)f2bf(o1) << 16);
    *reinterpret_cast<unsigned*>(outb + (size_t)gid * 128 + (lane << 1)) = pk;
}

// ================= launch =================
extern "C" void kernel_launch(void* const* d_in, const int* in_sizes, int n_in,
                              void* d_out, int out_size, void* d_ws, size_t ws_size,
                              hipStream_t stream)
{
    const float* x      = (const float*)d_in[0];
    const int*   ei     = (const int*)d_in[1];
    const int*   et     = (const int*)d_in[2];
    // d_in[3] edge_weight: unused by the reference
    const int*   idxp   = (const int*)d_in[4];
    const float* proj_w = (const float*)d_in[5];
    const float* proj_b = (const float*)d_in[6];
    const float* bn_g   = (const float*)d_in[7];
    const float* bn_b   = (const float*)d_in[8];
    const float* win_w[2]  = {(const float*)d_in[9],  (const float*)d_in[14]};
    const float* win_b[2]  = {(const float*)d_in[10], (const float*)d_in[15]};
    const float* wrel[2]   = {(const float*)d_in[11], (const float*)d_in[16]};
    const float* cout_w[2] = {(const float*)d_in[12], (const float*)d_in[17]};
    const float* cout_b[2] = {(const float*)d_in[13], (const float*)d_in[18]};

    const int Nn  = in_sizes[0] / 128;
    const int E   = in_sizes[1] / 2;
    const int Mo  = in_sizes[4];
    const int nrel = in_sizes[11] / (128 * 128);
    const size_t ND = (size_t)Nn * 128;

    const int HALFR = ((Nn + 3) / 4) * 2;
    const int WORDS = HALFR / 2;
    if (WORDS > HIST_MAXW) return;

    const int IA1 = 1 + nrel;
    const int IC1 = 2 + 2 * nrel;
    const int IPRJ = 3 + 2 * nrel;
    const int NMATS = 4 + 2 * nrel;   // + proj slot

    // workspace layout
    char* p = (char*)d_ws;
    float* h    = (float*)p;                  p += ND * 4;
    unsigned short* hb = (unsigned short*)p;  p += ND * 2;
    unsigned short* xb = (unsigned short*)p;  p += ND * 2;            // bf16 x
    unsigned short* Xb = (unsigned short*)p;  p += ND * 2;
    unsigned short* Yb = (unsigned short*)p;  p += (size_t)nrel * ND * 2 + 256;  // +sink row
    unsigned short* msgb = (unsigned short*)p; p += ND * 2;
    unsigned short* Wt = (unsigned short*)p;  p += (size_t)NMATS * 16384 * 2;
    float* WfA1 = (float*)p;                  p += (size_t)16384 * 4;
    float* biasbuf = (float*)p;               p += (size_t)NMATS * 128 * 4;
    uint4* csr  = (uint4*)p;                  p += ((size_t)E + 3 * (size_t)Nn + 16) * 16;
    unsigned* partial = (unsigned*)p;         p += (size_t)HIST_B * WORDS * 4;
    float* dis  = (float*)p;                  p += (size_t)Nn * 4;
    int*   cnt  = (int*)p;                    p += (size_t)Nn * 4;
    int*   rowptr = (int*)p;                  p += ((size_t)Nn + 1) * 4;
    int*   cursor = (int*)p;                  p += (size_t)Nn * 4;
    int*   bsum = (int*)p;                    p += 1024 * 4;
    float* bnsums = (float*)p;                p += 256 * 4;
    float* bnsc   = (float*)p;                p += 256 * 4;
    if ((size_t)(p - (char*)d_ws) > ws_size) return;

    const unsigned sink_woff = (unsigned)((size_t)nrel * Nn * 64);   // word offset in Yb

    const int tiles128 = (Nn + 127) / 128;
    const size_t n4 = ND / 4;
    const int n4grid = (int)((n4 + 255) / 256);
    const int nb = (Nn + 255) / 256;
    const int nRed = (4 * WORDS + 255) / 256;
    const int nS = (E + 511) / 512;
    const int nmats = 1 + nrel;
    const int nFused = nmats * tiles128;
    const int nConv = (int)((n4 + 255) / 256);   // x->bf16 blocks

    hipMemsetAsync(bnsums, 0, 256 * 4, stream);

    // histogram (depends only on ei)
    hist_kernel<<<HIST_B, 256, 0, stream>>>(ei, partial, Nn, E, WORDS, HALFR);

    // stage-1 weight products + converts + x->bf16
    kprod1<<<2 * (1 + nrel) + (1 + nrel) + 4 + nConv, 256, 0, stream>>>(
        win_w[0], win_b[0], win_w[1], win_b[1], cout_w[0], cout_b[0],
        cout_w[1], cout_b[1], wrel[0], x, proj_w, proj_b,
        xb, WfA1, Wt, biasbuf, nrel, n4);

    // proj via MFMA: h = xb @ proj_w + b (f32)
    kproj<<<tiles128, 512, 0, stream>>>(xb, Wt, biasbuf, h, IPRJ, Nn);

    // K2: hist reduce (dis, cnt) | bn_stats
    k2_reduce_bnstats<<<nRed + 256, 256, 0, stream>>>(
        partial, dis, cnt, h, bnsums, Nn, WORDS, HALFR, nRed);

    // K3: kprod2 | bn_finalize | scan level-1 (padded counts)
    k3_prod2_bnfin_scan1<<<3 * nrel + 1 + nb, 256, 0, stream>>>(
        wrel[1], WfA1, Wt, biasbuf, nrel,
        bnsums, bn_g, bn_b, bnsc, cnt, bsum, Nn);

    // K4: scan offsets | bn apply+relu -> hb
    k4_scanoff_bnapply<<<1 + n4grid, 256, 0, stream>>>(bsum, nb, h, bnsc, hb, n4);

    // K4b: scan final (padded rowptr/cursor) + sink pads + sink row
    k4b_scanfinal<<<nb + 1, 256, 0, stream>>>(cnt, bsum, rowptr, cursor, csr,
                                              (unsigned*)Yb, sink_woff, Nn, nb);

    // K5: layer-0 fused 6-mat MFMA | scatter (interleaved, 512 thr, XCD-swizzled)
    k5_mfma_scatter<<<nFused + nS, 512, 0, stream>>>(
        hb, Wt, biasbuf, Xb, Yb, Nn, nmats, nFused,
        ei, et, dis, cursor, csr, E, Nn, nS);

    // layer 0 gather (all nodes)
    node_gather<<<(Nn + 3) / 4, 256, 0, stream>>>(
        rowptr, csr, (const unsigned*)Xb, (const unsigned*)Yb, msgb, nullptr, Nn);

    // layer-1 fused 6-mat pass (all nodes, XCD-swizzled)
    k_fusedpass<<<nFused, 512, 0, stream>>>(msgb, Wt, biasbuf, Xb, Yb, IA1, Nn,
                                            nmats, nFused);

    // layer 1 gather: ONLY the idx destination nodes (dense Mo-row output)
    node_gather<<<(Mo + 3) / 4, 256, 0, stream>>>(
        rowptr, csr, (const unsigned*)Xb, (const unsigned*)Yb, msgb, idxp, Mo);

    // final: cout1 + gelu on dense Mo rows -> d_out
    k_cout_gelu<<<(Mo + 127) / 128, 512, 0, stream>>>(
        msgb, Wt, biasbuf, (float*)d_out, IC1, Mo);
}

// Round 17
// 291.521 us; speedup vs baseline: 1.4162x; 1.0026x over previous
//
#include <hip/hip_runtime.h>

#define HIST_BPG 32              // edge-slice blocks per (histogram, half) group
#define HIST_B   (HIST_BPG * 4)  // 4 groups: src-lo, src-hi, dst-lo, dst-hi
#define HIST_MAXW 12288          // max packed words (supports Nn <= ~49k)

// ---------- helpers ----------
__device__ inline float bf2f(unsigned short u) {
    return __uint_as_float(((unsigned)u) << 16);
}
__device__ inline unsigned short f2bf(float f) {
    unsigned u = __float_as_uint(f);
    u += 0x7fffu + ((u >> 16) & 1u);   // round-to-nearest-even
    return (unsigned short)(u >> 16);
}

// bijective XCD swizzle (m204)
__device__ inline int xcd_swizzle(int bid, int n)
{
    const int NX = 8;
    int q = n / NX, r = n % NX;
    int xcd = bid % NX;
    int rank = bid / NX;
    return (xcd < r) ? xcd * (q + 1) + rank : r * (q + 1) + (xcd - r) * q + rank;
}

typedef __attribute__((ext_vector_type(8))) short short8v;   // 8 bf16 (4 VGPRs)
typedef __attribute__((ext_vector_type(4))) float f32x4;

// ================= device bodies =================

// ---- f32 GEMM body (64-row tile, 256 threads): C[M x 128] = A @ W (+ bias) ----
// Optional outputs: C (f32) and Ct (bf16 transposed). __shared__ declared
// DIRECTLY (char*-cast LDS caused the r7-8 spill catastrophe).
__device__ __forceinline__
void gemmf32_body(const float* __restrict__ A, const float* __restrict__ W,
                  const float* __restrict__ bias, float* __restrict__ C,
                  unsigned short* __restrict__ Ct, int M, int tile)
{
    __shared__ float As[64][132];
    __shared__ float Ws[32][128];

    const int tid = threadIdx.x;
    const int row0 = tile * 64;

#pragma unroll
    for (int i = 0; i < 8; ++i) {
        int idx = tid + i * 256;
        int rr = idx >> 5;
        int cc = (idx & 31) << 2;
        int gr = row0 + rr;
        float4 v = make_float4(0.f, 0.f, 0.f, 0.f);
        if (gr < M) v = *reinterpret_cast<const float4*>(A + (size_t)gr * 128 + cc);
        *reinterpret_cast<float4*>(&As[rr][cc]) = v;
    }

    const int tx = tid & 15;
    const int ty = tid >> 4;
    float acc[4][8];
#pragma unroll
    for (int i = 0; i < 4; ++i)
#pragma unroll
        for (int j = 0; j < 8; ++j) acc[i][j] = 0.f;

    for (int kt = 0; kt < 4; ++kt) {
        __syncthreads();
#pragma unroll
        for (int i = 0; i < 4; ++i) {
            int idx = tid + i * 256;
            int rr = idx >> 5;
            int cc = (idx & 31) << 2;
            *reinterpret_cast<float4*>(&Ws[rr][cc]) =
                *reinterpret_cast<const float4*>(W + (size_t)(kt * 32 + rr) * 128 + cc);
        }
        __syncthreads();
#pragma unroll
        for (int kk = 0; kk < 32; ++kk) {
            const int k = kt * 32 + kk;
            float a0 = As[ty * 4 + 0][k];
            float a1 = As[ty * 4 + 1][k];
            float a2 = As[ty * 4 + 2][k];
            float a3 = As[ty * 4 + 3][k];
            float w[8];
#pragma unroll
            for (int j = 0; j < 8; ++j) w[j] = Ws[kk][tx + 16 * j];
#pragma unroll
            for (int j = 0; j < 8; ++j) {
                acc[0][j] = fmaf(a0, w[j], acc[0][j]);
                acc[1][j] = fmaf(a1, w[j], acc[1][j]);
                acc[2][j] = fmaf(a2, w[j], acc[2][j]);
                acc[3][j] = fmaf(a3, w[j], acc[3][j]);
            }
        }
    }

    float bb[8];
#pragma unroll
    for (int j = 0; j < 8; ++j) bb[j] = bias ? bias[tx + 16 * j] : 0.f;

#pragma unroll
    for (int i = 0; i < 4; ++i) {
        int gr = row0 + ty * 4 + i;
        if (gr >= M) continue;
#pragma unroll
        for (int j = 0; j < 8; ++j) {
            float v = acc[i][j] + bb[j];
            if (C)  C[(size_t)gr * 128 + tx + 16 * j] = v;
            if (Ct) Ct[(size_t)(tx + 16 * j) * 128 + gr] = f2bf(v);
        }
    }
}

// ---- MFMA GEMM body (operand-swapped), LDS-staged B, 512 THREADS ----
// 8 waves x 16 rows = 128-row tile; acc[8] + 4 prefetched A frags (~50 VGPR).
__device__ __forceinline__
void mfmaw_body(const unsigned short* __restrict__ A,
                const unsigned short* __restrict__ Wmat,
                const float* __restrict__ bias,
                float* __restrict__ Cf, unsigned short* __restrict__ Cb,
                int M, int tile)
{
    __shared__ unsigned short Bs[16384];   // 32 KB

    const int tid = threadIdx.x;
#pragma unroll
    for (int i = 0; i < 4; ++i) {
        int idx = tid + i * 512;                 // 16B chunk id, 0..2047
        uint4 v = *reinterpret_cast<const uint4*>(Wmat + (size_t)idx * 8);
        int row = idx >> 4;
        int j = idx & 15;
        int byte = row * 256 + ((j ^ (row & 15)) << 4);
        *reinterpret_cast<uint4*>(reinterpret_cast<char*>(Bs) + byte) = v;
    }

    const int wave = tid >> 6;                   // 0..7
    const int lane = tid & 63;
    const int grp = lane >> 4;
    const int l16 = lane & 15;
    const int row = tile * 128 + wave * 16 + l16;
    const int rc = row < M ? row : M - 1;        // clamp; tail rows not stored

    short8v a[4];
#pragma unroll
    for (int kt = 0; kt < 4; ++kt)
        a[kt] = *reinterpret_cast<const short8v*>(A + (size_t)rc * 128 + kt * 32 + grp * 8);

    __syncthreads();

    f32x4 acc[8] = {};
#pragma unroll
    for (int kt = 0; kt < 4; ++kt) {
        const int joff = kt * 4 + grp;           // k-chunk index 0..15
#pragma unroll
        for (int n = 0; n < 8; ++n) {
            int brow = 16 * n + l16;
            int byte = brow * 256 + ((joff ^ (brow & 15)) << 4);
            short8v b = *reinterpret_cast<const short8v*>(
                reinterpret_cast<const char*>(Bs) + byte);
            acc[n] = __builtin_amdgcn_mfma_f32_16x16x32_bf16(b, a[kt], acc[n], 0, 0, 0);
        }
    }

    if (row >= M) return;   // no barriers past this point

    float4 bb[8];
#pragma unroll
    for (int n = 0; n < 8; ++n)
        bb[n] = bias ? *reinterpret_cast<const float4*>(bias + 16 * n + grp * 4)
                     : make_float4(0.f, 0.f, 0.f, 0.f);

#pragma unroll
    for (int n = 0; n < 8; ++n) {
        float v0 = acc[n][0] + bb[n].x;
        float v1 = acc[n][1] + bb[n].y;
        float v2 = acc[n][2] + bb[n].z;
        float v3 = acc[n][3] + bb[n].w;
        if (Cf) {
            *reinterpret_cast<float4*>(Cf + (size_t)row * 128 + 16 * n + grp * 4) =
                make_float4(v0, v1, v2, v3);
        }
        if (Cb) {
            unsigned u0 = (unsigned)f2bf(v0) | ((unsigned)f2bf(v1) << 16);
            unsigned u1 = (unsigned)f2bf(v2) | ((unsigned)f2bf(v3) << 16);
            *reinterpret_cast<uint2*>(Cb + (size_t)row * 128 + 16 * n + grp * 4) =
                make_uint2(u0, u1);
        }
    }
}

// fused 6-mat pass dispatch; XCD-swizzled (tile-major within XCD)
__device__ void fused_dispatch(const unsigned short* A, const unsigned short* Wt,
                               const float* biasbuf, unsigned short* Xb,
                               unsigned short* Yb, int base, int M, int nmats,
                               int bid, int nF)
{
    int w = xcd_swizzle(bid, nF);
    int m = w % nmats;
    int tile = w / nmats;
    unsigned short* out = (m == 0) ? Xb : Yb + (size_t)(m - 1) * (size_t)M * 128;
    mfmaw_body(A, Wt + (size_t)(base + m) * 16384,
               biasbuf + (size_t)(base + m) * 128, nullptr, out, M, tile);
}

// ---- bias product body: out[t] = sum_j v[j]*W[j*128+t] (+ add[t]) ----
__device__ void biasprod_body(const float* __restrict__ v, const float* __restrict__ W,
                              const float* __restrict__ add, float* __restrict__ out)
{
    int t = threadIdx.x;
    if (t >= 128) return;
    float s = add ? add[t] : 0.f;
    for (int j = 0; j < 128; ++j) s = fmaf(v[j], W[(size_t)j * 128 + t], s);
    out[t] = s;
}

// ---- bf16-transpose convert body: Wt[mat] <- f32 W[k][n] ----
__device__ void wtconv_body(const float* __restrict__ W, unsigned short* __restrict__ O)
{
    for (int i = threadIdx.x; i < 16384; i += 256) {
        int k = i >> 7, n = i & 127;
        O[(size_t)n * 128 + k] = f2bf(W[i]);
    }
}

// ---- bn stats body ----
__device__ void bn_stats_body(const float* __restrict__ h, float* __restrict__ sums,
                              int Nn, int b)
{
    const int c = threadIdx.x & 127;
    const int half = threadIdx.x >> 7;
    float s = 0.f, q = 0.f;
    for (int row = b * 2 + half; row < Nn; row += 512) {
        float v = h[(size_t)row * 128 + c];
        s += v;
        q += v * v;
    }
    __shared__ float ls[256], lq[256];
    ls[threadIdx.x] = s;
    lq[threadIdx.x] = q;
    __syncthreads();
    if (half == 0) {
        s += ls[threadIdx.x + 128];
        q += lq[threadIdx.x + 128];
        atomicAdd(&sums[c], s);
        atomicAdd(&sums[128 + c], q);
    }
}

// ---- scan bodies (counts padded to multiple of 4 for CSR 4-unroll) ----
__device__ void scan_block_sums_body(const int* __restrict__ cnt, int* __restrict__ bsum,
                                     int Nn, int b)
{
    __shared__ int sd[256];
    int tid = threadIdx.x;
    int i = b * 256 + tid;
    sd[tid] = i < Nn ? ((cnt[i] + 3) & ~3) : 0;
    __syncthreads();
#pragma unroll
    for (int s = 128; s > 0; s >>= 1) {
        if (tid < s) sd[tid] += sd[tid + s];
        __syncthreads();
    }
    if (tid == 0) bsum[b] = sd[0];
}

__device__ void scan_offsets_body(int* __restrict__ bsum, int nb)   // nb <= 256
{
    __shared__ int sd[256];
    int tid = threadIdx.x;
    int v = tid < nb ? bsum[tid] : 0;
    sd[tid] = v;
    __syncthreads();
    for (int d = 1; d < 256; d <<= 1) {
        int t = tid >= d ? sd[tid - d] : 0;
        __syncthreads();
        sd[tid] += t;
        __syncthreads();
    }
    if (tid < nb) bsum[tid] = sd[tid] - v;   // exclusive
}

// ================= kernels =================

// histogram (standalone, low VGPR, no global atomics)
__global__ __launch_bounds__(256)
void hist_kernel(const int* __restrict__ ei, unsigned* __restrict__ partial,
                 int Nn, int E, int WORDS, int HALFR)
{
    __shared__ unsigned sh[HIST_MAXW];
    const int hbid = blockIdx.x;
    const int g = hbid / HIST_BPG;
    const int j = hbid - g * HIST_BPG;

    for (int w = threadIdx.x; w < WORDS; w += 256) sh[w] = 0;
    __syncthreads();

    const int* col = (g < 2) ? (ei + E) : ei;
    const int base = (g & 1) * HALFR;
    const size_t e0 = (size_t)E * j / HIST_BPG;
    const size_t e1 = (size_t)E * (j + 1) / HIST_BPG;
    for (size_t e = e0 + threadIdx.x; e < e1; e += 256) {
        int n = col[e] - base;
        if ((unsigned)n < (unsigned)HALFR)
            atomicAdd(&sh[n >> 1], 1u << ((n & 1) * 16));
    }
    __syncthreads();

    unsigned* out = partial + (size_t)hbid * WORDS;
    for (int w = threadIdx.x; w < WORDS; w += 256) out[w] = sh[w];
}

// KP1: stage-1 weight products + biases + converts + x->bf16 conversion.
// Wt slots: 0:A0(win0) 1..nrel:B0_r IA1:A1 IB1..:B1_r IC1:cout1 IPRJ:proj_w
__global__ __launch_bounds__(256)
void kprod1(const float* win0w, const float* win0b, const float* win1w, const float* win1b,
            const float* cout0w, const float* cout0b, const float* cout1w,
            const float* cout1b, const float* wrel0,
            const float* x, const float* proj_w, const float* proj_b,
            unsigned short* xb, float* WfA1, unsigned short* Wt, float* biasbuf,
            int nrel, size_t nx4)
{
    const int IA1 = 1 + nrel, IC1 = 2 + 2 * nrel, IPRJ = 3 + 2 * nrel;
    const int nProd = 1 + nrel;
    int bid = blockIdx.x;
    if (bid < 2 * nProd) {
        int p = bid >> 1, tile = bid & 1;
        if (p == 0)
            gemmf32_body(cout0w, win1w, nullptr, WfA1, Wt + (size_t)IA1 * 16384, 128, tile);
        else
            gemmf32_body(win0w, wrel0 + (size_t)(p - 1) * 16384, nullptr,
                         nullptr, Wt + (size_t)p * 16384, 128, tile);
        return;
    }
    bid -= 2 * nProd;
    if (bid < nProd) {
        if (bid == 0) biasprod_body(cout0b, win1w, win1b, biasbuf + (size_t)IA1 * 128);
        else biasprod_body(win0b, wrel0 + (size_t)(bid - 1) * 16384, nullptr,
                           biasbuf + (size_t)bid * 128);
        return;
    }
    bid -= nProd;
    if (bid == 0) { wtconv_body(win0w, Wt); return; }
    if (bid == 1) { wtconv_body(cout1w, Wt + (size_t)IC1 * 16384); return; }
    if (bid == 2) { wtconv_body(proj_w, Wt + (size_t)IPRJ * 16384); return; }
    if (bid == 3) {
        int t = threadIdx.x;
        if (t < 128) {
            biasbuf[t] = win0b[t];
            biasbuf[(size_t)IC1 * 128 + t] = cout1b[t];
            biasbuf[(size_t)IPRJ * 128 + t] = proj_b[t];
        }
        return;
    }
    // x -> bf16 conversion (float4 -> ushort4)
    size_t i = (size_t)(bid - 4) * 256 + threadIdx.x;
    if (i < nx4) {
        float4 v = reinterpret_cast<const float4*>(x)[i];
        ushort4 pk = make_ushort4(f2bf(v.x), f2bf(v.y), f2bf(v.z), f2bf(v.w));
        reinterpret_cast<ushort4*>(xb)[i] = pk;
    }
}

// KPROJ: h = xb @ proj_w + b  (MFMA, f32 out)
__global__ __launch_bounds__(512)
void kproj(const unsigned short* xb, const unsigned short* Wt, const float* biasbuf,
           float* h, int mat, int M)
{
    mfmaw_body(xb, Wt + (size_t)mat * 16384, biasbuf + (size_t)mat * 128,
               h, nullptr, M, blockIdx.x);
}

// K2: hist-reduce (-> dis, cnt) | bn_stats
__global__ __launch_bounds__(256)
void k2_reduce_bnstats(const unsigned* __restrict__ partial, float* __restrict__ dis,
                       int* __restrict__ cnt, const float* __restrict__ h,
                       float* __restrict__ bnsums, int Nn, int WORDS, int HALFR, int nRed)
{
    int bid = blockIdx.x;
    if (bid < nRed) {
        int t = bid * 256 + threadIdx.x;
        if (t < 4 * WORDS) {
            int histo = t / (2 * WORDS);
            int rem = t - histo * 2 * WORDS;
            int half = rem / WORDS;
            int w = rem - half * WORDS;
            int g = histo * 2 + half;
            unsigned slo = 0, shi = 0;
            const unsigned* p = partial + (size_t)(g * HIST_BPG) * WORDS + w;
#pragma unroll 4
            for (int j = 0; j < HIST_BPG; ++j) {
                unsigned u = p[(size_t)j * WORDS];
                slo += u & 0xffffu;
                shi += u >> 16;
            }
            int n0 = half * HALFR + 2 * w;
            int n1 = n0 + 1;
            if (histo == 0) {
                if (n0 < Nn) dis[n0] = slo ? rsqrtf((float)slo) : 0.f;
                if (n1 < Nn) dis[n1] = shi ? rsqrtf((float)shi) : 0.f;
            } else {
                if (n0 < Nn) cnt[n0] = (int)slo;
                if (n1 < Nn) cnt[n1] = (int)shi;
            }
        }
        return;
    }
    bn_stats_body(h, bnsums, Nn, bid - nRed);
}

// K3: kprod2 (stage-2 products) | bn_finalize | scan_block_sums
// kprod2 blocks first: B1_r = A1 @ wrel1_r ; bB1_r = bA1 @ wrel1_r
__global__ __launch_bounds__(256)
void k3_prod2_bnfin_scan1(const float* wrel1, const float* WfA1,
                          unsigned short* Wt, float* biasbuf, int nrel,
                          const float* __restrict__ sums, const float* __restrict__ g,
                          const float* __restrict__ b, float* __restrict__ sc,
                          const int* __restrict__ cnt, int* __restrict__ bsum, int Nn)
{
    const int IA1 = 1 + nrel, IB1 = 2 + nrel;
    int bid = blockIdx.x;
    if (bid < 2 * nrel) {
        int p = bid >> 1, tile = bid & 1;
        gemmf32_body(WfA1, wrel1 + (size_t)p * 16384, nullptr,
                     nullptr, Wt + (size_t)(IB1 + p) * 16384, 128, tile);
        return;
    }
    bid -= 2 * nrel;
    if (bid < nrel) {
        biasprod_body(biasbuf + (size_t)IA1 * 128, wrel1 + (size_t)bid * 16384, nullptr,
                      biasbuf + (size_t)(IB1 + bid) * 128);
        return;
    }
    bid -= nrel;
    if (bid == 0) {
        int c = threadIdx.x;
        if (c < 128) {
            float inv = 1.f / (float)Nn;
            float mu = sums[c] * inv;
            float var = sums[128 + c] * inv - mu * mu;
            float rstd = rsqrtf(var + 1e-5f);
            float scale = rstd * g[c];
            sc[c] = scale;
            sc[128 + c] = b[c] - mu * scale;
        }
        return;
    }
    scan_block_sums_body(cnt, bsum, Nn, bid - 1);
}

// K4: scan_offsets | bn_apply_relu (f32 -> bf16)
__global__ __launch_bounds__(256)
void k4_scanoff_bnapply(int* __restrict__ bsum, int nb,
                        const float* __restrict__ h, const float* __restrict__ sc,
                        unsigned short* __restrict__ hb, size_t n4)
{
    if (blockIdx.x == 0) { scan_offsets_body(bsum, nb); return; }
    size_t i = (size_t)(blockIdx.x - 1) * 256 + threadIdx.x;
    if (i >= n4) return;
    int c = (int)(i & 31) << 2;
    float4 v = reinterpret_cast<const float4*>(h)[i];
    float o0 = fmaxf(fmaf(v.x, sc[c + 0], sc[128 + c + 0]), 0.f);
    float o1 = fmaxf(fmaf(v.y, sc[c + 1], sc[128 + c + 1]), 0.f);
    float o2 = fmaxf(fmaf(v.z, sc[c + 2], sc[128 + c + 2]), 0.f);
    float o3 = fmaxf(fmaf(v.w, sc[c + 3], sc[128 + c + 3]), 0.f);
    ushort4 pk = make_ushort4(f2bf(o0), f2bf(o1), f2bf(o2), f2bf(o3));
    reinterpret_cast<ushort4*>(hb)[i] = pk;
}

// K4b: scan_final with 4-padded offsets; rowptr/cursor, sink pads, sink row.
__global__ __launch_bounds__(256)
void k4b_scanfinal(const int* __restrict__ cnt, const int* __restrict__ bsum,
                   int* __restrict__ rowptr, int* __restrict__ cursor,
                   uint4* __restrict__ csr, unsigned* __restrict__ Yw,
                   unsigned sink_woff, int Nn, int nb)
{
    if ((int)blockIdx.x == nb) {
        int t = threadIdx.x;
        if (t < 64) Yw[sink_woff + t] = 0xC2C8C2C8u;   // bf16 -100 pair
        return;
    }
    __shared__ int sd[256];
    int tid = threadIdx.x;
    int b = blockIdx.x;
    int i = b * 256 + tid;
    int v = i < Nn ? cnt[i] : 0;
    int pv = (v + 3) & ~3;
    sd[tid] = pv;
    __syncthreads();
    for (int d = 1; d < 256; d <<= 1) {
        int t2 = tid >= d ? sd[tid - d] : 0;
        __syncthreads();
        sd[tid] += t2;
        __syncthreads();
    }
    if (i < Nn) {
        int off = sd[tid] - pv + bsum[b];
        rowptr[i] = off;
        cursor[i] = off;
        uint4 sink = make_uint4(0u, sink_woff, 0u, 0u);
        for (int j = v; j < pv; ++j) csr[off + j] = sink;
        if (i == Nn - 1) {
            rowptr[Nn] = off + pv;
            for (int q = 0; q < 8; ++q) csr[off + pv + q] = sink;   // global pad
        }
    }
}

// K5: layer-0 fused 6-mat MFMA | scatter (interleaved), 512 threads
__global__ __launch_bounds__(512)
void k5_mfma_scatter(const unsigned short* hb, const unsigned short* Wt,
                     const float* biasbuf, unsigned short* Xb, unsigned short* Yb,
                     int M, int nmats, int nF,
                     const int* __restrict__ ei, const int* __restrict__ et,
                     const float* __restrict__ dis, int* __restrict__ cursor,
                     uint4* __restrict__ csr, int E, int Nn, int nS)
{
    const int minv = nF < nS ? nF : nS;
    int bid = blockIdx.x;
    int fIdx = -1, sIdx = -1;
    if (bid < 2 * minv) {
        if (bid & 1) fIdx = bid >> 1; else sIdx = bid >> 1;
    } else {
        int rem = bid - 2 * minv;
        if (nF > nS) fIdx = minv + rem; else sIdx = minv + rem;
    }
    if (sIdx >= 0) {
        int e = sIdx * 512 + threadIdx.x;
        if (e < E) {
            int dst = ei[e];
            int src = ei[E + e];
            int pos = atomicAdd(&cursor[dst], 1);
            float nrm = dis[dst] * dis[src];
            csr[pos] = make_uint4((unsigned)(src * 64),
                                  (unsigned)((et[e] * Nn + src) * 64),
                                  __float_as_uint(nrm), 0u);
        }
        return;
    }
    fused_dispatch(hb, Wt, biasbuf, Xb, Yb, 0, M, nmats, fIdx, nF);
}

// fused 6-mat MFMA pass (generic base, layer 1), 512 threads
__global__ __launch_bounds__(512)
void k_fusedpass(const unsigned short* A, const unsigned short* Wt, const float* biasbuf,
                 unsigned short* Xb, unsigned short* Yb, int base, int M, int nmats,
                 int nF)
{
    fused_dispatch(A, Wt, biasbuf, Xb, Yb, base, M, nmats, blockIdx.x, nF);
}

// final: out[row] = gelu(msg_dense[row] @ cout1 + b), f32, dense M rows, 512 thr
__global__ __launch_bounds__(512)
void k_cout_gelu(const unsigned short* __restrict__ A, const unsigned short* Wt,
                 const float* biasbuf, float* __restrict__ out, int mat, int M)
{
    const unsigned short* Wmat = Wt + (size_t)mat * 16384;
    const float* bias = biasbuf + (size_t)mat * 128;

    __shared__ unsigned short Bs[16384];
    const int tid = threadIdx.x;
#pragma unroll
    for (int i = 0; i < 4; ++i) {
        int idx = tid + i * 512;
        uint4 v = *reinterpret_cast<const uint4*>(Wmat + (size_t)idx * 8);
        int row = idx >> 4;
        int j = idx & 15;
        int byte = row * 256 + ((j ^ (row & 15)) << 4);
        *reinterpret_cast<uint4*>(reinterpret_cast<char*>(Bs) + byte) = v;
    }

    const int wave = tid >> 6;
    const int lane = tid & 63;
    const int grp = lane >> 4;
    const int l16 = lane & 15;
    const int row = blockIdx.x * 128 + wave * 16 + l16;
    const int rc = row < M ? row : M - 1;

    short8v a[4];
#pragma unroll
    for (int kt = 0; kt < 4; ++kt)
        a[kt] = *reinterpret_cast<const short8v*>(A + (size_t)rc * 128 + kt * 32 + grp * 8);

    __syncthreads();

    f32x4 acc[8] = {};
#pragma unroll
    for (int kt = 0; kt < 4; ++kt) {
        const int joff = kt * 4 + grp;
#pragma unroll
        for (int n = 0; n < 8; ++n) {
            int brow = 16 * n + l16;
            int byte = brow * 256 + ((joff ^ (brow & 15)) << 4);
            short8v b = *reinterpret_cast<const short8v*>(
                reinterpret_cast<const char*>(Bs) + byte);
            acc[n] = __builtin_amdgcn_mfma_f32_16x16x32_bf16(b, a[kt], acc[n], 0, 0, 0);
        }
    }

    if (row >= M) return;

    const float kg = 0.7071067811865475f;
#pragma unroll
    for (int n = 0; n < 8; ++n) {
        float4 bb = *reinterpret_cast<const float4*>(bias + 16 * n + grp * 4);
        float v0 = acc[n][0] + bb.x;
        float v1 = acc[n][1] + bb.y;
        float v2 = acc[n][2] + bb.z;
        float v3 = acc[n][3] + bb.w;
        v0 = 0.5f * v0 * (1.f + erff(v0 * kg));
        v1 = 0.5f * v1 * (1.f + erff(v1 * kg));
        v2 = 0.5f * v2 * (1.f + erff(v2 * kg));
        v3 = 0.5f * v3 * (1.f + erff(v3 * kg));
        *reinterpret_cast<float4*>(out + (size_t)row * 128 + 16 * n + grp * 4) =
            make_float4(v0, v1, v2, v3);
    }
}

// ---- fused per-node gather: gcn-sum + scatter-softmax + combine ----
__global__ __launch_bounds__(256)
void node_gather(const int* __restrict__ rowptr, const uint4* __restrict__ csr,
                 const unsigned* __restrict__ Xw, const unsigned* __restrict__ Yw,
                 unsigned short* __restrict__ outb,
                 const int* __restrict__ idxmap, int count)
{
    int gid = blockIdx.x * 4 + (threadIdx.x >> 6);
    if (gid >= count) return;
    int node = idxmap ? idxmap[gid] : gid;
    int lane = threadIdx.x & 63;

    int i = rowptr[node];
    const int end = rowptr[node + 1];

    float mg0 = 0.f, mg1 = 0.f, s0 = 0.f, s1 = 0.f, t0 = 0.f, t1 = 0.f;

    if (i < end) {
        uint4 cur[4];
#pragma unroll
        for (int q = 0; q < 4; ++q) cur[q] = csr[i + q];

        for (; i < end; i += 4) {
            uint4 nxt[4];
#pragma unroll
            for (int q = 0; q < 4; ++q) nxt[q] = csr[i + 4 + q];   // global pad covers

            unsigned xp[4], yp[4];
#pragma unroll
            for (int q = 0; q < 4; ++q) {
                xp[q] = Xw[cur[q].x + lane];
                yp[q] = Yw[cur[q].y + lane];
            }
#pragma unroll
            for (int q = 0; q < 4; ++q) {
                float nrm = __uint_as_float(cur[q].z);
                float x0 = bf2f((unsigned short)(xp[q] & 0xffffu));
                float x1 = bf2f((unsigned short)(xp[q] >> 16));
                float y0 = bf2f((unsigned short)(yp[q] & 0xffffu));
                float y1 = bf2f((unsigned short)(yp[q] >> 16));
                float w0 = __expf(y0), w1 = __expf(y1);
                mg0 = fmaf(x0, nrm, mg0);
                mg1 = fmaf(x1, nrm, mg1);
                s0 += w0; s1 += w1;
                t0 = fmaf(y0, w0, t0);
                t1 = fmaf(y1, w1, t1);
            }
#pragma unroll
            for (int q = 0; q < 4; ++q) cur[q] = nxt[q];
        }
    }

    float o0 = mg0 + 0.1f * fmaxf(s0 > 0.f ? t0 / s0 : 0.f, 0.f);
    float o1 = mg1 + 0.1f * fmaxf(s1 > 0.f ? t1 / s1 : 0.f, 0.f);
    unsigned pk = (unsigned)f2bf(o0) | ((unsigned)f2bf(o1) << 16);
    *reinterpret_cast<unsigned*>(outb + (size_t)gid * 128 + (lane << 1)) = pk;
}

// ================= launch =================
extern "C" void kernel_launch(void* const* d_in, const int* in_sizes, int n_in,
                              void* d_out, int out_size, void* d_ws, size_t ws_size,
                              hipStream_t stream)
{
    const float* x      = (const float*)d_in[0];
    const int*   ei     = (const int*)d_in[1];
    const int*   et     = (const int*)d_in[2];
    // d_in[3] edge_weight: unused by the reference
    const int*   idxp   = (const int*)d_in[4];
    const float* proj_w = (const float*)d_in[5];
    const float* proj_b = (const float*)d_in[6];
    const float* bn_g   = (const float*)d_in[7];
    const float* bn_b   = (const float*)d_in[8];
    const float* win_w[2]  = {(const float*)d_in[9],  (const float*)d_in[14]};
    const float* win_b[2]  = {(const float*)d_in[10], (const float*)d_in[15]};
    const float* wrel[2]   = {(const float*)d_in[11], (const float*)d_in[16]};
    const float* cout_w[2] = {(const float*)d_in[12], (const float*)d_in[17]};
    const float* cout_b[2] = {(const float*)d_in[13], (const float*)d_in[18]};

    const int Nn  = in_sizes[0] / 128;
    const int E   = in_sizes[1] / 2;
    const int Mo  = in_sizes[4];
    const int nrel = in_sizes[11] / (128 * 128);
    const size_t ND = (size_t)Nn * 128;

    const int HALFR = ((Nn + 3) / 4) * 2;
    const int WORDS = HALFR / 2;
    if (WORDS > HIST_MAXW) return;

    const int IA1 = 1 + nrel;
    const int IC1 = 2 + 2 * nrel;
    const int IPRJ = 3 + 2 * nrel;
    const int NMATS = 4 + 2 * nrel;   // + proj slot

    // workspace layout
    char* p = (char*)d_ws;
    float* h    = (float*)p;                  p += ND * 4;
    unsigned short* hb = (unsigned short*)p;  p += ND * 2;
    unsigned short* xb = (unsigned short*)p;  p += ND * 2;            // bf16 x
    unsigned short* Xb = (unsigned short*)p;  p += ND * 2;
    unsigned short* Yb = (unsigned short*)p;  p += (size_t)nrel * ND * 2 + 256;  // +sink row
    unsigned short* msgb = (unsigned short*)p; p += ND * 2;
    unsigned short* Wt = (unsigned short*)p;  p += (size_t)NMATS * 16384 * 2;
    float* WfA1 = (float*)p;                  p += (size_t)16384 * 4;
    float* biasbuf = (float*)p;               p += (size_t)NMATS * 128 * 4;
    uint4* csr  = (uint4*)p;                  p += ((size_t)E + 3 * (size_t)Nn + 16) * 16;
    unsigned* partial = (unsigned*)p;         p += (size_t)HIST_B * WORDS * 4;
    float* dis  = (float*)p;                  p += (size_t)Nn * 4;
    int*   cnt  = (int*)p;                    p += (size_t)Nn * 4;
    int*   rowptr = (int*)p;                  p += ((size_t)Nn + 1) * 4;
    int*   cursor = (int*)p;                  p += (size_t)Nn * 4;
    int*   bsum = (int*)p;                    p += 1024 * 4;
    float* bnsums = (float*)p;                p += 256 * 4;
    float* bnsc   = (float*)p;                p += 256 * 4;
    if ((size_t)(p - (char*)d_ws) > ws_size) return;

    const unsigned sink_woff = (unsigned)((size_t)nrel * Nn * 64);   // word offset in Yb

    const int tiles128 = (Nn + 127) / 128;
    const size_t n4 = ND / 4;
    const int n4grid = (int)((n4 + 255) / 256);
    const int nb = (Nn + 255) / 256;
    const int nRed = (4 * WORDS + 255) / 256;
    const int nS = (E + 511) / 512;
    const int nmats = 1 + nrel;
    const int nFused = nmats * tiles128;
    const int nConv = (int)((n4 + 255) / 256);   // x->bf16 blocks

    hipMemsetAsync(bnsums, 0, 256 * 4, stream);

    // histogram (depends only on ei)
    hist_kernel<<<HIST_B, 256, 0, stream>>>(ei, partial, Nn, E, WORDS, HALFR);

    // stage-1 weight products + converts + x->bf16
    kprod1<<<2 * (1 + nrel) + (1 + nrel) + 4 + nConv, 256, 0, stream>>>(
        win_w[0], win_b[0], win_w[1], win_b[1], cout_w[0], cout_b[0],
        cout_w[1], cout_b[1], wrel[0], x, proj_w, proj_b,
        xb, WfA1, Wt, biasbuf, nrel, n4);

    // proj via MFMA: h = xb @ proj_w + b (f32)
    kproj<<<tiles128, 512, 0, stream>>>(xb, Wt, biasbuf, h, IPRJ, Nn);

    // K2: hist reduce (dis, cnt) | bn_stats
    k2_reduce_bnstats<<<nRed + 256, 256, 0, stream>>>(
        partial, dis, cnt, h, bnsums, Nn, WORDS, HALFR, nRed);

    // K3: kprod2 | bn_finalize | scan level-1 (padded counts)
    k3_prod2_bnfin_scan1<<<3 * nrel + 1 + nb, 256, 0, stream>>>(
        wrel[1], WfA1, Wt, biasbuf, nrel,
        bnsums, bn_g, bn_b, bnsc, cnt, bsum, Nn);

    // K4: scan offsets | bn apply+relu -> hb
    k4_scanoff_bnapply<<<1 + n4grid, 256, 0, stream>>>(bsum, nb, h, bnsc, hb, n4);

    // K4b: scan final (padded rowptr/cursor) + sink pads + sink row
    k4b_scanfinal<<<nb + 1, 256, 0, stream>>>(cnt, bsum, rowptr, cursor, csr,
                                              (unsigned*)Yb, sink_woff, Nn, nb);

    // K5: layer-0 fused 6-mat MFMA | scatter (interleaved, 512 thr, XCD-swizzled)
    k5_mfma_scatter<<<nFused + nS, 512, 0, stream>>>(
        hb, Wt, biasbuf, Xb, Yb, Nn, nmats, nFused,
        ei, et, dis, cursor, csr, E, Nn, nS);

    // layer 0 gather (all nodes)
    node_gather<<<(Nn + 3) / 4, 256, 0, stream>>>(
        rowptr, csr, (const unsigned*)Xb, (const unsigned*)Yb, msgb, nullptr, Nn);

    // layer-1 fused 6-mat pass (all nodes, XCD-swizzled)
    k_fusedpass<<<nFused, 512, 0, stream>>>(msgb, Wt, biasbuf, Xb, Yb, IA1, Nn,
                                            nmats, nFused);

    // layer 1 gather: ONLY the idx destination nodes (dense Mo-row output)
    node_gather<<<(Mo + 3) / 4, 256, 0, stream>>>(
        rowptr, csr, (const unsigned*)Xb, (const unsigned*)Yb, msgb, idxp, Mo);

    // final: cout1 + gelu on dense Mo rows -> d_out
    k_cout_gelu<<<(Mo + 127) / 128, 512, 0, stream>>>(
        msgb, Wt, biasbuf, (float*)d_out, IC1, Mo);
}